// Round 19
// baseline (590.013 us; speedup 1.0000x reference)
//
#include <hip/hip_runtime.h>
#include <math.h>

#define SS 2048
#define DD 1024
#define HH 16
#define CAPC 327680u  // candidate slots per head (range ~9 bins x ~16K/bin ~ 150K expected)
#define LCAP 2048     // per-block LDS candidate buffer (expected ~1200/block)
#define RBIN 4        // predicted-bin safety margin (sampling sigma ~0.16 bins)
#define NSPL 2        // flash key-split count (round-17-proven; 4 regressed in r18)

// quantile index: floor(0.95*(S*S-1)) = floor(3984587.85)
#define K_A 3984587u
#define K_B 3984588u
#define QFRAC 0.85f
#define WSCALE 2048.0f      // W planes pre-scaled so lo-residuals stay normal fp16
#define WSCALE_INV (1.0f/2048.0f)
#define ESHIFT 4.0f         // exp(s - thr - ESHIFT): kept P in [e^-4, ~e^6] — fp16-safe
#define PLANE 2097152       // floats per 2048x1024 fp32 partial plane (8 MiB)
#define NSAMP_RANK 124518u  // floor(0.95 * 131072) — sample quantile rank

typedef _Float16 f16x8 __attribute__((ext_vector_type(8)));
typedef _Float16 f16x4 __attribute__((ext_vector_type(4)));
typedef float    f32x4 __attribute__((ext_vector_type(4)));

__device__ __forceinline__ unsigned sortkey(float f) {
  unsigned b = __float_as_uint(f);
  return (b & 0x80000000u) ? ~b : (b | 0x80000000u);
}
__device__ __forceinline__ float inv_sortkey(unsigned u) {
  unsigned b = (u & 0x80000000u) ? (u ^ 0x80000000u) : ~u;
  return __uint_as_float(b);
}

// ---------------- input splitting ----------------
__global__ __launch_bounds__(256) void split_x(const float* __restrict__ x,
                                               _Float16* __restrict__ xh,
                                               _Float16* __restrict__ xl)
{
  const int i = blockIdx.x * 256 + threadIdx.x;   // float4 index, 524288 total
  float4 v = ((const float4*)x)[i];
  float vv[4] = {v.x, v.y, v.z, v.w};
  f16x4 h, l;
#pragma unroll
  for (int j = 0; j < 4; ++j) {
    _Float16 hh = (_Float16)vv[j];
    h[j] = hh;
    l[j] = (_Float16)(vv[j] - (float)hh);
  }
  ((f16x4*)xh)[i] = h;
  ((f16x4*)xl)[i] = l;
}

// W -> transposed hi/lo fp16 planes WT[n][k], scaled by 2048 (keeps lo normal).
__global__ __launch_bounds__(256) void split_wT(const float* __restrict__ Wq,
                                                const float* __restrict__ Wk,
                                                const float* __restrict__ Wv,
                                                const float* __restrict__ Wo,
                                                _Float16* __restrict__ wplanes)
{
  const int z = blockIdx.z;
  const float* W = (z == 0) ? Wq : (z == 1) ? Wk : (z == 2) ? Wv : Wo;
  _Float16* WhT = wplanes + (size_t)(2*z)     * (1024*1024);
  _Float16* WlT = wplanes + (size_t)(2*z + 1) * (1024*1024);
  __shared__ float tile[64][65];
  const int t  = threadIdx.x;
  const int r  = t >> 2;         // 0..63
  const int c0 = (t & 3) * 16;   // 0/16/32/48
  const int k0 = blockIdx.y * 64;
  const int n0 = blockIdx.x * 64;
#pragma unroll
  for (int j = 0; j < 4; ++j) {
    float4 v = *(const float4*)&W[(size_t)(k0 + r) * 1024 + n0 + c0 + j*4];
    tile[r][c0+j*4+0] = v.x; tile[r][c0+j*4+1] = v.y;
    tile[r][c0+j*4+2] = v.z; tile[r][c0+j*4+3] = v.w;
  }
  __syncthreads();
  f16x8 h0, h1, l0, l1;
#pragma unroll
  for (int j = 0; j < 8; ++j) {
    float v = tile[c0 + j][r] * WSCALE;
    _Float16 h = (_Float16)v;
    h0[j] = h; l0[j] = (_Float16)(v - (float)h);
  }
#pragma unroll
  for (int j = 0; j < 8; ++j) {
    float v = tile[c0 + 8 + j][r] * WSCALE;
    _Float16 h = (_Float16)v;
    h1[j] = h; l1[j] = (_Float16)(v - (float)h);
  }
  const size_t o = (size_t)(n0 + r) * 1024 + k0 + c0;
  *(f16x8*)&WhT[o]     = h0;
  *(f16x8*)&WhT[o + 8] = h1;
  *(f16x8*)&WlT[o]     = l0;
  *(f16x8*)&WlT[o + 8] = l1;
}

// ---------------- split-K MFMA GEMM partial ----------------
__device__ __forceinline__ void gemm_mfma_part(const _Float16* __restrict__ Ah,
                                               const _Float16* __restrict__ Al,
                                               const _Float16* __restrict__ BhT,
                                               const _Float16* __restrict__ BlT,
                                               float* __restrict__ pout,
                                               int bm, int bn, int kh)
{
  const int wave = threadIdx.x >> 6, lane = threadIdx.x & 63;
  const int wr = wave >> 1, wc = wave & 1;
  const int m0 = bm * 128 + wr * 64;
  const int n0 = bn * 128 + wc * 64;
  const int lr = lane & 15;
  const int ko = lane >> 4;

  f32x4 acc[4][4];
#pragma unroll
  for (int i = 0; i < 4; ++i)
#pragma unroll
    for (int j = 0; j < 4; ++j) acc[i][j] = (f32x4){0.f, 0.f, 0.f, 0.f};

  for (int kk = kh*16; kk < kh*16 + 16; ++kk) {
    const int kof = kk*32 + ko*8;
    f16x8 aH[4], aL[4], bH[4], bL[4];
#pragma unroll
    for (int i = 0; i < 4; ++i) {
      const size_t aoff = (size_t)(m0 + i*16 + lr) * 1024 + kof;
      aH[i] = *(const f16x8*)(Ah + aoff);
      aL[i] = *(const f16x8*)(Al + aoff);
      const size_t boff = (size_t)(n0 + i*16 + lr) * 1024 + kof;
      bH[i] = *(const f16x8*)(BhT + boff);
      bL[i] = *(const f16x8*)(BlT + boff);
    }
#pragma unroll
    for (int i = 0; i < 4; ++i)
#pragma unroll
      for (int j = 0; j < 4; ++j) {
        acc[i][j] = __builtin_amdgcn_mfma_f32_16x16x32_f16(aL[i], bL[j], acc[i][j], 0, 0, 0);
        acc[i][j] = __builtin_amdgcn_mfma_f32_16x16x32_f16(aH[i], bL[j], acc[i][j], 0, 0, 0);
        acc[i][j] = __builtin_amdgcn_mfma_f32_16x16x32_f16(aL[i], bH[j], acc[i][j], 0, 0, 0);
        acc[i][j] = __builtin_amdgcn_mfma_f32_16x16x32_f16(aH[i], bH[j], acc[i][j], 0, 0, 0);
      }
  }

#pragma unroll
  for (int i = 0; i < 4; ++i)
#pragma unroll
    for (int j = 0; j < 4; ++j)
#pragma unroll
      for (int r = 0; r < 4; ++r) {
        const int row = m0 + i*16 + ko*4 + r;
        const int col = n0 + j*16 + lr;
        pout[(size_t)row * 1024 + col] = acc[i][j][r];
      }
}

__global__ __launch_bounds__(256) void gemm_qkv_part(const _Float16* __restrict__ xh,
                                                     const _Float16* __restrict__ xl,
                                                     const _Float16* __restrict__ wplanes,
                                                     float* __restrict__ pbuf)
{
  const int z = blockIdx.z;           // 0..5: gemm_id*2 + khalf
  const int g = z >> 1, kh = z & 1;
  const _Float16* BhT = wplanes + (size_t)(2*g)     * (1024*1024);
  const _Float16* BlT = wplanes + (size_t)(2*g + 1) * (1024*1024);
  gemm_mfma_part(xh, xl, BhT, BlT, pbuf + (size_t)z * PLANE,
                 blockIdx.y, blockIdx.x, kh);
}

__global__ __launch_bounds__(256) void gemm_o_part(const _Float16* __restrict__ ctxh,
                                                   const _Float16* __restrict__ ctxl,
                                                   const _Float16* __restrict__ wplanes,
                                                   float* __restrict__ pO)
{
  const int kh = blockIdx.z;          // 0..1
  gemm_mfma_part(ctxh, ctxl,
                 wplanes + (size_t)6 * (1024*1024),
                 wplanes + (size_t)7 * (1024*1024),
                 pO + (size_t)kh * PLANE, blockIdx.y, blockIdx.x, kh);
}

// ---------------- combine kernels ----------------
__global__ __launch_bounds__(256) void combine_qk(const float* __restrict__ pbuf,
                                                  const float* __restrict__ bq,
                                                  const float* __restrict__ bk,
                                                  _Float16* __restrict__ Qh,
                                                  _Float16* __restrict__ Ql,
                                                  _Float16* __restrict__ Kh,
                                                  _Float16* __restrict__ Kl)
{
  const int which = blockIdx.y;       // 0=Q, 1=K
  const float* p0 = pbuf + (size_t)(which*2)     * PLANE;
  const float* p1 = pbuf + (size_t)(which*2 + 1) * PLANE;
  const float* bias = which ? bk : bq;
  _Float16* Oh = which ? Kh : Qh;
  _Float16* Ol = which ? Kl : Ql;
  const int i = blockIdx.x * 256 + threadIdx.x;   // f4 index, 524288
  const int coloff = (i & 255) * 4;
  float4 a = ((const float4*)p0)[i];
  float4 b = ((const float4*)p1)[i];
  float av[4] = {a.x, a.y, a.z, a.w};
  float bv[4] = {b.x, b.y, b.z, b.w};
  f16x4 h, l;
#pragma unroll
  for (int j = 0; j < 4; ++j) {
    const float val = (av[j] + bv[j]) * WSCALE_INV + bias[coloff + j];
    _Float16 hh = (_Float16)val;
    h[j] = hh;
    l[j] = (_Float16)(val - (float)hh);
  }
  ((f16x4*)Oh)[i] = h;
  ((f16x4*)Ol)[i] = l;
}

// V: combine + transpose to Vt[dim][row] hi/lo planes (LDS 64x64 tile).
__global__ __launch_bounds__(256) void combine_vT(const float* __restrict__ pbuf,
                                                  const float* __restrict__ bv,
                                                  _Float16* __restrict__ VtH,
                                                  _Float16* __restrict__ VtL)
{
  const float* p0 = pbuf + (size_t)4 * PLANE;
  const float* p1 = pbuf + (size_t)5 * PLANE;
  __shared__ float tile[64][65];
  const int t  = threadIdx.x;
  const int d0 = blockIdx.x * 64;     // dim tile
  const int m0 = blockIdx.y * 64;     // row tile
  {
    const int r  = t >> 2;            // row 0..63
    const int c0 = (t & 3) * 16;
#pragma unroll
    for (int j = 0; j < 4; ++j) {
      const size_t o = (size_t)(m0 + r) * 1024 + d0 + c0 + j*4;
      float4 a = *(const float4*)(p0 + o);
      float4 b = *(const float4*)(p1 + o);
      tile[r][c0+j*4+0] = (a.x + b.x) * WSCALE_INV + bv[d0 + c0 + j*4 + 0];
      tile[r][c0+j*4+1] = (a.y + b.y) * WSCALE_INV + bv[d0 + c0 + j*4 + 1];
      tile[r][c0+j*4+2] = (a.z + b.z) * WSCALE_INV + bv[d0 + c0 + j*4 + 2];
      tile[r][c0+j*4+3] = (a.w + b.w) * WSCALE_INV + bv[d0 + c0 + j*4 + 3];
    }
  }
  __syncthreads();
  {
    const int d  = t >> 2;            // dim 0..63
    const int rg = (t & 3) * 16;      // row group
#pragma unroll
    for (int j = 0; j < 4; ++j) {
      f16x4 hv, lv;
#pragma unroll
      for (int r = 0; r < 4; ++r) {
        const float val = tile[rg + j*4 + r][d];
        _Float16 h = (_Float16)val;
        hv[r] = h; lv[r] = (_Float16)(val - (float)h);
      }
      const size_t o = (size_t)(d0 + d) * 2048 + m0 + rg + j*4;
      *(f16x4*)&VtH[o] = hv;
      *(f16x4*)&VtL[o] = lv;
    }
  }
}

__global__ __launch_bounds__(256) void combine_o(const float* __restrict__ pO,
                                                 const float* __restrict__ bo,
                                                 float* __restrict__ out)
{
  const float* p0 = pO;
  const float* p1 = pO + (size_t)1 * PLANE;
  const int i = blockIdx.x * 256 + threadIdx.x;
  const int coloff = (i & 255) * 4;
  float4 a = ((const float4*)p0)[i];
  float4 b = ((const float4*)p1)[i];
  float4 o;
  o.x = (a.x + b.x) * WSCALE_INV + bo[coloff + 0];
  o.y = (a.y + b.y) * WSCALE_INV + bo[coloff + 1];
  o.z = (a.z + b.z) * WSCALE_INV + bo[coloff + 2];
  o.w = (a.w + b.w) * WSCALE_INV + bo[coloff + 3];
  ((float4*)out)[i] = o;
}

// ctx: sum of NSPL partials / sum of NSPL rowsums, then fp16 hi/lo split.
__global__ __launch_bounds__(256) void combine_ctx(const float* __restrict__ pctx,
                                                   const float* __restrict__ prs,
                                                   _Float16* __restrict__ ctxh,
                                                   _Float16* __restrict__ ctxl)
{
  const int i = blockIdx.x * 256 + threadIdx.x;   // f4 index, 524288
  const int row = i >> 8;
  const int cd  = (i & 255) * 4;
  const int h   = cd >> 6;
  float rs = 0.f;
#pragma unroll
  for (int q = 0; q < NSPL; ++q) rs += prs[q*32768 + h*2048 + row];
  float av[4] = {0.f, 0.f, 0.f, 0.f};
#pragma unroll
  for (int q = 0; q < NSPL; ++q) {
    float4 a = ((const float4*)(pctx + (size_t)q * PLANE))[i];
    av[0] += a.x; av[1] += a.y; av[2] += a.z; av[3] += a.w;
  }
  f16x4 hh, ll;
#pragma unroll
  for (int j = 0; j < 4; ++j) {
    const float val = av[j] / rs;
    _Float16 hv = (_Float16)val;
    hh[j] = hv;
    ll[j] = (_Float16)(val - (float)hv);
  }
  ((f16x4*)ctxh)[i] = hh;
  ((f16x4*)ctxl)[i] = ll;
}

// ---------------- selection init ----------------
__global__ __launch_bounds__(256) void init_sel(unsigned* __restrict__ ghist,
                                                unsigned* __restrict__ shist,
                                                unsigned* __restrict__ ccnt,
                                                unsigned* __restrict__ flag,
                                                unsigned* __restrict__ fhist,
                                                unsigned* __restrict__ cntBelow,
                                                unsigned* __restrict__ ghist9)
{
  int i = blockIdx.x * 256 + threadIdx.x;
  for (; i < HH * 16384; i += gridDim.x * 256) { ghist[i] = 0; shist[i] = 0; }
  const int j = blockIdx.x * 256 + threadIdx.x;
  if (j < HH * 512) fhist[j] = 0;
  if (j < HH * 16) ghist9[j] = 0;
  if (blockIdx.x == 0 && threadIdx.x < HH) {
    ccnt[threadIdx.x] = 0; flag[threadIdx.x] = 0; cntBelow[threadIdx.x] = 0;
  }
}

// ---------------- sampling pass: 64 of 2048 query rows (stride 32) ----------------
__global__ __launch_bounds__(256) void sample_hist(const _Float16* __restrict__ Qh,
                                                   const _Float16* __restrict__ Ql,
                                                   const _Float16* __restrict__ Kh,
                                                   const _Float16* __restrict__ Kl,
                                                   unsigned* __restrict__ shist)
{
  const int kb = blockIdx.x, h = blockIdx.y;
  const int wave = threadIdx.x >> 6, lane = threadIdx.x & 63;
  const int lr = lane & 15, ko = lane >> 4;
  const int n0 = kb*128 + wave*32;

  __shared__ unsigned lh[16384];   // 64 KB
  for (int i = threadIdx.x; i < 16384; i += 256) lh[i] = 0;
  __syncthreads();

  f32x4 acc[4][2];
#pragma unroll
  for (int i = 0; i < 4; ++i)
#pragma unroll
    for (int j = 0; j < 2; ++j) acc[i][j] = (f32x4){0.f, 0.f, 0.f, 0.f};

#pragma unroll
  for (int kk = 0; kk < 2; ++kk) {
    f16x8 aH[4], aL[4], bH[2], bL[2];
#pragma unroll
    for (int i = 0; i < 4; ++i) {
      const size_t aoff = (size_t)((i*16 + lr) * 32) * 1024 + h*64 + kk*32 + ko*8;
      aH[i] = *(const f16x8*)(Qh + aoff);
      aL[i] = *(const f16x8*)(Ql + aoff);
    }
#pragma unroll
    for (int j = 0; j < 2; ++j) {
      const size_t boff = (size_t)(n0 + j*16 + lr) * 1024 + h*64 + kk*32 + ko*8;
      bH[j] = *(const f16x8*)(Kh + boff);
      bL[j] = *(const f16x8*)(Kl + boff);
    }
#pragma unroll
    for (int i = 0; i < 4; ++i)
#pragma unroll
      for (int j = 0; j < 2; ++j) {
        acc[i][j] = __builtin_amdgcn_mfma_f32_16x16x32_f16(aL[i], bL[j], acc[i][j], 0, 0, 0);
        acc[i][j] = __builtin_amdgcn_mfma_f32_16x16x32_f16(aH[i], bL[j], acc[i][j], 0, 0, 0);
        acc[i][j] = __builtin_amdgcn_mfma_f32_16x16x32_f16(aL[i], bH[j], acc[i][j], 0, 0, 0);
        acc[i][j] = __builtin_amdgcn_mfma_f32_16x16x32_f16(aH[i], bH[j], acc[i][j], 0, 0, 0);
      }
  }

#pragma unroll
  for (int i = 0; i < 4; ++i)
#pragma unroll
    for (int j = 0; j < 2; ++j)
#pragma unroll
      for (int r = 0; r < 4; ++r) {
        const float val = acc[i][j][r] * 0.125f;
        atomicAdd(&lh[sortkey(val) >> 18], 1u);
      }
  __syncthreads();
  unsigned* __restrict__ gh = shist + (size_t)h * 16384;
  for (int i = threadIdx.x; i < 16384; i += 256) {
    const unsigned c = lh[i];
    if (c) atomicAdd(&gh[i], c);
  }
}

// find sample-quantile bin; emit conservative range [bin-RBIN, bin+RBIN]
__global__ __launch_bounds__(256) void sample_scan(const unsigned* __restrict__ shist,
                                                   unsigned* __restrict__ rangeLo,
                                                   unsigned* __restrict__ rangeHi)
{
  const int hh = blockIdx.x;
  const int t = threadIdx.x;
  __shared__ unsigned part[256];
  __shared__ unsigned outb;
  if (t == 0) outb = 8192u;  // defensive default
  const unsigned* __restrict__ hb = shist + (size_t)hh * 16384;
  unsigned s = 0;
  for (int j = 0; j < 64; ++j) s += hb[t*64 + j];
  part[t] = s;
  __syncthreads();
  if (t == 0) {
    unsigned run = 0;
    for (int i = 0; i < 256; ++i) { unsigned tmp = part[i]; part[i] = run; run += tmp; }
  }
  __syncthreads();
  const unsigned cum0 = part[t];
  if (NSAMP_RANK >= cum0 && NSAMP_RANK < cum0 + s) {
    unsigned c2 = cum0;
    for (int j = 0; j < 64; ++j) {
      const unsigned c = hb[t*64 + j];
      if (NSAMP_RANK < c2 + c) { outb = t*64 + j; break; }
      c2 += c;
    }
  }
  __syncthreads();
  if (t == 0) {
    const int b = (int)outb;
    rangeLo[hh] = (unsigned)((b - RBIN < 0) ? 0 : b - RBIN);
    rangeHi[hh] = (unsigned)((b + RBIN > 16383) ? 16383 : b + RBIN);
  }
}

// ---------------- pass 1: count-below + range compaction ----------------
// r18 post-mortem: epilogue cost = per-score sortkey VALU + same-address lcnt
// LDS atomics (~1200/block, wave-serialized). Fixes: (a) float-domain range
// tests (sortkey monotonic; MFMA scores never -0.0 since acc starts +0 and
// IEEE sums of mixed signs give +0) -> sortkey only for ~3.5% in-range;
// (b) wave-aggregated push: ballot+popcount prefix, ONE lcnt atomic per wave.
// Candidate multiset identical (order differs; histograms order-invariant).
__global__ __launch_bounds__(512) void range_count(const _Float16* __restrict__ Qh,
                                                   const _Float16* __restrict__ Ql,
                                                   const _Float16* __restrict__ Kh,
                                                   const _Float16* __restrict__ Kl,
                                                   const unsigned* __restrict__ rangeLo,
                                                   const unsigned* __restrict__ rangeHi,
                                                   unsigned* __restrict__ cand,
                                                   unsigned* __restrict__ ccnt,
                                                   unsigned* __restrict__ cntBelow)
{
  const int bn = blockIdx.x, bm = blockIdx.y, h = blockIdx.z;
  const int wave = threadIdx.x >> 6, lane = threadIdx.x & 63;
  const int wr = wave >> 1, wc = wave & 1;
  const int m0 = bm * 256 + wr * 64;
  const int n0 = bn * 128 + wc * 64;
  const int lr = lane & 15;
  const int ko = lane >> 4;
  const unsigned lo = rangeLo[h], hi = rangeHi[h];
  const float thrLo = inv_sortkey(lo << 18);
  const float thrHi = (hi >= 16383u) ? INFINITY : inv_sortkey((hi + 1u) << 18);
  unsigned* __restrict__ mycand = cand + (size_t)h * CAPC;

  __shared__ unsigned lbuf[LCAP];  // 8 KB
  __shared__ unsigned lcnt, gbase, lbelow;
  if (threadIdx.x == 0) { lcnt = 0; lbelow = 0; }
  __syncthreads();

  f32x4 acc[4][4];
#pragma unroll
  for (int i = 0; i < 4; ++i)
#pragma unroll
    for (int j = 0; j < 4; ++j) acc[i][j] = (f32x4){0.f, 0.f, 0.f, 0.f};

#pragma unroll
  for (int kk = 0; kk < 2; ++kk) {
    f16x8 aH[4], aL[4], bH[4], bL[4];
#pragma unroll
    for (int i = 0; i < 4; ++i) {
      const size_t aoff = (size_t)(m0 + i*16 + lr) * 1024 + h*64 + kk*32 + ko*8;
      aH[i] = *(const f16x8*)(Qh + aoff);
      aL[i] = *(const f16x8*)(Ql + aoff);
      const size_t boff = (size_t)(n0 + i*16 + lr) * 1024 + h*64 + kk*32 + ko*8;
      bH[i] = *(const f16x8*)(Kh + boff);
      bL[i] = *(const f16x8*)(Kl + boff);
    }
#pragma unroll
    for (int i = 0; i < 4; ++i)
#pragma unroll
      for (int j = 0; j < 4; ++j) {
        acc[i][j] = __builtin_amdgcn_mfma_f32_16x16x32_f16(aL[i], bL[j], acc[i][j], 0, 0, 0);
        acc[i][j] = __builtin_amdgcn_mfma_f32_16x16x32_f16(aH[i], bL[j], acc[i][j], 0, 0, 0);
        acc[i][j] = __builtin_amdgcn_mfma_f32_16x16x32_f16(aL[i], bH[j], acc[i][j], 0, 0, 0);
        acc[i][j] = __builtin_amdgcn_mfma_f32_16x16x32_f16(aH[i], bH[j], acc[i][j], 0, 0, 0);
      }
  }

  unsigned nb = 0;
#pragma unroll
  for (int i = 0; i < 4; ++i)
#pragma unroll
    for (int j = 0; j < 4; ++j)
#pragma unroll
      for (int r = 0; r < 4; ++r) {
        const float val = acc[i][j][r] * 0.125f;
        nb += (val < thrLo) ? 1u : 0u;
        const bool inr = (val >= thrLo) && (val < thrHi);
        const unsigned long long mk = __ballot(inr);
        if (mk) {
          const unsigned cntw = (unsigned)__popcll(mk);
          unsigned basew = 0;
          if (lane == 0) basew = atomicAdd(&lcnt, cntw);   // loop is divergence-free
          basew = __shfl(basew, 0);
          if (inr) {
            const unsigned u = sortkey(val);
            const unsigned prefix = (unsigned)__popcll(mk & ((1ull << lane) - 1ull));
            const unsigned id = basew + prefix;
            if (id < LCAP) lbuf[id] = u;
            else { unsigned g = atomicAdd(&ccnt[h], 1u); if (g < CAPC) mycand[g] = u; }
          }
        }
      }
  // wave-reduce below-count, one LDS atomic per wave
  nb += __shfl_xor(nb, 1);  nb += __shfl_xor(nb, 2);
  nb += __shfl_xor(nb, 4);  nb += __shfl_xor(nb, 8);
  nb += __shfl_xor(nb, 16); nb += __shfl_xor(nb, 32);
  if (lane == 0) atomicAdd(&lbelow, nb);
  __syncthreads();
  if (threadIdx.x == 0 && lbelow) atomicAdd(&cntBelow[h], lbelow);
  const unsigned n = (lcnt < LCAP) ? lcnt : LCAP;
  if (threadIdx.x == 0) gbase = n ? atomicAdd(&ccnt[h], n) : 0u;
  __syncthreads();
  const unsigned gb = gbase;
  for (unsigned i = threadIdx.x; i < n; i += 512)
    if (gb + i < CAPC) mycand[gb + i] = lbuf[i];
}

// exact 9-bin histogram from the candidate list (wave-ballot, no per-item atomics)
__global__ __launch_bounds__(256) void hist9_from_cands(const unsigned* __restrict__ cand,
                                                        const unsigned* __restrict__ ccnt,
                                                        const unsigned* __restrict__ rangeLo,
                                                        unsigned* __restrict__ ghist9)
{
  const int hh = blockIdx.y;
  const int lane = threadIdx.x & 63;
  const unsigned lo = rangeLo[hh];
  unsigned n = ccnt[hh]; if (n > CAPC) n = CAPC;
  const unsigned* __restrict__ list = cand + (size_t)hh * CAPC;
  unsigned cnt[2*RBIN + 1];
#pragma unroll
  for (int b = 0; b <= 2*RBIN; ++b) cnt[b] = 0;
  for (unsigned i = blockIdx.x * 256 + threadIdx.x; i < n; i += 8 * 256) {
    const unsigned bin = (list[i] >> 18) - lo;
#pragma unroll
    for (int b = 0; b <= 2*RBIN; ++b) {
      const unsigned long long m = __ballot(bin == (unsigned)b);
      if (lane == 0) cnt[b] += (unsigned)__popcll(m);
    }
  }
  if (lane == 0) {
#pragma unroll
    for (int b = 0; b <= 2*RBIN; ++b)
      if (cnt[b]) atomicAdd(&ghist9[hh*16 + b], cnt[b]);
  }
}

// ---------------- scan over 9-bin range: exact binA/residA/binB/residB ----------------
__global__ __launch_bounds__(64) void scan9(const unsigned* __restrict__ ghist9,
                                            const unsigned* __restrict__ cntBelow,
                                            const unsigned* __restrict__ rangeLo,
                                            const unsigned* __restrict__ rangeHi,
                                            unsigned* __restrict__ ccnt,
                                            unsigned* __restrict__ state,
                                            unsigned* __restrict__ flag)
{
  const int hh = threadIdx.x;
  if (hh >= HH) return;
  const unsigned lo = rangeLo[hh], hi = rangeHi[hh];
  const int nbins = (int)(hi - lo + 1);
  const unsigned base = cntBelow[hh];
  unsigned ok = 0;
  unsigned binA = 0, residA = 0, binB = 0, residB = 0;
  if (K_A >= base) {
    unsigned k = K_A - base;
    unsigned cum = 0;
    for (int b = 0; b < nbins; ++b) {
      const unsigned c = ghist9[hh*16 + b];
      if (k < cum + c) {
        binA = lo + b;
        residA = k - cum;
        if (residA + 1 < c) { binB = binA; residB = residA + 1; ok = 1; }
        else {
          for (int b2 = b + 1; b2 < nbins; ++b2) {
            if (ghist9[hh*16 + b2]) { binB = lo + b2; residB = 0; ok = 1; break; }
          }
        }
        break;
      }
      cum += c;
    }
  }
  if (ccnt[hh] > CAPC) ok = 0;
  flag[hh] = ok;
  if (ok) {
    state[hh*4+0] = binA; state[hh*4+1] = residA;
    state[hh*4+2] = binB; state[hh*4+3] = residB;
  } else {
    ccnt[hh] = 0;   // fallback recollects cleanly
  }
}

// ---------------- fallback chain (early-exit when prediction held) ----------------
__global__ __launch_bounds__(512) void fb_scores_hist(const _Float16* __restrict__ Qh,
                                                      const _Float16* __restrict__ Ql,
                                                      const _Float16* __restrict__ Kh,
                                                      const _Float16* __restrict__ Kl,
                                                      const unsigned* __restrict__ flagArr,
                                                      unsigned* __restrict__ ghist)
{
  const int bn = blockIdx.x, bm = blockIdx.y, h = blockIdx.z;
  if (flagArr[h] != 0) return;
  const int wave = threadIdx.x >> 6, lane = threadIdx.x & 63;
  const int wr = wave >> 1, wc = wave & 1;
  const int m0 = bm * 256 + wr * 64;
  const int n0 = bn * 128 + wc * 64;
  const int lr = lane & 15;
  const int ko = lane >> 4;

  __shared__ unsigned lh[16384];   // 64 KB
  for (int i = threadIdx.x; i < 16384; i += 512) lh[i] = 0;
  __syncthreads();

  f32x4 acc[4][4];
#pragma unroll
  for (int i = 0; i < 4; ++i)
#pragma unroll
    for (int j = 0; j < 4; ++j) acc[i][j] = (f32x4){0.f, 0.f, 0.f, 0.f};

#pragma unroll
  for (int kk = 0; kk < 2; ++kk) {
    f16x8 aH[4], aL[4], bH[4], bL[4];
#pragma unroll
    for (int i = 0; i < 4; ++i) {
      const size_t aoff = (size_t)(m0 + i*16 + lr) * 1024 + h*64 + kk*32 + ko*8;
      aH[i] = *(const f16x8*)(Qh + aoff);
      aL[i] = *(const f16x8*)(Ql + aoff);
      const size_t boff = (size_t)(n0 + i*16 + lr) * 1024 + h*64 + kk*32 + ko*8;
      bH[i] = *(const f16x8*)(Kh + boff);
      bL[i] = *(const f16x8*)(Kl + boff);
    }
#pragma unroll
    for (int i = 0; i < 4; ++i)
#pragma unroll
      for (int j = 0; j < 4; ++j) {
        acc[i][j] = __builtin_amdgcn_mfma_f32_16x16x32_f16(aL[i], bL[j], acc[i][j], 0, 0, 0);
        acc[i][j] = __builtin_amdgcn_mfma_f32_16x16x32_f16(aH[i], bL[j], acc[i][j], 0, 0, 0);
        acc[i][j] = __builtin_amdgcn_mfma_f32_16x16x32_f16(aL[i], bH[j], acc[i][j], 0, 0, 0);
        acc[i][j] = __builtin_amdgcn_mfma_f32_16x16x32_f16(aH[i], bH[j], acc[i][j], 0, 0, 0);
      }
  }

#pragma unroll
  for (int i = 0; i < 4; ++i)
#pragma unroll
    for (int j = 0; j < 4; ++j)
#pragma unroll
      for (int r = 0; r < 4; ++r) {
        const float val = acc[i][j][r] * 0.125f;
        atomicAdd(&lh[sortkey(val) >> 18], 1u);
      }
  __syncthreads();
  unsigned* __restrict__ gh = ghist + (size_t)h * 16384;
  for (int i = threadIdx.x; i < 16384; i += 512) {
    const unsigned c = lh[i];
    if (c) atomicAdd(&gh[i], c);
  }
}

__global__ __launch_bounds__(256) void fb_scan14(const unsigned* __restrict__ ghist,
                                                 const unsigned* __restrict__ flagArr,
                                                 unsigned* __restrict__ state)
{
  const int hh = blockIdx.x;
  if (flagArr[hh] != 0) return;
  const int t = threadIdx.x;
  __shared__ unsigned part[256];
  __shared__ unsigned out[4];
  const unsigned* __restrict__ hb = ghist + (size_t)hh * 16384;
  unsigned s = 0;
  for (int j = 0; j < 64; ++j) s += hb[t*64 + j];
  part[t] = s;
  __syncthreads();
  if (t == 0) {
    unsigned run = 0;
    for (int i = 0; i < 256; ++i) { unsigned tmp = part[i]; part[i] = run; run += tmp; }
  }
  __syncthreads();
  const unsigned cum0 = part[t];
  if (K_A >= cum0 && K_A < cum0 + s) {
    unsigned c2 = cum0;
    for (int j = 0; j < 64; ++j) {
      const unsigned c = hb[t*64 + j];
      if (K_A < c2 + c) {
        const unsigned binA = t*64 + j;
        const unsigned residA = K_A - c2;
        unsigned binB, residB;
        if (residA + 1 < c) { binB = binA; residB = residA + 1; }
        else {
          unsigned bb = binA + 1;
          while (bb < 16384 && hb[bb] == 0) ++bb;
          if (bb >= 16384) bb = 16383;  // defensive
          binB = bb; residB = 0;
        }
        out[0] = binA; out[1] = residA; out[2] = binB; out[3] = residB;
        break;
      }
      c2 += c;
    }
  }
  __syncthreads();
  if (t < 4) state[hh*4 + t] = out[t];
}

__global__ __launch_bounds__(512) void fallback_compact(const _Float16* __restrict__ Qh,
                                                        const _Float16* __restrict__ Ql,
                                                        const _Float16* __restrict__ Kh,
                                                        const _Float16* __restrict__ Kl,
                                                        const unsigned* __restrict__ state,
                                                        const unsigned* __restrict__ flagArr,
                                                        unsigned* __restrict__ cand,
                                                        unsigned* __restrict__ ccnt)
{
  const int bn = blockIdx.x, bm = blockIdx.y, h = blockIdx.z;
  if (flagArr[h] != 0) return;
  const int wave = threadIdx.x >> 6, lane = threadIdx.x & 63;
  const int wr = wave >> 1, wc = wave & 1;
  const int m0 = bm * 256 + wr * 64;
  const int n0 = bn * 128 + wc * 64;
  const int lr = lane & 15;
  const int ko = lane >> 4;

  __shared__ unsigned lbuf[LCAP];
  __shared__ unsigned lcnt, gbase;
  if (threadIdx.x == 0) lcnt = 0;
  __syncthreads();
  const unsigned binA = state[h*4+0];
  const unsigned binB = state[h*4+2];
  unsigned* __restrict__ mycand = cand + (size_t)h * CAPC;

  f32x4 acc[4][4];
#pragma unroll
  for (int i = 0; i < 4; ++i)
#pragma unroll
    for (int j = 0; j < 4; ++j) acc[i][j] = (f32x4){0.f, 0.f, 0.f, 0.f};

#pragma unroll
  for (int kk = 0; kk < 2; ++kk) {
    f16x8 aH[4], aL[4], bH[4], bL[4];
#pragma unroll
    for (int i = 0; i < 4; ++i) {
      const size_t aoff = (size_t)(m0 + i*16 + lr) * 1024 + h*64 + kk*32 + ko*8;
      aH[i] = *(const f16x8*)(Qh + aoff);
      aL[i] = *(const f16x8*)(Ql + aoff);
      const size_t boff = (size_t)(n0 + i*16 + lr) * 1024 + h*64 + kk*32 + ko*8;
      bH[i] = *(const f16x8*)(Kh + boff);
      bL[i] = *(const f16x8*)(Kl + boff);
    }
#pragma unroll
    for (int i = 0; i < 4; ++i)
#pragma unroll
      for (int j = 0; j < 4; ++j) {
        acc[i][j] = __builtin_amdgcn_mfma_f32_16x16x32_f16(aL[i], bL[j], acc[i][j], 0, 0, 0);
        acc[i][j] = __builtin_amdgcn_mfma_f32_16x16x32_f16(aH[i], bL[j], acc[i][j], 0, 0, 0);
        acc[i][j] = __builtin_amdgcn_mfma_f32_16x16x32_f16(aL[i], bH[j], acc[i][j], 0, 0, 0);
        acc[i][j] = __builtin_amdgcn_mfma_f32_16x16x32_f16(aH[i], bH[j], acc[i][j], 0, 0, 0);
      }
  }

#pragma unroll
  for (int i = 0; i < 4; ++i)
#pragma unroll
    for (int j = 0; j < 4; ++j)
#pragma unroll
      for (int r = 0; r < 4; ++r) {
        const float val = acc[i][j][r] * 0.125f;
        const unsigned u = sortkey(val);
        const unsigned bin = u >> 18;
        if (bin == binA || bin == binB) {
          unsigned id = atomicAdd(&lcnt, 1u);
          if (id < LCAP) lbuf[id] = u;
          else { unsigned g = atomicAdd(&ccnt[h], 1u); if (g < CAPC) mycand[g] = u; }
        }
      }
  __syncthreads();
  const unsigned n = (lcnt < LCAP) ? lcnt : LCAP;
  if (threadIdx.x == 0) gbase = n ? atomicAdd(&ccnt[h], n) : 0u;
  __syncthreads();
  const unsigned gb = gbase;
  for (unsigned i = threadIdx.x; i < n; i += 512)
    if (gb + i < CAPC) mycand[gb + i] = lbuf[i];
}

// seed the parallel-final-select state after scan9/fallback resolved binA/binB
__global__ __launch_bounds__(64) void seed_fs(const unsigned* __restrict__ state,
                                              unsigned* __restrict__ sstate)
{
  const int t = threadIdx.x;
  if (t < HH * 4) sstate[t] = state[t];
}

// ---------------- parallel final select: 3 rounds of (hist over 32 blocks, scan) ----------------
__global__ __launch_bounds__(256) void fs_hist(const unsigned* __restrict__ cand,
                                               const unsigned* __restrict__ ccnt,
                                               const unsigned* __restrict__ sstate,
                                               unsigned* __restrict__ fhist,
                                               int s, int w)
{
  const int hh = blockIdx.y;
  const int t = threadIdx.x;
  const unsigned nb = 1u << w;
  __shared__ unsigned lh0[256], lh1[256];
  lh0[t] = 0; lh1[t] = 0;
  __syncthreads();
  const unsigned pfxA = sstate[hh*4+0];
  const unsigned pfxB = sstate[hh*4+2];
  unsigned n = ccnt[hh]; if (n > CAPC) n = CAPC;
  const unsigned* __restrict__ list = cand + (size_t)hh * CAPC;
  for (unsigned i = blockIdx.x * 256 + t; i < n; i += 32 * 256) {
    const unsigned u = list[i];
    if ((u >> (s + w)) == pfxA) atomicAdd(&lh0[(u >> s) & (nb - 1)], 1u);
    if ((u >> (s + w)) == pfxB) atomicAdd(&lh1[(u >> s) & (nb - 1)], 1u);
  }
  __syncthreads();
  if (t < (int)nb) {
    if (lh0[t]) atomicAdd(&fhist[hh*512 + t], lh0[t]);
    if (lh1[t]) atomicAdd(&fhist[hh*512 + 256 + t], lh1[t]);
  }
}

__global__ __launch_bounds__(256) void fs_scan(unsigned* __restrict__ fhist,
                                               unsigned* __restrict__ sstate,
                                               float* __restrict__ thr,
                                               int s, int w)
{
  const int hh = blockIdx.x;
  const int t = threadIdx.x;
  const unsigned nb = 1u << w;
  if (t == 0) {
    float vals[2];
    for (int tgt = 0; tgt < 2; ++tgt) {
      unsigned pfx = sstate[hh*4 + tgt*2];
      unsigned k   = sstate[hh*4 + tgt*2 + 1];
      const unsigned* hb = &fhist[hh*512 + tgt*256];
      unsigned cum = 0, b = 0;
      for (; b < nb; ++b) { const unsigned c = hb[b]; if (cum + c > k) break; cum += c; }
      if (b == nb) b = nb - 1;
      pfx = (pfx << w) | b;
      k -= cum;
      sstate[hh*4 + tgt*2]     = pfx;
      sstate[hh*4 + tgt*2 + 1] = k;
      if (s == 0) vals[tgt] = inv_sortkey(pfx);
    }
    if (s == 0) thr[hh] = vals[0] + QFRAC * (vals[1] - vals[0]);
  }
  __syncthreads();
  fhist[hh*512 + t] = 0;           // zero for next round
  fhist[hh*512 + 256 + t] = 0;
}

// ---------------- pass 3: flash softmax+PV, key-split over NSPL halves ----------------
__global__ __launch_bounds__(256) void flash_pv_sk(const _Float16* __restrict__ Qh,
                                                   const _Float16* __restrict__ Ql,
                                                   const _Float16* __restrict__ Kh,
                                                   const _Float16* __restrict__ Kl,
                                                   const _Float16* __restrict__ VtH,
                                                   const _Float16* __restrict__ VtL,
                                                   const float* __restrict__ thrArr,
                                                   float* __restrict__ pctx,
                                                   float* __restrict__ prs)
{
  const int bm = blockIdx.x;          // 0..31 -> rows bm*64
  const int h  = blockIdx.y;
  const int q  = blockIdx.z;          // 0..NSPL-1
  const int wave = threadIdx.x >> 6, lane = threadIdx.x & 63;
  const int lr = lane & 15;
  const int ko = lane >> 4;
  const int m0 = bm * 64;
  const float thr = thrArr[h];
  const int KTS = 16 / NSPL;

  __shared__ _Float16 Plds[64][136];  // pad 128->136
  __shared__ float rsLDS[64][4];

  // Q fragments are kt-invariant: hoist
  f16x8 qH[4][2], qL[4][2];
#pragma unroll
  for (int i = 0; i < 4; ++i)
#pragma unroll
    for (int kk = 0; kk < 2; ++kk) {
      const size_t aoff = (size_t)(m0 + i*16 + lr) * 1024 + h*64 + kk*32 + ko*8;
      qH[i][kk] = *(const f16x8*)(Qh + aoff);
      qL[i][kk] = *(const f16x8*)(Ql + aoff);
    }

  f32x4 oacc[4];
#pragma unroll
  for (int i = 0; i < 4; ++i) oacc[i] = (f32x4){0.f, 0.f, 0.f, 0.f};
  float rs[4][4];
#pragma unroll
  for (int i = 0; i < 4; ++i)
#pragma unroll
    for (int r = 0; r < 4; ++r) rs[i][r] = 0.f;

  const int d0 = wave * 16;   // PV: wave owns dims d0..d0+15

  for (int kt = q*KTS; kt < q*KTS + KTS; ++kt) {
    const int n0 = kt*128 + wave*32;   // S: wave owns keys n0..n0+31
    f32x4 sacc[4][2];
#pragma unroll
    for (int i = 0; i < 4; ++i)
#pragma unroll
      for (int j = 0; j < 2; ++j) sacc[i][j] = (f32x4){0.f, 0.f, 0.f, 0.f};

#pragma unroll
    for (int kk = 0; kk < 2; ++kk) {
      f16x8 bH[2], bL[2];
#pragma unroll
      for (int j = 0; j < 2; ++j) {
        const size_t boff = (size_t)(n0 + j*16 + lr) * 1024 + h*64 + kk*32 + ko*8;
        bH[j] = *(const f16x8*)(Kh + boff);
        bL[j] = *(const f16x8*)(Kl + boff);
      }
#pragma unroll
      for (int i = 0; i < 4; ++i)
#pragma unroll
        for (int j = 0; j < 2; ++j) {
          sacc[i][j] = __builtin_amdgcn_mfma_f32_16x16x32_f16(qL[i][kk], bL[j], sacc[i][j], 0, 0, 0);
          sacc[i][j] = __builtin_amdgcn_mfma_f32_16x16x32_f16(qH[i][kk], bL[j], sacc[i][j], 0, 0, 0);
          sacc[i][j] = __builtin_amdgcn_mfma_f32_16x16x32_f16(qL[i][kk], bH[j], sacc[i][j], 0, 0, 0);
          sacc[i][j] = __builtin_amdgcn_mfma_f32_16x16x32_f16(qH[i][kk], bH[j], sacc[i][j], 0, 0, 0);
        }
    }

    // mask + exp + P->LDS + rowsum partials
#pragma unroll
    for (int i = 0; i < 4; ++i)
#pragma unroll
      for (int j = 0; j < 2; ++j)
#pragma unroll
        for (int r = 0; r < 4; ++r) {
          const float val = sacc[i][j][r] * 0.125f;
          const float p = (val >= thr) ? __expf(val - thr - ESHIFT) : 0.f;
          rs[i][r] += p;
          Plds[i*16 + ko*4 + r][wave*32 + j*16 + lr] = (_Float16)p;
        }
    __syncthreads();

    // PV: oacc[i] over dims d0+lr, keys kt*128..+127
#pragma unroll
    for (int kk2 = 0; kk2 < 4; ++kk2) {
      f16x8 pa[4];
#pragma unroll
      for (int i = 0; i < 4; ++i)
        pa[i] = *(const f16x8*)&Plds[i*16 + lr][kk2*32 + ko*8];
      const size_t vo = (size_t)(h*64 + d0 + lr) * 2048 + kt*128 + kk2*32 + ko*8;
      const f16x8 vH = *(const f16x8*)(VtH + vo);
      const f16x8 vL = *(const f16x8*)(VtL + vo);
#pragma unroll
      for (int i = 0; i < 4; ++i) {
        oacc[i] = __builtin_amdgcn_mfma_f32_16x16x32_f16(pa[i], vL, oacc[i], 0, 0, 0);
        oacc[i] = __builtin_amdgcn_mfma_f32_16x16x32_f16(pa[i], vH, oacc[i], 0, 0, 0);
      }
    }
    __syncthreads();   // before next kt overwrites Plds
  }

  // rowsum: reduce across the 16 lanes of each ko-group, then across waves
#pragma unroll
  for (int i = 0; i < 4; ++i)
#pragma unroll
    for (int r = 0; r < 4; ++r) {
      float v = rs[i][r];
      v += __shfl_xor(v, 1); v += __shfl_xor(v, 2);
      v += __shfl_xor(v, 4); v += __shfl_xor(v, 8);
      rs[i][r] = v;
    }
  if (lr == 0) {
#pragma unroll
    for (int i = 0; i < 4; ++i)
#pragma unroll
      for (int r = 0; r < 4; ++r)
        rsLDS[i*16 + ko*4 + r][wave] = rs[i][r];
  }
  __syncthreads();

  // write partial rowsums
  if (wave == 0 && lr == 0) {
#pragma unroll
    for (int i = 0; i < 4; ++i)
#pragma unroll
      for (int r = 0; r < 4; ++r) {
        const int lrow = i*16 + ko*4 + r;
        prs[q*32768 + h*2048 + m0 + lrow] =
            rsLDS[lrow][0] + rsLDS[lrow][1] + rsLDS[lrow][2] + rsLDS[lrow][3];
      }
  }

  // store raw partial O
  float* __restrict__ pc = pctx + (size_t)q * PLANE;
#pragma unroll
  for (int i = 0; i < 4; ++i)
#pragma unroll
    for (int r = 0; r < 4; ++r) {
      const int lrow = i*16 + ko*4 + r;
      pc[(size_t)(m0 + lrow) * 1024 + h*64 + d0 + lr] = oacc[i][r];
    }
}

// ---------------- host ----------------
extern "C" void kernel_launch(void* const* d_in, const int* in_sizes, int n_in,
                              void* d_out, int out_size, void* d_ws, size_t ws_size,
                              hipStream_t stream)
{
  const float* x  = (const float*)d_in[0];
  const float* Wq = (const float*)d_in[1];
  const float* bq = (const float*)d_in[2];
  const float* Wk = (const float*)d_in[3];
  const float* bk = (const float*)d_in[4];
  const float* Wv = (const float*)d_in[5];
  const float* bv = (const float*)d_in[6];
  const float* Wo = (const float*)d_in[7];
  const float* bo = (const float*)d_in[8];
  float* out = (float*)d_out;
  char*  ws  = (char*)d_ws;

  const size_t MB = 1u << 20;
  _Float16* xh      = (_Float16*)(ws + 0*MB);
  _Float16* xl      = (_Float16*)(ws + 4*MB);
  _Float16* wplanes = (_Float16*)(ws + 8*MB);    // 8 x 2 MiB transposed W planes
  _Float16* Qh      = (_Float16*)(ws + 24*MB);
  _Float16* Ql      = (_Float16*)(ws + 28*MB);
  _Float16* Kh      = (_Float16*)(ws + 32*MB);
  _Float16* Kl      = (_Float16*)(ws + 36*MB);
  _Float16* VtH     = (_Float16*)(ws + 40*MB);   // [1024 dims][2048 rows]
  _Float16* VtL     = (_Float16*)(ws + 44*MB);
  _Float16* ctxh    = (_Float16*)(ws + 48*MB);
  _Float16* ctxl    = (_Float16*)(ws + 52*MB);
  const size_t base = 56*MB;
  unsigned* state    = (unsigned*)(ws + base);
  float*    thr      = (float*)(ws + base + 4096);
  unsigned* ccnt     = (unsigned*)(ws + base + 8192);
  unsigned* flag     = (unsigned*)(ws + base + 12288);
  unsigned* rangeLo  = (unsigned*)(ws + base + 16384);
  unsigned* rangeHi  = (unsigned*)(ws + base + 20480);
  unsigned* sstate   = (unsigned*)(ws + base + 24576);
  unsigned* fhist    = (unsigned*)(ws + base + 28672);  // HH*512*4 = 32 KiB
  unsigned* cntBelow = (unsigned*)(ws + base + 65536);
  unsigned* ghist9   = (unsigned*)(ws + base + 69632);  // HH*16 u32
  unsigned* ghist    = (unsigned*)(ws + 57*MB);   // 1 MiB (fallback only)
  unsigned* shist    = (unsigned*)(ws + 58*MB);   // 1 MiB
  unsigned* cand     = (unsigned*)(ws + 59*MB);   // HH * CAPC * 4 = 20 MiB
  float*    prs      = (float*)(ws + 80*MB);      // NSPL x 16 x 2048 f32
  float*    pbuf     = (float*)(ws + 81*MB);      // 6 x 8 MiB partials
  float*    pctx     = pbuf;                      // planes 0,1 (post combine_qk)
  float*    pO       = pbuf + (size_t)2 * PLANE;  // planes 2,3

  split_x<<<2048, 256, 0, stream>>>(x, xh, xl);
  split_wT<<<dim3(16, 16, 4), 256, 0, stream>>>(Wq, Wk, Wv, Wo, wplanes);
  gemm_qkv_part<<<dim3(8, 16, 6), 256, 0, stream>>>(xh, xl, wplanes, pbuf);
  combine_qk<<<dim3(2048, 2), 256, 0, stream>>>(pbuf, bq, bk, Qh, Ql, Kh, Kl);
  combine_vT<<<dim3(16, 32), 256, 0, stream>>>(pbuf, bv, VtH, VtL);

  init_sel<<<256, 256, 0, stream>>>(ghist, shist, ccnt, flag, fhist, cntBelow, ghist9);
  sample_hist<<<dim3(16, HH), 256, 0, stream>>>(Qh, Ql, Kh, Kl, shist);
  sample_scan<<<HH, 256, 0, stream>>>(shist, rangeLo, rangeHi);
  range_count<<<dim3(16, 8, HH), 512, 0, stream>>>(Qh, Ql, Kh, Kl, rangeLo, rangeHi,
                                                   cand, ccnt, cntBelow);
  hist9_from_cands<<<dim3(8, HH), 256, 0, stream>>>(cand, ccnt, rangeLo, ghist9);
  scan9<<<1, 64, 0, stream>>>(ghist9, cntBelow, rangeLo, rangeHi, ccnt, state, flag);
  // fallback chain (early-exit per head when prediction held)
  fb_scores_hist<<<dim3(16, 8, HH), 512, 0, stream>>>(Qh, Ql, Kh, Kl, flag, ghist);
  fb_scan14<<<HH, 256, 0, stream>>>(ghist, flag, state);
  fallback_compact<<<dim3(16, 8, HH), 512, 0, stream>>>(Qh, Ql, Kh, Kl, state, flag, cand, ccnt);
  seed_fs<<<1, 64, 0, stream>>>(state, sstate);
  // parallel final select: rounds (s,w) = (10,8), (2,8), (0,2)
  fs_hist<<<dim3(32, HH), 256, 0, stream>>>(cand, ccnt, sstate, fhist, 10, 8);
  fs_scan<<<HH, 256, 0, stream>>>(fhist, sstate, thr, 10, 8);
  fs_hist<<<dim3(32, HH), 256, 0, stream>>>(cand, ccnt, sstate, fhist, 2, 8);
  fs_scan<<<HH, 256, 0, stream>>>(fhist, sstate, thr, 2, 8);
  fs_hist<<<dim3(32, HH), 256, 0, stream>>>(cand, ccnt, sstate, fhist, 0, 2);
  fs_scan<<<HH, 256, 0, stream>>>(fhist, sstate, thr, 0, 2);

  flash_pv_sk<<<dim3(32, HH, NSPL), 256, 0, stream>>>(Qh, Ql, Kh, Kl, VtH, VtL, thr, pctx, prs);
  combine_ctx<<<2048, 256, 0, stream>>>(pctx, prs, ctxh, ctxl);

  gemm_o_part<<<dim3(8, 16, 2), 256, 0, stream>>>(ctxh, ctxl, wplanes, pO);
  combine_o<<<2048, 256, 0, stream>>>(pO, bo, out);
}

// Round 20
// 561.597 us; speedup vs baseline: 1.0506x; 1.0506x over previous
//
#include <hip/hip_runtime.h>
#include <math.h>

#define SS 2048
#define DD 1024
#define HH 16
#define CAPC 327680u  // candidate slots per head (range ~9 bins x ~16K/bin ~ 150K expected)
#define LCAP 2048     // per-block LDS candidate buffer (expected ~1200/block)
#define RBIN 4        // predicted-bin safety margin (sampling sigma ~0.16 bins)
#define NSPL 2        // flash key-split count (r17-proven; 4 regressed in r18)

// quantile index: floor(0.95*(S*S-1)) = floor(3984587.85)
#define K_A 3984587u
#define K_B 3984588u
#define QFRAC 0.85f
#define WSCALE 2048.0f      // W planes pre-scaled so lo-residuals stay normal fp16
#define WSCALE_INV (1.0f/2048.0f)
#define ESHIFT 4.0f         // exp(s - thr - ESHIFT): kept P in [e^-4, ~e^6] — fp16-safe
#define PLANE 2097152       // floats per 2048x1024 fp32 partial plane (8 MiB)
#define NSAMP_RANK 124518u  // floor(0.95 * 131072) — sample quantile rank

typedef _Float16 f16x8 __attribute__((ext_vector_type(8)));
typedef _Float16 f16x4 __attribute__((ext_vector_type(4)));
typedef float    f32x4 __attribute__((ext_vector_type(4)));

__device__ __forceinline__ unsigned sortkey(float f) {
  unsigned b = __float_as_uint(f);
  return (b & 0x80000000u) ? ~b : (b | 0x80000000u);
}
__device__ __forceinline__ float inv_sortkey(unsigned u) {
  unsigned b = (u & 0x80000000u) ? (u ^ 0x80000000u) : ~u;
  return __uint_as_float(b);
}

// ---------------- input splitting ----------------
__global__ __launch_bounds__(256) void split_x(const float* __restrict__ x,
                                               _Float16* __restrict__ xh,
                                               _Float16* __restrict__ xl)
{
  const int i = blockIdx.x * 256 + threadIdx.x;   // float4 index, 524288 total
  float4 v = ((const float4*)x)[i];
  float vv[4] = {v.x, v.y, v.z, v.w};
  f16x4 h, l;
#pragma unroll
  for (int j = 0; j < 4; ++j) {
    _Float16 hh = (_Float16)vv[j];
    h[j] = hh;
    l[j] = (_Float16)(vv[j] - (float)hh);
  }
  ((f16x4*)xh)[i] = h;
  ((f16x4*)xl)[i] = l;
}

// W -> transposed hi/lo fp16 planes WT[n][k], scaled by 2048 (keeps lo normal).
__global__ __launch_bounds__(256) void split_wT(const float* __restrict__ Wq,
                                                const float* __restrict__ Wk,
                                                const float* __restrict__ Wv,
                                                const float* __restrict__ Wo,
                                                _Float16* __restrict__ wplanes)
{
  const int z = blockIdx.z;
  const float* W = (z == 0) ? Wq : (z == 1) ? Wk : (z == 2) ? Wv : Wo;
  _Float16* WhT = wplanes + (size_t)(2*z)     * (1024*1024);
  _Float16* WlT = wplanes + (size_t)(2*z + 1) * (1024*1024);
  __shared__ float tile[64][65];
  const int t  = threadIdx.x;
  const int r  = t >> 2;         // 0..63
  const int c0 = (t & 3) * 16;   // 0/16/32/48
  const int k0 = blockIdx.y * 64;
  const int n0 = blockIdx.x * 64;
#pragma unroll
  for (int j = 0; j < 4; ++j) {
    float4 v = *(const float4*)&W[(size_t)(k0 + r) * 1024 + n0 + c0 + j*4];
    tile[r][c0+j*4+0] = v.x; tile[r][c0+j*4+1] = v.y;
    tile[r][c0+j*4+2] = v.z; tile[r][c0+j*4+3] = v.w;
  }
  __syncthreads();
  f16x8 h0, h1, l0, l1;
#pragma unroll
  for (int j = 0; j < 8; ++j) {
    float v = tile[c0 + j][r] * WSCALE;
    _Float16 h = (_Float16)v;
    h0[j] = h; l0[j] = (_Float16)(v - (float)h);
  }
#pragma unroll
  for (int j = 0; j < 8; ++j) {
    float v = tile[c0 + 8 + j][r] * WSCALE;
    _Float16 h = (_Float16)v;
    h1[j] = h; l1[j] = (_Float16)(v - (float)h);
  }
  const size_t o = (size_t)(n0 + r) * 1024 + k0 + c0;
  *(f16x8*)&WhT[o]     = h0;
  *(f16x8*)&WhT[o + 8] = h1;
  *(f16x8*)&WlT[o]     = l0;
  *(f16x8*)&WlT[o + 8] = l1;
}

// ---------------- split-K MFMA GEMM partial ----------------
__device__ __forceinline__ void gemm_mfma_part(const _Float16* __restrict__ Ah,
                                               const _Float16* __restrict__ Al,
                                               const _Float16* __restrict__ BhT,
                                               const _Float16* __restrict__ BlT,
                                               float* __restrict__ pout,
                                               int bm, int bn, int kh)
{
  const int wave = threadIdx.x >> 6, lane = threadIdx.x & 63;
  const int wr = wave >> 1, wc = wave & 1;
  const int m0 = bm * 128 + wr * 64;
  const int n0 = bn * 128 + wc * 64;
  const int lr = lane & 15;
  const int ko = lane >> 4;

  f32x4 acc[4][4];
#pragma unroll
  for (int i = 0; i < 4; ++i)
#pragma unroll
    for (int j = 0; j < 4; ++j) acc[i][j] = (f32x4){0.f, 0.f, 0.f, 0.f};

  for (int kk = kh*16; kk < kh*16 + 16; ++kk) {
    const int kof = kk*32 + ko*8;
    f16x8 aH[4], aL[4], bH[4], bL[4];
#pragma unroll
    for (int i = 0; i < 4; ++i) {
      const size_t aoff = (size_t)(m0 + i*16 + lr) * 1024 + kof;
      aH[i] = *(const f16x8*)(Ah + aoff);
      aL[i] = *(const f16x8*)(Al + aoff);
      const size_t boff = (size_t)(n0 + i*16 + lr) * 1024 + kof;
      bH[i] = *(const f16x8*)(BhT + boff);
      bL[i] = *(const f16x8*)(BlT + boff);
    }
#pragma unroll
    for (int i = 0; i < 4; ++i)
#pragma unroll
      for (int j = 0; j < 4; ++j) {
        acc[i][j] = __builtin_amdgcn_mfma_f32_16x16x32_f16(aL[i], bL[j], acc[i][j], 0, 0, 0);
        acc[i][j] = __builtin_amdgcn_mfma_f32_16x16x32_f16(aH[i], bL[j], acc[i][j], 0, 0, 0);
        acc[i][j] = __builtin_amdgcn_mfma_f32_16x16x32_f16(aL[i], bH[j], acc[i][j], 0, 0, 0);
        acc[i][j] = __builtin_amdgcn_mfma_f32_16x16x32_f16(aH[i], bH[j], acc[i][j], 0, 0, 0);
      }
  }

#pragma unroll
  for (int i = 0; i < 4; ++i)
#pragma unroll
    for (int j = 0; j < 4; ++j)
#pragma unroll
      for (int r = 0; r < 4; ++r) {
        const int row = m0 + i*16 + ko*4 + r;
        const int col = n0 + j*16 + lr;
        pout[(size_t)row * 1024 + col] = acc[i][j][r];
      }
}

__global__ __launch_bounds__(256) void gemm_qkv_part(const _Float16* __restrict__ xh,
                                                     const _Float16* __restrict__ xl,
                                                     const _Float16* __restrict__ wplanes,
                                                     float* __restrict__ pbuf)
{
  const int z = blockIdx.z;           // 0..5: gemm_id*2 + khalf
  const int g = z >> 1, kh = z & 1;
  const _Float16* BhT = wplanes + (size_t)(2*g)     * (1024*1024);
  const _Float16* BlT = wplanes + (size_t)(2*g + 1) * (1024*1024);
  gemm_mfma_part(xh, xl, BhT, BlT, pbuf + (size_t)z * PLANE,
                 blockIdx.y, blockIdx.x, kh);
}

__global__ __launch_bounds__(256) void gemm_o_part(const _Float16* __restrict__ ctxh,
                                                   const _Float16* __restrict__ ctxl,
                                                   const _Float16* __restrict__ wplanes,
                                                   float* __restrict__ pO)
{
  const int kh = blockIdx.z;          // 0..1
  gemm_mfma_part(ctxh, ctxl,
                 wplanes + (size_t)6 * (1024*1024),
                 wplanes + (size_t)7 * (1024*1024),
                 pO + (size_t)kh * PLANE, blockIdx.y, blockIdx.x, kh);
}

// ---------------- combine kernels ----------------
__global__ __launch_bounds__(256) void combine_qk(const float* __restrict__ pbuf,
                                                  const float* __restrict__ bq,
                                                  const float* __restrict__ bk,
                                                  _Float16* __restrict__ Qh,
                                                  _Float16* __restrict__ Ql,
                                                  _Float16* __restrict__ Kh,
                                                  _Float16* __restrict__ Kl)
{
  const int which = blockIdx.y;       // 0=Q, 1=K
  const float* p0 = pbuf + (size_t)(which*2)     * PLANE;
  const float* p1 = pbuf + (size_t)(which*2 + 1) * PLANE;
  const float* bias = which ? bk : bq;
  _Float16* Oh = which ? Kh : Qh;
  _Float16* Ol = which ? Kl : Ql;
  const int i = blockIdx.x * 256 + threadIdx.x;   // f4 index, 524288
  const int coloff = (i & 255) * 4;
  float4 a = ((const float4*)p0)[i];
  float4 b = ((const float4*)p1)[i];
  float av[4] = {a.x, a.y, a.z, a.w};
  float bv[4] = {b.x, b.y, b.z, b.w};
  f16x4 h, l;
#pragma unroll
  for (int j = 0; j < 4; ++j) {
    const float val = (av[j] + bv[j]) * WSCALE_INV + bias[coloff + j];
    _Float16 hh = (_Float16)val;
    h[j] = hh;
    l[j] = (_Float16)(val - (float)hh);
  }
  ((f16x4*)Oh)[i] = h;
  ((f16x4*)Ol)[i] = l;
}

// V: combine + transpose to Vt[dim][row] hi/lo planes (LDS 64x64 tile).
__global__ __launch_bounds__(256) void combine_vT(const float* __restrict__ pbuf,
                                                  const float* __restrict__ bv,
                                                  _Float16* __restrict__ VtH,
                                                  _Float16* __restrict__ VtL)
{
  const float* p0 = pbuf + (size_t)4 * PLANE;
  const float* p1 = pbuf + (size_t)5 * PLANE;
  __shared__ float tile[64][65];
  const int t  = threadIdx.x;
  const int d0 = blockIdx.x * 64;     // dim tile
  const int m0 = blockIdx.y * 64;     // row tile
  {
    const int r  = t >> 2;            // row 0..63
    const int c0 = (t & 3) * 16;
#pragma unroll
    for (int j = 0; j < 4; ++j) {
      const size_t o = (size_t)(m0 + r) * 1024 + d0 + c0 + j*4;
      float4 a = *(const float4*)(p0 + o);
      float4 b = *(const float4*)(p1 + o);
      tile[r][c0+j*4+0] = (a.x + b.x) * WSCALE_INV + bv[d0 + c0 + j*4 + 0];
      tile[r][c0+j*4+1] = (a.y + b.y) * WSCALE_INV + bv[d0 + c0 + j*4 + 1];
      tile[r][c0+j*4+2] = (a.z + b.z) * WSCALE_INV + bv[d0 + c0 + j*4 + 2];
      tile[r][c0+j*4+3] = (a.w + b.w) * WSCALE_INV + bv[d0 + c0 + j*4 + 3];
    }
  }
  __syncthreads();
  {
    const int d  = t >> 2;            // dim 0..63
    const int rg = (t & 3) * 16;      // row group
#pragma unroll
    for (int j = 0; j < 4; ++j) {
      f16x4 hv, lv;
#pragma unroll
      for (int r = 0; r < 4; ++r) {
        const float val = tile[rg + j*4 + r][d];
        _Float16 h = (_Float16)val;
        hv[r] = h; lv[r] = (_Float16)(val - (float)h);
      }
      const size_t o = (size_t)(d0 + d) * 2048 + m0 + rg + j*4;
      *(f16x4*)&VtH[o] = hv;
      *(f16x4*)&VtL[o] = lv;
    }
  }
}

__global__ __launch_bounds__(256) void combine_o(const float* __restrict__ pO,
                                                 const float* __restrict__ bo,
                                                 float* __restrict__ out)
{
  const float* p0 = pO;
  const float* p1 = pO + (size_t)1 * PLANE;
  const int i = blockIdx.x * 256 + threadIdx.x;
  const int coloff = (i & 255) * 4;
  float4 a = ((const float4*)p0)[i];
  float4 b = ((const float4*)p1)[i];
  float4 o;
  o.x = (a.x + b.x) * WSCALE_INV + bo[coloff + 0];
  o.y = (a.y + b.y) * WSCALE_INV + bo[coloff + 1];
  o.z = (a.z + b.z) * WSCALE_INV + bo[coloff + 2];
  o.w = (a.w + b.w) * WSCALE_INV + bo[coloff + 3];
  ((float4*)out)[i] = o;
}

// ctx: sum of NSPL partials / sum of NSPL rowsums, then fp16 hi/lo split.
__global__ __launch_bounds__(256) void combine_ctx(const float* __restrict__ pctx,
                                                   const float* __restrict__ prs,
                                                   _Float16* __restrict__ ctxh,
                                                   _Float16* __restrict__ ctxl)
{
  const int i = blockIdx.x * 256 + threadIdx.x;   // f4 index, 524288
  const int row = i >> 8;
  const int cd  = (i & 255) * 4;
  const int h   = cd >> 6;
  float rs = 0.f;
#pragma unroll
  for (int q = 0; q < NSPL; ++q) rs += prs[q*32768 + h*2048 + row];
  float av[4] = {0.f, 0.f, 0.f, 0.f};
#pragma unroll
  for (int q = 0; q < NSPL; ++q) {
    float4 a = ((const float4*)(pctx + (size_t)q * PLANE))[i];
    av[0] += a.x; av[1] += a.y; av[2] += a.z; av[3] += a.w;
  }
  f16x4 hh, ll;
#pragma unroll
  for (int j = 0; j < 4; ++j) {
    const float val = av[j] / rs;
    _Float16 hv = (_Float16)val;
    hh[j] = hv;
    ll[j] = (_Float16)(val - (float)hv);
  }
  ((f16x4*)ctxh)[i] = hh;
  ((f16x4*)ctxl)[i] = ll;
}

// ---------------- selection init ----------------
__global__ __launch_bounds__(256) void init_sel(unsigned* __restrict__ ghist,
                                                unsigned* __restrict__ shist,
                                                unsigned* __restrict__ ccnt,
                                                unsigned* __restrict__ flag,
                                                unsigned* __restrict__ fhist,
                                                unsigned* __restrict__ cntBelow,
                                                unsigned* __restrict__ ghist9)
{
  int i = blockIdx.x * 256 + threadIdx.x;
  for (; i < HH * 16384; i += gridDim.x * 256) { ghist[i] = 0; shist[i] = 0; }
  const int j = blockIdx.x * 256 + threadIdx.x;
  if (j < HH * 512) fhist[j] = 0;
  if (j < HH * 16) ghist9[j] = 0;
  if (blockIdx.x == 0 && threadIdx.x < HH) {
    ccnt[threadIdx.x] = 0; flag[threadIdx.x] = 0; cntBelow[threadIdx.x] = 0;
  }
}

// ---------------- sampling pass: 64 of 2048 query rows (stride 32) ----------------
__global__ __launch_bounds__(256) void sample_hist(const _Float16* __restrict__ Qh,
                                                   const _Float16* __restrict__ Ql,
                                                   const _Float16* __restrict__ Kh,
                                                   const _Float16* __restrict__ Kl,
                                                   unsigned* __restrict__ shist)
{
  const int kb = blockIdx.x, h = blockIdx.y;
  const int wave = threadIdx.x >> 6, lane = threadIdx.x & 63;
  const int lr = lane & 15, ko = lane >> 4;
  const int n0 = kb*128 + wave*32;

  __shared__ unsigned lh[16384];   // 64 KB
  for (int i = threadIdx.x; i < 16384; i += 256) lh[i] = 0;
  __syncthreads();

  f32x4 acc[4][2];
#pragma unroll
  for (int i = 0; i < 4; ++i)
#pragma unroll
    for (int j = 0; j < 2; ++j) acc[i][j] = (f32x4){0.f, 0.f, 0.f, 0.f};

#pragma unroll
  for (int kk = 0; kk < 2; ++kk) {
    f16x8 aH[4], aL[4], bH[2], bL[2];
#pragma unroll
    for (int i = 0; i < 4; ++i) {
      const size_t aoff = (size_t)((i*16 + lr) * 32) * 1024 + h*64 + kk*32 + ko*8;
      aH[i] = *(const f16x8*)(Qh + aoff);
      aL[i] = *(const f16x8*)(Ql + aoff);
    }
#pragma unroll
    for (int j = 0; j < 2; ++j) {
      const size_t boff = (size_t)(n0 + j*16 + lr) * 1024 + h*64 + kk*32 + ko*8;
      bH[j] = *(const f16x8*)(Kh + boff);
      bL[j] = *(const f16x8*)(Kl + boff);
    }
#pragma unroll
    for (int i = 0; i < 4; ++i)
#pragma unroll
      for (int j = 0; j < 2; ++j) {
        acc[i][j] = __builtin_amdgcn_mfma_f32_16x16x32_f16(aL[i], bL[j], acc[i][j], 0, 0, 0);
        acc[i][j] = __builtin_amdgcn_mfma_f32_16x16x32_f16(aH[i], bL[j], acc[i][j], 0, 0, 0);
        acc[i][j] = __builtin_amdgcn_mfma_f32_16x16x32_f16(aL[i], bH[j], acc[i][j], 0, 0, 0);
        acc[i][j] = __builtin_amdgcn_mfma_f32_16x16x32_f16(aH[i], bH[j], acc[i][j], 0, 0, 0);
      }
  }

#pragma unroll
  for (int i = 0; i < 4; ++i)
#pragma unroll
    for (int j = 0; j < 2; ++j)
#pragma unroll
      for (int r = 0; r < 4; ++r) {
        const float val = acc[i][j][r] * 0.125f;
        atomicAdd(&lh[sortkey(val) >> 18], 1u);
      }
  __syncthreads();
  unsigned* __restrict__ gh = shist + (size_t)h * 16384;
  for (int i = threadIdx.x; i < 16384; i += 256) {
    const unsigned c = lh[i];
    if (c) atomicAdd(&gh[i], c);
  }
}

// find sample-quantile bin; emit conservative range [bin-RBIN, bin+RBIN]
__global__ __launch_bounds__(256) void sample_scan(const unsigned* __restrict__ shist,
                                                   unsigned* __restrict__ rangeLo,
                                                   unsigned* __restrict__ rangeHi)
{
  const int hh = blockIdx.x;
  const int t = threadIdx.x;
  __shared__ unsigned part[256];
  __shared__ unsigned outb;
  if (t == 0) outb = 8192u;  // defensive default
  const unsigned* __restrict__ hb = shist + (size_t)hh * 16384;
  unsigned s = 0;
  for (int j = 0; j < 64; ++j) s += hb[t*64 + j];
  part[t] = s;
  __syncthreads();
  if (t == 0) {
    unsigned run = 0;
    for (int i = 0; i < 256; ++i) { unsigned tmp = part[i]; part[i] = run; run += tmp; }
  }
  __syncthreads();
  const unsigned cum0 = part[t];
  if (NSAMP_RANK >= cum0 && NSAMP_RANK < cum0 + s) {
    unsigned c2 = cum0;
    for (int j = 0; j < 64; ++j) {
      const unsigned c = hb[t*64 + j];
      if (NSAMP_RANK < c2 + c) { outb = t*64 + j; break; }
      c2 += c;
    }
  }
  __syncthreads();
  if (t == 0) {
    const int b = (int)outb;
    rangeLo[hh] = (unsigned)((b - RBIN < 0) ? 0 : b - RBIN);
    rangeHi[hh] = (unsigned)((b + RBIN > 16383) ? 16383 : b + RBIN);
  }
}

// ---------------- pass 1: count-below + range compaction (r18-proven variant) ----------------
// Per score: sortkey + bin compares; below-count in registers (wave-reduced);
// per-item lcnt LDS push for the ~3.5% in-range. Best measured: ~169us (r18).
__global__ __launch_bounds__(512) void range_count(const _Float16* __restrict__ Qh,
                                                   const _Float16* __restrict__ Ql,
                                                   const _Float16* __restrict__ Kh,
                                                   const _Float16* __restrict__ Kl,
                                                   const unsigned* __restrict__ rangeLo,
                                                   const unsigned* __restrict__ rangeHi,
                                                   unsigned* __restrict__ cand,
                                                   unsigned* __restrict__ ccnt,
                                                   unsigned* __restrict__ cntBelow)
{
  const int bn = blockIdx.x, bm = blockIdx.y, h = blockIdx.z;
  const int wave = threadIdx.x >> 6, lane = threadIdx.x & 63;
  const int wr = wave >> 1, wc = wave & 1;
  const int m0 = bm * 256 + wr * 64;
  const int n0 = bn * 128 + wc * 64;
  const int lr = lane & 15;
  const int ko = lane >> 4;
  const unsigned lo = rangeLo[h], hi = rangeHi[h];
  unsigned* __restrict__ mycand = cand + (size_t)h * CAPC;

  __shared__ unsigned lbuf[LCAP];  // 8 KB
  __shared__ unsigned lcnt, gbase, lbelow;
  if (threadIdx.x == 0) { lcnt = 0; lbelow = 0; }
  __syncthreads();

  f32x4 acc[4][4];
#pragma unroll
  for (int i = 0; i < 4; ++i)
#pragma unroll
    for (int j = 0; j < 4; ++j) acc[i][j] = (f32x4){0.f, 0.f, 0.f, 0.f};

#pragma unroll
  for (int kk = 0; kk < 2; ++kk) {
    f16x8 aH[4], aL[4], bH[4], bL[4];
#pragma unroll
    for (int i = 0; i < 4; ++i) {
      const size_t aoff = (size_t)(m0 + i*16 + lr) * 1024 + h*64 + kk*32 + ko*8;
      aH[i] = *(const f16x8*)(Qh + aoff);
      aL[i] = *(const f16x8*)(Ql + aoff);
      const size_t boff = (size_t)(n0 + i*16 + lr) * 1024 + h*64 + kk*32 + ko*8;
      bH[i] = *(const f16x8*)(Kh + boff);
      bL[i] = *(const f16x8*)(Kl + boff);
    }
#pragma unroll
    for (int i = 0; i < 4; ++i)
#pragma unroll
      for (int j = 0; j < 4; ++j) {
        acc[i][j] = __builtin_amdgcn_mfma_f32_16x16x32_f16(aL[i], bL[j], acc[i][j], 0, 0, 0);
        acc[i][j] = __builtin_amdgcn_mfma_f32_16x16x32_f16(aH[i], bL[j], acc[i][j], 0, 0, 0);
        acc[i][j] = __builtin_amdgcn_mfma_f32_16x16x32_f16(aL[i], bH[j], acc[i][j], 0, 0, 0);
        acc[i][j] = __builtin_amdgcn_mfma_f32_16x16x32_f16(aH[i], bH[j], acc[i][j], 0, 0, 0);
      }
  }

  unsigned nb = 0;
#pragma unroll
  for (int i = 0; i < 4; ++i)
#pragma unroll
    for (int j = 0; j < 4; ++j)
#pragma unroll
      for (int r = 0; r < 4; ++r) {
        const float val = acc[i][j][r] * 0.125f;
        const unsigned u = sortkey(val);
        const unsigned bin = u >> 18;
        nb += (bin < lo) ? 1u : 0u;
        if (bin >= lo && bin <= hi) {
          unsigned id = atomicAdd(&lcnt, 1u);
          if (id < LCAP) lbuf[id] = u;
          else { unsigned g = atomicAdd(&ccnt[h], 1u); if (g < CAPC) mycand[g] = u; }
        }
      }
  // wave-reduce below-count, one LDS atomic per wave
  nb += __shfl_xor(nb, 1);  nb += __shfl_xor(nb, 2);
  nb += __shfl_xor(nb, 4);  nb += __shfl_xor(nb, 8);
  nb += __shfl_xor(nb, 16); nb += __shfl_xor(nb, 32);
  if (lane == 0) atomicAdd(&lbelow, nb);
  __syncthreads();
  if (threadIdx.x == 0 && lbelow) atomicAdd(&cntBelow[h], lbelow);
  const unsigned n = (lcnt < LCAP) ? lcnt : LCAP;
  if (threadIdx.x == 0) gbase = n ? atomicAdd(&ccnt[h], n) : 0u;
  __syncthreads();
  const unsigned gb = gbase;
  for (unsigned i = threadIdx.x; i < n; i += 512)
    if (gb + i < CAPC) mycand[gb + i] = lbuf[i];
}

// exact 9-bin histogram from the candidate list (wave-ballot, no per-item atomics)
__global__ __launch_bounds__(256) void hist9_from_cands(const unsigned* __restrict__ cand,
                                                        const unsigned* __restrict__ ccnt,
                                                        const unsigned* __restrict__ rangeLo,
                                                        unsigned* __restrict__ ghist9)
{
  const int hh = blockIdx.y;
  const int lane = threadIdx.x & 63;
  const unsigned lo = rangeLo[hh];
  unsigned n = ccnt[hh]; if (n > CAPC) n = CAPC;
  const unsigned* __restrict__ list = cand + (size_t)hh * CAPC;
  unsigned cnt[2*RBIN + 1];
#pragma unroll
  for (int b = 0; b <= 2*RBIN; ++b) cnt[b] = 0;
  for (unsigned i = blockIdx.x * 256 + threadIdx.x; i < n; i += 8 * 256) {
    const unsigned bin = (list[i] >> 18) - lo;
#pragma unroll
    for (int b = 0; b <= 2*RBIN; ++b) {
      const unsigned long long m = __ballot(bin == (unsigned)b);
      if (lane == 0) cnt[b] += (unsigned)__popcll(m);
    }
  }
  if (lane == 0) {
#pragma unroll
    for (int b = 0; b <= 2*RBIN; ++b)
      if (cnt[b]) atomicAdd(&ghist9[hh*16 + b], cnt[b]);
  }
}

// ---------------- scan over 9-bin range: exact binA/residA/binB/residB ----------------
__global__ __launch_bounds__(64) void scan9(const unsigned* __restrict__ ghist9,
                                            const unsigned* __restrict__ cntBelow,
                                            const unsigned* __restrict__ rangeLo,
                                            const unsigned* __restrict__ rangeHi,
                                            unsigned* __restrict__ ccnt,
                                            unsigned* __restrict__ state,
                                            unsigned* __restrict__ flag)
{
  const int hh = threadIdx.x;
  if (hh >= HH) return;
  const unsigned lo = rangeLo[hh], hi = rangeHi[hh];
  const int nbins = (int)(hi - lo + 1);
  const unsigned base = cntBelow[hh];
  unsigned ok = 0;
  unsigned binA = 0, residA = 0, binB = 0, residB = 0;
  if (K_A >= base) {
    unsigned k = K_A - base;
    unsigned cum = 0;
    for (int b = 0; b < nbins; ++b) {
      const unsigned c = ghist9[hh*16 + b];
      if (k < cum + c) {
        binA = lo + b;
        residA = k - cum;
        if (residA + 1 < c) { binB = binA; residB = residA + 1; ok = 1; }
        else {
          for (int b2 = b + 1; b2 < nbins; ++b2) {
            if (ghist9[hh*16 + b2]) { binB = lo + b2; residB = 0; ok = 1; break; }
          }
        }
        break;
      }
      cum += c;
    }
  }
  if (ccnt[hh] > CAPC) ok = 0;
  flag[hh] = ok;
  if (ok) {
    state[hh*4+0] = binA; state[hh*4+1] = residA;
    state[hh*4+2] = binB; state[hh*4+3] = residB;
  } else {
    ccnt[hh] = 0;   // fallback recollects cleanly
  }
}

// ---------------- fallback chain (early-exit when prediction held) ----------------
__global__ __launch_bounds__(512) void fb_scores_hist(const _Float16* __restrict__ Qh,
                                                      const _Float16* __restrict__ Ql,
                                                      const _Float16* __restrict__ Kh,
                                                      const _Float16* __restrict__ Kl,
                                                      const unsigned* __restrict__ flagArr,
                                                      unsigned* __restrict__ ghist)
{
  const int bn = blockIdx.x, bm = blockIdx.y, h = blockIdx.z;
  if (flagArr[h] != 0) return;
  const int wave = threadIdx.x >> 6, lane = threadIdx.x & 63;
  const int wr = wave >> 1, wc = wave & 1;
  const int m0 = bm * 256 + wr * 64;
  const int n0 = bn * 128 + wc * 64;
  const int lr = lane & 15;
  const int ko = lane >> 4;

  __shared__ unsigned lh[16384];   // 64 KB
  for (int i = threadIdx.x; i < 16384; i += 512) lh[i] = 0;
  __syncthreads();

  f32x4 acc[4][4];
#pragma unroll
  for (int i = 0; i < 4; ++i)
#pragma unroll
    for (int j = 0; j < 4; ++j) acc[i][j] = (f32x4){0.f, 0.f, 0.f, 0.f};

#pragma unroll
  for (int kk = 0; kk < 2; ++kk) {
    f16x8 aH[4], aL[4], bH[4], bL[4];
#pragma unroll
    for (int i = 0; i < 4; ++i) {
      const size_t aoff = (size_t)(m0 + i*16 + lr) * 1024 + h*64 + kk*32 + ko*8;
      aH[i] = *(const f16x8*)(Qh + aoff);
      aL[i] = *(const f16x8*)(Ql + aoff);
      const size_t boff = (size_t)(n0 + i*16 + lr) * 1024 + h*64 + kk*32 + ko*8;
      bH[i] = *(const f16x8*)(Kh + boff);
      bL[i] = *(const f16x8*)(Kl + boff);
    }
#pragma unroll
    for (int i = 0; i < 4; ++i)
#pragma unroll
      for (int j = 0; j < 4; ++j) {
        acc[i][j] = __builtin_amdgcn_mfma_f32_16x16x32_f16(aL[i], bL[j], acc[i][j], 0, 0, 0);
        acc[i][j] = __builtin_amdgcn_mfma_f32_16x16x32_f16(aH[i], bL[j], acc[i][j], 0, 0, 0);
        acc[i][j] = __builtin_amdgcn_mfma_f32_16x16x32_f16(aL[i], bH[j], acc[i][j], 0, 0, 0);
        acc[i][j] = __builtin_amdgcn_mfma_f32_16x16x32_f16(aH[i], bH[j], acc[i][j], 0, 0, 0);
      }
  }

#pragma unroll
  for (int i = 0; i < 4; ++i)
#pragma unroll
    for (int j = 0; j < 4; ++j)
#pragma unroll
      for (int r = 0; r < 4; ++r) {
        const float val = acc[i][j][r] * 0.125f;
        atomicAdd(&lh[sortkey(val) >> 18], 1u);
      }
  __syncthreads();
  unsigned* __restrict__ gh = ghist + (size_t)h * 16384;
  for (int i = threadIdx.x; i < 16384; i += 512) {
    const unsigned c = lh[i];
    if (c) atomicAdd(&gh[i], c);
  }
}

__global__ __launch_bounds__(256) void fb_scan14(const unsigned* __restrict__ ghist,
                                                 const unsigned* __restrict__ flagArr,
                                                 unsigned* __restrict__ state)
{
  const int hh = blockIdx.x;
  if (flagArr[hh] != 0) return;
  const int t = threadIdx.x;
  __shared__ unsigned part[256];
  __shared__ unsigned out[4];
  const unsigned* __restrict__ hb = ghist + (size_t)hh * 16384;
  unsigned s = 0;
  for (int j = 0; j < 64; ++j) s += hb[t*64 + j];
  part[t] = s;
  __syncthreads();
  if (t == 0) {
    unsigned run = 0;
    for (int i = 0; i < 256; ++i) { unsigned tmp = part[i]; part[i] = run; run += tmp; }
  }
  __syncthreads();
  const unsigned cum0 = part[t];
  if (K_A >= cum0 && K_A < cum0 + s) {
    unsigned c2 = cum0;
    for (int j = 0; j < 64; ++j) {
      const unsigned c = hb[t*64 + j];
      if (K_A < c2 + c) {
        const unsigned binA = t*64 + j;
        const unsigned residA = K_A - c2;
        unsigned binB, residB;
        if (residA + 1 < c) { binB = binA; residB = residA + 1; }
        else {
          unsigned bb = binA + 1;
          while (bb < 16384 && hb[bb] == 0) ++bb;
          if (bb >= 16384) bb = 16383;  // defensive
          binB = bb; residB = 0;
        }
        out[0] = binA; out[1] = residA; out[2] = binB; out[3] = residB;
        break;
      }
      c2 += c;
    }
  }
  __syncthreads();
  if (t < 4) state[hh*4 + t] = out[t];
}

__global__ __launch_bounds__(512) void fallback_compact(const _Float16* __restrict__ Qh,
                                                        const _Float16* __restrict__ Ql,
                                                        const _Float16* __restrict__ Kh,
                                                        const _Float16* __restrict__ Kl,
                                                        const unsigned* __restrict__ state,
                                                        const unsigned* __restrict__ flagArr,
                                                        unsigned* __restrict__ cand,
                                                        unsigned* __restrict__ ccnt)
{
  const int bn = blockIdx.x, bm = blockIdx.y, h = blockIdx.z;
  if (flagArr[h] != 0) return;
  const int wave = threadIdx.x >> 6, lane = threadIdx.x & 63;
  const int wr = wave >> 1, wc = wave & 1;
  const int m0 = bm * 256 + wr * 64;
  const int n0 = bn * 128 + wc * 64;
  const int lr = lane & 15;
  const int ko = lane >> 4;

  __shared__ unsigned lbuf[LCAP];
  __shared__ unsigned lcnt, gbase;
  if (threadIdx.x == 0) lcnt = 0;
  __syncthreads();
  const unsigned binA = state[h*4+0];
  const unsigned binB = state[h*4+2];
  unsigned* __restrict__ mycand = cand + (size_t)h * CAPC;

  f32x4 acc[4][4];
#pragma unroll
  for (int i = 0; i < 4; ++i)
#pragma unroll
    for (int j = 0; j < 4; ++j) acc[i][j] = (f32x4){0.f, 0.f, 0.f, 0.f};

#pragma unroll
  for (int kk = 0; kk < 2; ++kk) {
    f16x8 aH[4], aL[4], bH[4], bL[4];
#pragma unroll
    for (int i = 0; i < 4; ++i) {
      const size_t aoff = (size_t)(m0 + i*16 + lr) * 1024 + h*64 + kk*32 + ko*8;
      aH[i] = *(const f16x8*)(Qh + aoff);
      aL[i] = *(const f16x8*)(Ql + aoff);
      const size_t boff = (size_t)(n0 + i*16 + lr) * 1024 + h*64 + kk*32 + ko*8;
      bH[i] = *(const f16x8*)(Kh + boff);
      bL[i] = *(const f16x8*)(Kl + boff);
    }
#pragma unroll
    for (int i = 0; i < 4; ++i)
#pragma unroll
      for (int j = 0; j < 4; ++j) {
        acc[i][j] = __builtin_amdgcn_mfma_f32_16x16x32_f16(aL[i], bL[j], acc[i][j], 0, 0, 0);
        acc[i][j] = __builtin_amdgcn_mfma_f32_16x16x32_f16(aH[i], bL[j], acc[i][j], 0, 0, 0);
        acc[i][j] = __builtin_amdgcn_mfma_f32_16x16x32_f16(aL[i], bH[j], acc[i][j], 0, 0, 0);
        acc[i][j] = __builtin_amdgcn_mfma_f32_16x16x32_f16(aH[i], bH[j], acc[i][j], 0, 0, 0);
      }
  }

#pragma unroll
  for (int i = 0; i < 4; ++i)
#pragma unroll
    for (int j = 0; j < 4; ++j)
#pragma unroll
      for (int r = 0; r < 4; ++r) {
        const float val = acc[i][j][r] * 0.125f;
        const unsigned u = sortkey(val);
        const unsigned bin = u >> 18;
        if (bin == binA || bin == binB) {
          unsigned id = atomicAdd(&lcnt, 1u);
          if (id < LCAP) lbuf[id] = u;
          else { unsigned g = atomicAdd(&ccnt[h], 1u); if (g < CAPC) mycand[g] = u; }
        }
      }
  __syncthreads();
  const unsigned n = (lcnt < LCAP) ? lcnt : LCAP;
  if (threadIdx.x == 0) gbase = n ? atomicAdd(&ccnt[h], n) : 0u;
  __syncthreads();
  const unsigned gb = gbase;
  for (unsigned i = threadIdx.x; i < n; i += 512)
    if (gb + i < CAPC) mycand[gb + i] = lbuf[i];
}

// seed the parallel-final-select state after scan9/fallback resolved binA/binB
__global__ __launch_bounds__(64) void seed_fs(const unsigned* __restrict__ state,
                                              unsigned* __restrict__ sstate)
{
  const int t = threadIdx.x;
  if (t < HH * 4) sstate[t] = state[t];
}

// ---------------- parallel final select: 3 rounds of (hist over 32 blocks, scan) ----------------
__global__ __launch_bounds__(256) void fs_hist(const unsigned* __restrict__ cand,
                                               const unsigned* __restrict__ ccnt,
                                               const unsigned* __restrict__ sstate,
                                               unsigned* __restrict__ fhist,
                                               int s, int w)
{
  const int hh = blockIdx.y;
  const int t = threadIdx.x;
  const unsigned nb = 1u << w;
  __shared__ unsigned lh0[256], lh1[256];
  lh0[t] = 0; lh1[t] = 0;
  __syncthreads();
  const unsigned pfxA = sstate[hh*4+0];
  const unsigned pfxB = sstate[hh*4+2];
  unsigned n = ccnt[hh]; if (n > CAPC) n = CAPC;
  const unsigned* __restrict__ list = cand + (size_t)hh * CAPC;
  for (unsigned i = blockIdx.x * 256 + t; i < n; i += 32 * 256) {
    const unsigned u = list[i];
    if ((u >> (s + w)) == pfxA) atomicAdd(&lh0[(u >> s) & (nb - 1)], 1u);
    if ((u >> (s + w)) == pfxB) atomicAdd(&lh1[(u >> s) & (nb - 1)], 1u);
  }
  __syncthreads();
  if (t < (int)nb) {
    if (lh0[t]) atomicAdd(&fhist[hh*512 + t], lh0[t]);
    if (lh1[t]) atomicAdd(&fhist[hh*512 + 256 + t], lh1[t]);
  }
}

__global__ __launch_bounds__(256) void fs_scan(unsigned* __restrict__ fhist,
                                               unsigned* __restrict__ sstate,
                                               float* __restrict__ thr,
                                               int s, int w)
{
  const int hh = blockIdx.x;
  const int t = threadIdx.x;
  const unsigned nb = 1u << w;
  if (t == 0) {
    float vals[2];
    for (int tgt = 0; tgt < 2; ++tgt) {
      unsigned pfx = sstate[hh*4 + tgt*2];
      unsigned k   = sstate[hh*4 + tgt*2 + 1];
      const unsigned* hb = &fhist[hh*512 + tgt*256];
      unsigned cum = 0, b = 0;
      for (; b < nb; ++b) { const unsigned c = hb[b]; if (cum + c > k) break; cum += c; }
      if (b == nb) b = nb - 1;
      pfx = (pfx << w) | b;
      k -= cum;
      sstate[hh*4 + tgt*2]     = pfx;
      sstate[hh*4 + tgt*2 + 1] = k;
      if (s == 0) vals[tgt] = inv_sortkey(pfx);
    }
    if (s == 0) thr[hh] = vals[0] + QFRAC * (vals[1] - vals[0]);
  }
  __syncthreads();
  fhist[hh*512 + t] = 0;           // zero for next round
  fhist[hh*512 + 256 + t] = 0;
}

// ---------------- pass 3: flash softmax+PV, key-split over NSPL halves ----------------
__global__ __launch_bounds__(256) void flash_pv_sk(const _Float16* __restrict__ Qh,
                                                   const _Float16* __restrict__ Ql,
                                                   const _Float16* __restrict__ Kh,
                                                   const _Float16* __restrict__ Kl,
                                                   const _Float16* __restrict__ VtH,
                                                   const _Float16* __restrict__ VtL,
                                                   const float* __restrict__ thrArr,
                                                   float* __restrict__ pctx,
                                                   float* __restrict__ prs)
{
  const int bm = blockIdx.x;          // 0..31 -> rows bm*64
  const int h  = blockIdx.y;
  const int q  = blockIdx.z;          // 0..NSPL-1
  const int wave = threadIdx.x >> 6, lane = threadIdx.x & 63;
  const int lr = lane & 15;
  const int ko = lane >> 4;
  const int m0 = bm * 64;
  const float thr = thrArr[h];
  const int KTS = 16 / NSPL;

  __shared__ _Float16 Plds[64][136];  // pad 128->136
  __shared__ float rsLDS[64][4];

  // Q fragments are kt-invariant: hoist
  f16x8 qH[4][2], qL[4][2];
#pragma unroll
  for (int i = 0; i < 4; ++i)
#pragma unroll
    for (int kk = 0; kk < 2; ++kk) {
      const size_t aoff = (size_t)(m0 + i*16 + lr) * 1024 + h*64 + kk*32 + ko*8;
      qH[i][kk] = *(const f16x8*)(Qh + aoff);
      qL[i][kk] = *(const f16x8*)(Ql + aoff);
    }

  f32x4 oacc[4];
#pragma unroll
  for (int i = 0; i < 4; ++i) oacc[i] = (f32x4){0.f, 0.f, 0.f, 0.f};
  float rs[4][4];
#pragma unroll
  for (int i = 0; i < 4; ++i)
#pragma unroll
    for (int r = 0; r < 4; ++r) rs[i][r] = 0.f;

  const int d0 = wave * 16;   // PV: wave owns dims d0..d0+15

  for (int kt = q*KTS; kt < q*KTS + KTS; ++kt) {
    const int n0 = kt*128 + wave*32;   // S: wave owns keys n0..n0+31
    f32x4 sacc[4][2];
#pragma unroll
    for (int i = 0; i < 4; ++i)
#pragma unroll
      for (int j = 0; j < 2; ++j) sacc[i][j] = (f32x4){0.f, 0.f, 0.f, 0.f};

#pragma unroll
    for (int kk = 0; kk < 2; ++kk) {
      f16x8 bH[2], bL[2];
#pragma unroll
      for (int j = 0; j < 2; ++j) {
        const size_t boff = (size_t)(n0 + j*16 + lr) * 1024 + h*64 + kk*32 + ko*8;
        bH[j] = *(const f16x8*)(Kh + boff);
        bL[j] = *(const f16x8*)(Kl + boff);
      }
#pragma unroll
      for (int i = 0; i < 4; ++i)
#pragma unroll
        for (int j = 0; j < 2; ++j) {
          sacc[i][j] = __builtin_amdgcn_mfma_f32_16x16x32_f16(qL[i][kk], bL[j], sacc[i][j], 0, 0, 0);
          sacc[i][j] = __builtin_amdgcn_mfma_f32_16x16x32_f16(qH[i][kk], bL[j], sacc[i][j], 0, 0, 0);
          sacc[i][j] = __builtin_amdgcn_mfma_f32_16x16x32_f16(qL[i][kk], bH[j], sacc[i][j], 0, 0, 0);
          sacc[i][j] = __builtin_amdgcn_mfma_f32_16x16x32_f16(qH[i][kk], bH[j], sacc[i][j], 0, 0, 0);
        }
    }

    // mask + exp + P->LDS + rowsum partials
#pragma unroll
    for (int i = 0; i < 4; ++i)
#pragma unroll
      for (int j = 0; j < 2; ++j)
#pragma unroll
        for (int r = 0; r < 4; ++r) {
          const float val = sacc[i][j][r] * 0.125f;
          const float p = (val >= thr) ? __expf(val - thr - ESHIFT) : 0.f;
          rs[i][r] += p;
          Plds[i*16 + ko*4 + r][wave*32 + j*16 + lr] = (_Float16)p;
        }
    __syncthreads();

    // PV: oacc[i] over dims d0+lr, keys kt*128..+127
#pragma unroll
    for (int kk2 = 0; kk2 < 4; ++kk2) {
      f16x8 pa[4];
#pragma unroll
      for (int i = 0; i < 4; ++i)
        pa[i] = *(const f16x8*)&Plds[i*16 + lr][kk2*32 + ko*8];
      const size_t vo = (size_t)(h*64 + d0 + lr) * 2048 + kt*128 + kk2*32 + ko*8;
      const f16x8 vH = *(const f16x8*)(VtH + vo);
      const f16x8 vL = *(const f16x8*)(VtL + vo);
#pragma unroll
      for (int i = 0; i < 4; ++i) {
        oacc[i] = __builtin_amdgcn_mfma_f32_16x16x32_f16(pa[i], vL, oacc[i], 0, 0, 0);
        oacc[i] = __builtin_amdgcn_mfma_f32_16x16x32_f16(pa[i], vH, oacc[i], 0, 0, 0);
      }
    }
    __syncthreads();   // before next kt overwrites Plds
  }

  // rowsum: reduce across the 16 lanes of each ko-group, then across waves
#pragma unroll
  for (int i = 0; i < 4; ++i)
#pragma unroll
    for (int r = 0; r < 4; ++r) {
      float v = rs[i][r];
      v += __shfl_xor(v, 1); v += __shfl_xor(v, 2);
      v += __shfl_xor(v, 4); v += __shfl_xor(v, 8);
      rs[i][r] = v;
    }
  if (lr == 0) {
#pragma unroll
    for (int i = 0; i < 4; ++i)
#pragma unroll
      for (int r = 0; r < 4; ++r)
        rsLDS[i*16 + ko*4 + r][wave] = rs[i][r];
  }
  __syncthreads();

  // write partial rowsums
  if (wave == 0 && lr == 0) {
#pragma unroll
    for (int i = 0; i < 4; ++i)
#pragma unroll
      for (int r = 0; r < 4; ++r) {
        const int lrow = i*16 + ko*4 + r;
        prs[q*32768 + h*2048 + m0 + lrow] =
            rsLDS[lrow][0] + rsLDS[lrow][1] + rsLDS[lrow][2] + rsLDS[lrow][3];
      }
  }

  // store raw partial O
  float* __restrict__ pc = pctx + (size_t)q * PLANE;
#pragma unroll
  for (int i = 0; i < 4; ++i)
#pragma unroll
    for (int r = 0; r < 4; ++r) {
      const int lrow = i*16 + ko*4 + r;
      pc[(size_t)(m0 + lrow) * 1024 + h*64 + d0 + lr] = oacc[i][r];
    }
}

// ---------------- host ----------------
extern "C" void kernel_launch(void* const* d_in, const int* in_sizes, int n_in,
                              void* d_out, int out_size, void* d_ws, size_t ws_size,
                              hipStream_t stream)
{
  const float* x  = (const float*)d_in[0];
  const float* Wq = (const float*)d_in[1];
  const float* bq = (const float*)d_in[2];
  const float* Wk = (const float*)d_in[3];
  const float* bk = (const float*)d_in[4];
  const float* Wv = (const float*)d_in[5];
  const float* bv = (const float*)d_in[6];
  const float* Wo = (const float*)d_in[7];
  const float* bo = (const float*)d_in[8];
  float* out = (float*)d_out;
  char*  ws  = (char*)d_ws;

  const size_t MB = 1u << 20;
  _Float16* xh      = (_Float16*)(ws + 0*MB);
  _Float16* xl      = (_Float16*)(ws + 4*MB);
  _Float16* wplanes = (_Float16*)(ws + 8*MB);    // 8 x 2 MiB transposed W planes
  _Float16* Qh      = (_Float16*)(ws + 24*MB);
  _Float16* Ql      = (_Float16*)(ws + 28*MB);
  _Float16* Kh      = (_Float16*)(ws + 32*MB);
  _Float16* Kl      = (_Float16*)(ws + 36*MB);
  _Float16* VtH     = (_Float16*)(ws + 40*MB);   // [1024 dims][2048 rows]
  _Float16* VtL     = (_Float16*)(ws + 44*MB);
  _Float16* ctxh    = (_Float16*)(ws + 48*MB);
  _Float16* ctxl    = (_Float16*)(ws + 52*MB);
  const size_t base = 56*MB;
  unsigned* state    = (unsigned*)(ws + base);
  float*    thr      = (float*)(ws + base + 4096);
  unsigned* ccnt     = (unsigned*)(ws + base + 8192);
  unsigned* flag     = (unsigned*)(ws + base + 12288);
  unsigned* rangeLo  = (unsigned*)(ws + base + 16384);
  unsigned* rangeHi  = (unsigned*)(ws + base + 20480);
  unsigned* sstate   = (unsigned*)(ws + base + 24576);
  unsigned* fhist    = (unsigned*)(ws + base + 28672);  // HH*512*4 = 32 KiB
  unsigned* cntBelow = (unsigned*)(ws + base + 65536);
  unsigned* ghist9   = (unsigned*)(ws + base + 69632);  // HH*16 u32
  unsigned* ghist    = (unsigned*)(ws + 57*MB);   // 1 MiB (fallback only)
  unsigned* shist    = (unsigned*)(ws + 58*MB);   // 1 MiB
  unsigned* cand     = (unsigned*)(ws + 59*MB);   // HH * CAPC * 4 = 20 MiB
  float*    prs      = (float*)(ws + 80*MB);      // NSPL x 16 x 2048 f32
  float*    pbuf     = (float*)(ws + 81*MB);      // 6 x 8 MiB partials
  float*    pctx     = pbuf;                      // planes 0..NSPL-1 (post combine_qk)
  float*    pO       = pbuf + (size_t)4 * PLANE;  // planes 4,5

  split_x<<<2048, 256, 0, stream>>>(x, xh, xl);
  split_wT<<<dim3(16, 16, 4), 256, 0, stream>>>(Wq, Wk, Wv, Wo, wplanes);
  gemm_qkv_part<<<dim3(8, 16, 6), 256, 0, stream>>>(xh, xl, wplanes, pbuf);
  combine_qk<<<dim3(2048, 2), 256, 0, stream>>>(pbuf, bq, bk, Qh, Ql, Kh, Kl);
  combine_vT<<<dim3(16, 32), 256, 0, stream>>>(pbuf, bv, VtH, VtL);

  init_sel<<<256, 256, 0, stream>>>(ghist, shist, ccnt, flag, fhist, cntBelow, ghist9);
  sample_hist<<<dim3(16, HH), 256, 0, stream>>>(Qh, Ql, Kh, Kl, shist);
  sample_scan<<<HH, 256, 0, stream>>>(shist, rangeLo, rangeHi);
  range_count<<<dim3(16, 8, HH), 512, 0, stream>>>(Qh, Ql, Kh, Kl, rangeLo, rangeHi,
                                                   cand, ccnt, cntBelow);
  hist9_from_cands<<<dim3(8, HH), 256, 0, stream>>>(cand, ccnt, rangeLo, ghist9);
  scan9<<<1, 64, 0, stream>>>(ghist9, cntBelow, rangeLo, rangeHi, ccnt, state, flag);
  // fallback chain (early-exit per head when prediction held)
  fb_scores_hist<<<dim3(16, 8, HH), 512, 0, stream>>>(Qh, Ql, Kh, Kl, flag, ghist);
  fb_scan14<<<HH, 256, 0, stream>>>(ghist, flag, state);
  fallback_compact<<<dim3(16, 8, HH), 512, 0, stream>>>(Qh, Ql, Kh, Kl, state, flag, cand, ccnt);
  seed_fs<<<1, 64, 0, stream>>>(state, sstate);
  // parallel final select: rounds (s,w) = (10,8), (2,8), (0,2)
  fs_hist<<<dim3(32, HH), 256, 0, stream>>>(cand, ccnt, sstate, fhist, 10, 8);
  fs_scan<<<HH, 256, 0, stream>>>(fhist, sstate, thr, 10, 8);
  fs_hist<<<dim3(32, HH), 256, 0, stream>>>(cand, ccnt, sstate, fhist, 2, 8);
  fs_scan<<<HH, 256, 0, stream>>>(fhist, sstate, thr, 2, 8);
  fs_hist<<<dim3(32, HH), 256, 0, stream>>>(cand, ccnt, sstate, fhist, 0, 2);
  fs_scan<<<HH, 256, 0, stream>>>(fhist, sstate, thr, 0, 2);

  flash_pv_sk<<<dim3(32, HH, NSPL), 256, 0, stream>>>(Qh, Ql, Kh, Kl, VtH, VtL, thr, pctx, prs);
  combine_ctx<<<2048, 256, 0, stream>>>(pctx, prs, ctxh, ctxl);

  gemm_o_part<<<dim3(8, 16, 2), 256, 0, stream>>>(ctxh, ctxl, wplanes, pO);
  combine_o<<<2048, 256, 0, stream>>>(pO, bo, out);
}

// Round 21
// 538.115 us; speedup vs baseline: 1.0964x; 1.0436x over previous
//
#include <hip/hip_runtime.h>
#include <math.h>

#define SS 2048
#define DD 1024
#define HH 16
#define CAPC 327680u  // candidate slots per head (range ~9 bins x ~16K/bin ~ 150K expected)
#define LCAP 2048     // per-block LDS candidate buffer (expected ~1200/block)
#define RBIN 4        // predicted-bin safety margin (sampling sigma ~0.16 bins)

// quantile index: floor(0.95*(S*S-1)) = floor(3984587.85)
#define K_A 3984587u
#define K_B 3984588u
#define QFRAC 0.85f
#define WSCALE 2048.0f      // W planes pre-scaled so lo-residuals stay normal fp16
#define WSCALE_INV (1.0f/2048.0f)
#define ESHIFT 4.0f         // exp(s - thr - ESHIFT): kept P in [e^-4, ~e^6] — fp16-safe
#define PLANE 2097152       // floats per 2048x1024 fp32 partial plane (8 MiB)
#define NSAMP_RANK 124518u  // floor(0.95 * 131072) — sample quantile rank

typedef _Float16 f16x8 __attribute__((ext_vector_type(8)));
typedef _Float16 f16x4 __attribute__((ext_vector_type(4)));
typedef float    f32x4 __attribute__((ext_vector_type(4)));

__device__ __forceinline__ unsigned sortkey(float f) {
  unsigned b = __float_as_uint(f);
  return (b & 0x80000000u) ? ~b : (b | 0x80000000u);
}
__device__ __forceinline__ float inv_sortkey(unsigned u) {
  unsigned b = (u & 0x80000000u) ? (u ^ 0x80000000u) : ~u;
  return __uint_as_float(b);
}

// ---------------- input splitting ----------------
__global__ __launch_bounds__(256) void split_x(const float* __restrict__ x,
                                               _Float16* __restrict__ xh,
                                               _Float16* __restrict__ xl)
{
  const int i = blockIdx.x * 256 + threadIdx.x;   // float4 index, 524288 total
  float4 v = ((const float4*)x)[i];
  float vv[4] = {v.x, v.y, v.z, v.w};
  f16x4 h, l;
#pragma unroll
  for (int j = 0; j < 4; ++j) {
    _Float16 hh = (_Float16)vv[j];
    h[j] = hh;
    l[j] = (_Float16)(vv[j] - (float)hh);
  }
  ((f16x4*)xh)[i] = h;
  ((f16x4*)xl)[i] = l;
}

// W -> transposed hi/lo fp16 planes WT[n][k], scaled by 2048 (keeps lo normal).
__global__ __launch_bounds__(256) void split_wT(const float* __restrict__ Wq,
                                                const float* __restrict__ Wk,
                                                const float* __restrict__ Wv,
                                                const float* __restrict__ Wo,
                                                _Float16* __restrict__ wplanes)
{
  const int z = blockIdx.z;
  const float* W = (z == 0) ? Wq : (z == 1) ? Wk : (z == 2) ? Wv : Wo;
  _Float16* WhT = wplanes + (size_t)(2*z)     * (1024*1024);
  _Float16* WlT = wplanes + (size_t)(2*z + 1) * (1024*1024);
  __shared__ float tile[64][65];
  const int t  = threadIdx.x;
  const int r  = t >> 2;         // 0..63
  const int c0 = (t & 3) * 16;   // 0/16/32/48
  const int k0 = blockIdx.y * 64;
  const int n0 = blockIdx.x * 64;
#pragma unroll
  for (int j = 0; j < 4; ++j) {
    float4 v = *(const float4*)&W[(size_t)(k0 + r) * 1024 + n0 + c0 + j*4];
    tile[r][c0+j*4+0] = v.x; tile[r][c0+j*4+1] = v.y;
    tile[r][c0+j*4+2] = v.z; tile[r][c0+j*4+3] = v.w;
  }
  __syncthreads();
  f16x8 h0, h1, l0, l1;
#pragma unroll
  for (int j = 0; j < 8; ++j) {
    float v = tile[c0 + j][r] * WSCALE;
    _Float16 h = (_Float16)v;
    h0[j] = h; l0[j] = (_Float16)(v - (float)h);
  }
#pragma unroll
  for (int j = 0; j < 8; ++j) {
    float v = tile[c0 + 8 + j][r] * WSCALE;
    _Float16 h = (_Float16)v;
    h1[j] = h; l1[j] = (_Float16)(v - (float)h);
  }
  const size_t o = (size_t)(n0 + r) * 1024 + k0 + c0;
  *(f16x8*)&WhT[o]     = h0;
  *(f16x8*)&WhT[o + 8] = h1;
  *(f16x8*)&WlT[o]     = l0;
  *(f16x8*)&WlT[o + 8] = l1;
}

// ---------------- split-K MFMA GEMM partial ----------------
__device__ __forceinline__ void gemm_mfma_part(const _Float16* __restrict__ Ah,
                                               const _Float16* __restrict__ Al,
                                               const _Float16* __restrict__ BhT,
                                               const _Float16* __restrict__ BlT,
                                               float* __restrict__ pout,
                                               int bm, int bn, int kh)
{
  const int wave = threadIdx.x >> 6, lane = threadIdx.x & 63;
  const int wr = wave >> 1, wc = wave & 1;
  const int m0 = bm * 128 + wr * 64;
  const int n0 = bn * 128 + wc * 64;
  const int lr = lane & 15;
  const int ko = lane >> 4;

  f32x4 acc[4][4];
#pragma unroll
  for (int i = 0; i < 4; ++i)
#pragma unroll
    for (int j = 0; j < 4; ++j) acc[i][j] = (f32x4){0.f, 0.f, 0.f, 0.f};

  for (int kk = kh*16; kk < kh*16 + 16; ++kk) {
    const int kof = kk*32 + ko*8;
    f16x8 aH[4], aL[4], bH[4], bL[4];
#pragma unroll
    for (int i = 0; i < 4; ++i) {
      const size_t aoff = (size_t)(m0 + i*16 + lr) * 1024 + kof;
      aH[i] = *(const f16x8*)(Ah + aoff);
      aL[i] = *(const f16x8*)(Al + aoff);
      const size_t boff = (size_t)(n0 + i*16 + lr) * 1024 + kof;
      bH[i] = *(const f16x8*)(BhT + boff);
      bL[i] = *(const f16x8*)(BlT + boff);
    }
#pragma unroll
    for (int i = 0; i < 4; ++i)
#pragma unroll
      for (int j = 0; j < 4; ++j) {
        acc[i][j] = __builtin_amdgcn_mfma_f32_16x16x32_f16(aL[i], bL[j], acc[i][j], 0, 0, 0);
        acc[i][j] = __builtin_amdgcn_mfma_f32_16x16x32_f16(aH[i], bL[j], acc[i][j], 0, 0, 0);
        acc[i][j] = __builtin_amdgcn_mfma_f32_16x16x32_f16(aL[i], bH[j], acc[i][j], 0, 0, 0);
        acc[i][j] = __builtin_amdgcn_mfma_f32_16x16x32_f16(aH[i], bH[j], acc[i][j], 0, 0, 0);
      }
  }

#pragma unroll
  for (int i = 0; i < 4; ++i)
#pragma unroll
    for (int j = 0; j < 4; ++j)
#pragma unroll
      for (int r = 0; r < 4; ++r) {
        const int row = m0 + i*16 + ko*4 + r;
        const int col = n0 + j*16 + lr;
        pout[(size_t)row * 1024 + col] = acc[i][j][r];
      }
}

__global__ __launch_bounds__(256) void gemm_qkv_part(const _Float16* __restrict__ xh,
                                                     const _Float16* __restrict__ xl,
                                                     const _Float16* __restrict__ wplanes,
                                                     float* __restrict__ pbuf)
{
  const int z = blockIdx.z;           // 0..5: gemm_id*2 + khalf
  const int g = z >> 1, kh = z & 1;
  const _Float16* BhT = wplanes + (size_t)(2*g)     * (1024*1024);
  const _Float16* BlT = wplanes + (size_t)(2*g + 1) * (1024*1024);
  gemm_mfma_part(xh, xl, BhT, BlT, pbuf + (size_t)z * PLANE,
                 blockIdx.y, blockIdx.x, kh);
}

__global__ __launch_bounds__(256) void gemm_o_part(const _Float16* __restrict__ ctxh,
                                                   const _Float16* __restrict__ ctxl,
                                                   const _Float16* __restrict__ wplanes,
                                                   float* __restrict__ pO)
{
  const int kh = blockIdx.z;          // 0..1
  gemm_mfma_part(ctxh, ctxl,
                 wplanes + (size_t)6 * (1024*1024),
                 wplanes + (size_t)7 * (1024*1024),
                 pO + (size_t)kh * PLANE, blockIdx.y, blockIdx.x, kh);
}

// ---------------- combine kernels ----------------
__global__ __launch_bounds__(256) void combine_qk(const float* __restrict__ pbuf,
                                                  const float* __restrict__ bq,
                                                  const float* __restrict__ bk,
                                                  _Float16* __restrict__ Qh,
                                                  _Float16* __restrict__ Ql,
                                                  _Float16* __restrict__ Kh,
                                                  _Float16* __restrict__ Kl)
{
  const int which = blockIdx.y;       // 0=Q, 1=K
  const float* p0 = pbuf + (size_t)(which*2)     * PLANE;
  const float* p1 = pbuf + (size_t)(which*2 + 1) * PLANE;
  const float* bias = which ? bk : bq;
  _Float16* Oh = which ? Kh : Qh;
  _Float16* Ol = which ? Kl : Ql;
  const int i = blockIdx.x * 256 + threadIdx.x;   // f4 index, 524288
  const int coloff = (i & 255) * 4;
  float4 a = ((const float4*)p0)[i];
  float4 b = ((const float4*)p1)[i];
  float av[4] = {a.x, a.y, a.z, a.w};
  float bv[4] = {b.x, b.y, b.z, b.w};
  f16x4 h, l;
#pragma unroll
  for (int j = 0; j < 4; ++j) {
    const float val = (av[j] + bv[j]) * WSCALE_INV + bias[coloff + j];
    _Float16 hh = (_Float16)val;
    h[j] = hh;
    l[j] = (_Float16)(val - (float)hh);
  }
  ((f16x4*)Oh)[i] = h;
  ((f16x4*)Ol)[i] = l;
}

// V: combine + transpose to Vt[dim][row] hi/lo planes (LDS 64x64 tile).
__global__ __launch_bounds__(256) void combine_vT(const float* __restrict__ pbuf,
                                                  const float* __restrict__ bv,
                                                  _Float16* __restrict__ VtH,
                                                  _Float16* __restrict__ VtL)
{
  const float* p0 = pbuf + (size_t)4 * PLANE;
  const float* p1 = pbuf + (size_t)5 * PLANE;
  __shared__ float tile[64][65];
  const int t  = threadIdx.x;
  const int d0 = blockIdx.x * 64;     // dim tile
  const int m0 = blockIdx.y * 64;     // row tile
  {
    const int r  = t >> 2;            // row 0..63
    const int c0 = (t & 3) * 16;
#pragma unroll
    for (int j = 0; j < 4; ++j) {
      const size_t o = (size_t)(m0 + r) * 1024 + d0 + c0 + j*4;
      float4 a = *(const float4*)(p0 + o);
      float4 b = *(const float4*)(p1 + o);
      tile[r][c0+j*4+0] = (a.x + b.x) * WSCALE_INV + bv[d0 + c0 + j*4 + 0];
      tile[r][c0+j*4+1] = (a.y + b.y) * WSCALE_INV + bv[d0 + c0 + j*4 + 1];
      tile[r][c0+j*4+2] = (a.z + b.z) * WSCALE_INV + bv[d0 + c0 + j*4 + 2];
      tile[r][c0+j*4+3] = (a.w + b.w) * WSCALE_INV + bv[d0 + c0 + j*4 + 3];
    }
  }
  __syncthreads();
  {
    const int d  = t >> 2;            // dim 0..63
    const int rg = (t & 3) * 16;      // row group
#pragma unroll
    for (int j = 0; j < 4; ++j) {
      f16x4 hv, lv;
#pragma unroll
      for (int r = 0; r < 4; ++r) {
        const float val = tile[rg + j*4 + r][d];
        _Float16 h = (_Float16)val;
        hv[r] = h; lv[r] = (_Float16)(val - (float)h);
      }
      const size_t o = (size_t)(d0 + d) * 2048 + m0 + rg + j*4;
      *(f16x4*)&VtH[o] = hv;
      *(f16x4*)&VtL[o] = lv;
    }
  }
}

__global__ __launch_bounds__(256) void combine_o(const float* __restrict__ pO,
                                                 const float* __restrict__ bo,
                                                 float* __restrict__ out)
{
  const float* p0 = pO;
  const float* p1 = pO + (size_t)1 * PLANE;
  const int i = blockIdx.x * 256 + threadIdx.x;
  const int coloff = (i & 255) * 4;
  float4 a = ((const float4*)p0)[i];
  float4 b = ((const float4*)p1)[i];
  float4 o;
  o.x = (a.x + b.x) * WSCALE_INV + bo[coloff + 0];
  o.y = (a.y + b.y) * WSCALE_INV + bo[coloff + 1];
  o.z = (a.z + b.z) * WSCALE_INV + bo[coloff + 2];
  o.w = (a.w + b.w) * WSCALE_INV + bo[coloff + 3];
  ((float4*)out)[i] = o;
}

// ctx: (p0+p1) / (rs0+rs1), then fp16 hi/lo split.
__global__ __launch_bounds__(256) void combine_ctx(const float* __restrict__ pctx,
                                                   const float* __restrict__ prs,
                                                   _Float16* __restrict__ ctxh,
                                                   _Float16* __restrict__ ctxl)
{
  const float* p0 = pctx;
  const float* p1 = pctx + (size_t)1 * PLANE;
  const int i = blockIdx.x * 256 + threadIdx.x;   // f4 index, 524288
  const int row = i >> 8;
  const int cd  = (i & 255) * 4;
  const int h   = cd >> 6;
  const float rs = prs[h*2048 + row] + prs[32768 + h*2048 + row];
  float4 a = ((const float4*)p0)[i];
  float4 b = ((const float4*)p1)[i];
  float av[4] = {a.x, a.y, a.z, a.w};
  float bv[4] = {b.x, b.y, b.z, b.w};
  f16x4 hh, ll;
#pragma unroll
  for (int j = 0; j < 4; ++j) {
    const float val = (av[j] + bv[j]) / rs;
    _Float16 hv = (_Float16)val;
    hh[j] = hv;
    ll[j] = (_Float16)(val - (float)hv);
  }
  ((f16x4*)ctxh)[i] = hh;
  ((f16x4*)ctxl)[i] = ll;
}

// ---------------- selection init ----------------
__global__ __launch_bounds__(256) void init_sel(unsigned* __restrict__ ghist,
                                                unsigned* __restrict__ shist,
                                                unsigned* __restrict__ ccnt,
                                                unsigned* __restrict__ flag,
                                                unsigned* __restrict__ fhist,
                                                unsigned* __restrict__ cntBelow,
                                                unsigned* __restrict__ ghist9)
{
  int i = blockIdx.x * 256 + threadIdx.x;
  for (; i < HH * 16384; i += gridDim.x * 256) { ghist[i] = 0; shist[i] = 0; }
  const int j = blockIdx.x * 256 + threadIdx.x;
  if (j < HH * 512) fhist[j] = 0;
  if (j < HH * 16) ghist9[j] = 0;
  if (blockIdx.x == 0 && threadIdx.x < HH) {
    ccnt[threadIdx.x] = 0; flag[threadIdx.x] = 0; cntBelow[threadIdx.x] = 0;
  }
}

// ---------------- sampling pass: 64 of 2048 query rows (stride 32) ----------------
__global__ __launch_bounds__(256) void sample_hist(const _Float16* __restrict__ Qh,
                                                   const _Float16* __restrict__ Ql,
                                                   const _Float16* __restrict__ Kh,
                                                   const _Float16* __restrict__ Kl,
                                                   unsigned* __restrict__ shist)
{
  const int kb = blockIdx.x, h = blockIdx.y;
  const int wave = threadIdx.x >> 6, lane = threadIdx.x & 63;
  const int lr = lane & 15, ko = lane >> 4;
  const int n0 = kb*128 + wave*32;

  __shared__ unsigned lh[16384];   // 64 KB
  for (int i = threadIdx.x; i < 16384; i += 256) lh[i] = 0;
  __syncthreads();

  f32x4 acc[4][2];
#pragma unroll
  for (int i = 0; i < 4; ++i)
#pragma unroll
    for (int j = 0; j < 2; ++j) acc[i][j] = (f32x4){0.f, 0.f, 0.f, 0.f};

#pragma unroll
  for (int kk = 0; kk < 2; ++kk) {
    f16x8 aH[4], aL[4], bH[2], bL[2];
#pragma unroll
    for (int i = 0; i < 4; ++i) {
      const size_t aoff = (size_t)((i*16 + lr) * 32) * 1024 + h*64 + kk*32 + ko*8;
      aH[i] = *(const f16x8*)(Qh + aoff);
      aL[i] = *(const f16x8*)(Ql + aoff);
    }
#pragma unroll
    for (int j = 0; j < 2; ++j) {
      const size_t boff = (size_t)(n0 + j*16 + lr) * 1024 + h*64 + kk*32 + ko*8;
      bH[j] = *(const f16x8*)(Kh + boff);
      bL[j] = *(const f16x8*)(Kl + boff);
    }
#pragma unroll
    for (int i = 0; i < 4; ++i)
#pragma unroll
      for (int j = 0; j < 2; ++j) {
        acc[i][j] = __builtin_amdgcn_mfma_f32_16x16x32_f16(aL[i], bL[j], acc[i][j], 0, 0, 0);
        acc[i][j] = __builtin_amdgcn_mfma_f32_16x16x32_f16(aH[i], bL[j], acc[i][j], 0, 0, 0);
        acc[i][j] = __builtin_amdgcn_mfma_f32_16x16x32_f16(aL[i], bH[j], acc[i][j], 0, 0, 0);
        acc[i][j] = __builtin_amdgcn_mfma_f32_16x16x32_f16(aH[i], bH[j], acc[i][j], 0, 0, 0);
      }
  }

#pragma unroll
  for (int i = 0; i < 4; ++i)
#pragma unroll
    for (int j = 0; j < 2; ++j)
#pragma unroll
      for (int r = 0; r < 4; ++r) {
        const float val = acc[i][j][r] * 0.125f;
        atomicAdd(&lh[sortkey(val) >> 18], 1u);
      }
  __syncthreads();
  unsigned* __restrict__ gh = shist + (size_t)h * 16384;
  for (int i = threadIdx.x; i < 16384; i += 256) {
    const unsigned c = lh[i];
    if (c) atomicAdd(&gh[i], c);
  }
}

// find sample-quantile bin; emit conservative range [bin-RBIN, bin+RBIN]
__global__ __launch_bounds__(256) void sample_scan(const unsigned* __restrict__ shist,
                                                   unsigned* __restrict__ rangeLo,
                                                   unsigned* __restrict__ rangeHi)
{
  const int hh = blockIdx.x;
  const int t = threadIdx.x;
  __shared__ unsigned part[256];
  __shared__ unsigned outb;
  if (t == 0) outb = 8192u;  // defensive default
  const unsigned* __restrict__ hb = shist + (size_t)hh * 16384;
  unsigned s = 0;
  for (int j = 0; j < 64; ++j) s += hb[t*64 + j];
  part[t] = s;
  __syncthreads();
  if (t == 0) {
    unsigned run = 0;
    for (int i = 0; i < 256; ++i) { unsigned tmp = part[i]; part[i] = run; run += tmp; }
  }
  __syncthreads();
  const unsigned cum0 = part[t];
  if (NSAMP_RANK >= cum0 && NSAMP_RANK < cum0 + s) {
    unsigned c2 = cum0;
    for (int j = 0; j < 64; ++j) {
      const unsigned c = hb[t*64 + j];
      if (NSAMP_RANK < c2 + c) { outb = t*64 + j; break; }
      c2 += c;
    }
  }
  __syncthreads();
  if (t == 0) {
    const int b = (int)outb;
    rangeLo[hh] = (unsigned)((b - RBIN < 0) ? 0 : b - RBIN);
    rangeHi[hh] = (unsigned)((b + RBIN > 16383) ? 16383 : b + RBIN);
  }
}

// ---------------- pass 1: count-below + 9-bin range histogram + compaction ----------------
// r17-measured-best variant: in-loop 16-entry LDS minihist + per-item lcnt push.
__global__ __launch_bounds__(512) void range_count(const _Float16* __restrict__ Qh,
                                                   const _Float16* __restrict__ Ql,
                                                   const _Float16* __restrict__ Kh,
                                                   const _Float16* __restrict__ Kl,
                                                   const unsigned* __restrict__ rangeLo,
                                                   const unsigned* __restrict__ rangeHi,
                                                   unsigned* __restrict__ cand,
                                                   unsigned* __restrict__ ccnt,
                                                   unsigned* __restrict__ cntBelow,
                                                   unsigned* __restrict__ ghist9)
{
  const int bn = blockIdx.x, bm = blockIdx.y, h = blockIdx.z;
  const int wave = threadIdx.x >> 6, lane = threadIdx.x & 63;
  const int wr = wave >> 1, wc = wave & 1;
  const int m0 = bm * 256 + wr * 64;
  const int n0 = bn * 128 + wc * 64;
  const int lr = lane & 15;
  const int ko = lane >> 4;
  const unsigned lo = rangeLo[h], hi = rangeHi[h];
  unsigned* __restrict__ mycand = cand + (size_t)h * CAPC;

  __shared__ unsigned lh9[16];
  __shared__ unsigned lbuf[LCAP];  // 8 KB
  __shared__ unsigned lcnt, gbase, lbelow;
  if (threadIdx.x < 16) lh9[threadIdx.x] = 0;
  if (threadIdx.x == 0) { lcnt = 0; lbelow = 0; }
  __syncthreads();

  f32x4 acc[4][4];
#pragma unroll
  for (int i = 0; i < 4; ++i)
#pragma unroll
    for (int j = 0; j < 4; ++j) acc[i][j] = (f32x4){0.f, 0.f, 0.f, 0.f};

#pragma unroll
  for (int kk = 0; kk < 2; ++kk) {
    f16x8 aH[4], aL[4], bH[4], bL[4];
#pragma unroll
    for (int i = 0; i < 4; ++i) {
      const size_t aoff = (size_t)(m0 + i*16 + lr) * 1024 + h*64 + kk*32 + ko*8;
      aH[i] = *(const f16x8*)(Qh + aoff);
      aL[i] = *(const f16x8*)(Ql + aoff);
      const size_t boff = (size_t)(n0 + i*16 + lr) * 1024 + h*64 + kk*32 + ko*8;
      bH[i] = *(const f16x8*)(Kh + boff);
      bL[i] = *(const f16x8*)(Kl + boff);
    }
#pragma unroll
    for (int i = 0; i < 4; ++i)
#pragma unroll
      for (int j = 0; j < 4; ++j) {
        acc[i][j] = __builtin_amdgcn_mfma_f32_16x16x32_f16(aL[i], bL[j], acc[i][j], 0, 0, 0);
        acc[i][j] = __builtin_amdgcn_mfma_f32_16x16x32_f16(aH[i], bL[j], acc[i][j], 0, 0, 0);
        acc[i][j] = __builtin_amdgcn_mfma_f32_16x16x32_f16(aL[i], bH[j], acc[i][j], 0, 0, 0);
        acc[i][j] = __builtin_amdgcn_mfma_f32_16x16x32_f16(aH[i], bH[j], acc[i][j], 0, 0, 0);
      }
  }

  unsigned nb = 0;
#pragma unroll
  for (int i = 0; i < 4; ++i)
#pragma unroll
    for (int j = 0; j < 4; ++j)
#pragma unroll
      for (int r = 0; r < 4; ++r) {
        const float val = acc[i][j][r] * 0.125f;
        const unsigned u = sortkey(val);
        const unsigned bin = u >> 18;
        nb += (bin < lo) ? 1u : 0u;
        if (bin >= lo && bin <= hi) {
          atomicAdd(&lh9[bin - lo], 1u);
          unsigned id = atomicAdd(&lcnt, 1u);
          if (id < LCAP) lbuf[id] = u;
          else { unsigned g = atomicAdd(&ccnt[h], 1u); if (g < CAPC) mycand[g] = u; }
        }
      }
  // wave-reduce below-count, one LDS atomic per wave
  nb += __shfl_xor(nb, 1);  nb += __shfl_xor(nb, 2);
  nb += __shfl_xor(nb, 4);  nb += __shfl_xor(nb, 8);
  nb += __shfl_xor(nb, 16); nb += __shfl_xor(nb, 32);
  if (lane == 0) atomicAdd(&lbelow, nb);
  __syncthreads();
  if (threadIdx.x < 16) {
    const unsigned c = lh9[threadIdx.x];
    if (c) atomicAdd(&ghist9[h*16 + threadIdx.x], c);
  }
  if (threadIdx.x == 0 && lbelow) atomicAdd(&cntBelow[h], lbelow);
  const unsigned n = (lcnt < LCAP) ? lcnt : LCAP;
  if (threadIdx.x == 0) gbase = n ? atomicAdd(&ccnt[h], n) : 0u;
  __syncthreads();
  const unsigned gb = gbase;
  for (unsigned i = threadIdx.x; i < n; i += 512)
    if (gb + i < CAPC) mycand[gb + i] = lbuf[i];
}

// ---------------- scan over 9-bin range: exact binA/residA/binB/residB ----------------
__global__ __launch_bounds__(64) void scan9(const unsigned* __restrict__ ghist9,
                                            const unsigned* __restrict__ cntBelow,
                                            const unsigned* __restrict__ rangeLo,
                                            const unsigned* __restrict__ rangeHi,
                                            unsigned* __restrict__ ccnt,
                                            unsigned* __restrict__ state,
                                            unsigned* __restrict__ flag)
{
  const int hh = threadIdx.x;
  if (hh >= HH) return;
  const unsigned lo = rangeLo[hh], hi = rangeHi[hh];
  const int nbins = (int)(hi - lo + 1);
  const unsigned base = cntBelow[hh];
  unsigned ok = 0;
  unsigned binA = 0, residA = 0, binB = 0, residB = 0;
  if (K_A >= base) {
    unsigned k = K_A - base;
    unsigned cum = 0;
    for (int b = 0; b < nbins; ++b) {
      const unsigned c = ghist9[hh*16 + b];
      if (k < cum + c) {
        binA = lo + b;
        residA = k - cum;
        if (residA + 1 < c) { binB = binA; residB = residA + 1; ok = 1; }
        else {
          for (int b2 = b + 1; b2 < nbins; ++b2) {
            if (ghist9[hh*16 + b2]) { binB = lo + b2; residB = 0; ok = 1; break; }
          }
        }
        break;
      }
      cum += c;
    }
  }
  if (ccnt[hh] > CAPC) ok = 0;
  flag[hh] = ok;
  if (ok) {
    state[hh*4+0] = binA; state[hh*4+1] = residA;
    state[hh*4+2] = binB; state[hh*4+3] = residB;
  } else {
    ccnt[hh] = 0;   // fallback recollects cleanly
  }
}

// ---------------- fallback chain (early-exit when prediction held) ----------------
__global__ __launch_bounds__(512) void fb_scores_hist(const _Float16* __restrict__ Qh,
                                                      const _Float16* __restrict__ Ql,
                                                      const _Float16* __restrict__ Kh,
                                                      const _Float16* __restrict__ Kl,
                                                      const unsigned* __restrict__ flagArr,
                                                      unsigned* __restrict__ ghist)
{
  const int bn = blockIdx.x, bm = blockIdx.y, h = blockIdx.z;
  if (flagArr[h] != 0) return;
  const int wave = threadIdx.x >> 6, lane = threadIdx.x & 63;
  const int wr = wave >> 1, wc = wave & 1;
  const int m0 = bm * 256 + wr * 64;
  const int n0 = bn * 128 + wc * 64;
  const int lr = lane & 15;
  const int ko = lane >> 4;

  __shared__ unsigned lh[16384];   // 64 KB
  for (int i = threadIdx.x; i < 16384; i += 512) lh[i] = 0;
  __syncthreads();

  f32x4 acc[4][4];
#pragma unroll
  for (int i = 0; i < 4; ++i)
#pragma unroll
    for (int j = 0; j < 4; ++j) acc[i][j] = (f32x4){0.f, 0.f, 0.f, 0.f};

#pragma unroll
  for (int kk = 0; kk < 2; ++kk) {
    f16x8 aH[4], aL[4], bH[4], bL[4];
#pragma unroll
    for (int i = 0; i < 4; ++i) {
      const size_t aoff = (size_t)(m0 + i*16 + lr) * 1024 + h*64 + kk*32 + ko*8;
      aH[i] = *(const f16x8*)(Qh + aoff);
      aL[i] = *(const f16x8*)(Ql + aoff);
      const size_t boff = (size_t)(n0 + i*16 + lr) * 1024 + h*64 + kk*32 + ko*8;
      bH[i] = *(const f16x8*)(Kh + boff);
      bL[i] = *(const f16x8*)(Kl + boff);
    }
#pragma unroll
    for (int i = 0; i < 4; ++i)
#pragma unroll
      for (int j = 0; j < 4; ++j) {
        acc[i][j] = __builtin_amdgcn_mfma_f32_16x16x32_f16(aL[i], bL[j], acc[i][j], 0, 0, 0);
        acc[i][j] = __builtin_amdgcn_mfma_f32_16x16x32_f16(aH[i], bL[j], acc[i][j], 0, 0, 0);
        acc[i][j] = __builtin_amdgcn_mfma_f32_16x16x32_f16(aL[i], bH[j], acc[i][j], 0, 0, 0);
        acc[i][j] = __builtin_amdgcn_mfma_f32_16x16x32_f16(aH[i], bH[j], acc[i][j], 0, 0, 0);
      }
  }

#pragma unroll
  for (int i = 0; i < 4; ++i)
#pragma unroll
    for (int j = 0; j < 4; ++j)
#pragma unroll
      for (int r = 0; r < 4; ++r) {
        const float val = acc[i][j][r] * 0.125f;
        atomicAdd(&lh[sortkey(val) >> 18], 1u);
      }
  __syncthreads();
  unsigned* __restrict__ gh = ghist + (size_t)h * 16384;
  for (int i = threadIdx.x; i < 16384; i += 512) {
    const unsigned c = lh[i];
    if (c) atomicAdd(&gh[i], c);
  }
}

__global__ __launch_bounds__(256) void fb_scan14(const unsigned* __restrict__ ghist,
                                                 const unsigned* __restrict__ flagArr,
                                                 unsigned* __restrict__ state)
{
  const int hh = blockIdx.x;
  if (flagArr[hh] != 0) return;
  const int t = threadIdx.x;
  __shared__ unsigned part[256];
  __shared__ unsigned out[4];
  const unsigned* __restrict__ hb = ghist + (size_t)hh * 16384;
  unsigned s = 0;
  for (int j = 0; j < 64; ++j) s += hb[t*64 + j];
  part[t] = s;
  __syncthreads();
  if (t == 0) {
    unsigned run = 0;
    for (int i = 0; i < 256; ++i) { unsigned tmp = part[i]; part[i] = run; run += tmp; }
  }
  __syncthreads();
  const unsigned cum0 = part[t];
  if (K_A >= cum0 && K_A < cum0 + s) {
    unsigned c2 = cum0;
    for (int j = 0; j < 64; ++j) {
      const unsigned c = hb[t*64 + j];
      if (K_A < c2 + c) {
        const unsigned binA = t*64 + j;
        const unsigned residA = K_A - c2;
        unsigned binB, residB;
        if (residA + 1 < c) { binB = binA; residB = residA + 1; }
        else {
          unsigned bb = binA + 1;
          while (bb < 16384 && hb[bb] == 0) ++bb;
          if (bb >= 16384) bb = 16383;  // defensive
          binB = bb; residB = 0;
        }
        out[0] = binA; out[1] = residA; out[2] = binB; out[3] = residB;
        break;
      }
      c2 += c;
    }
  }
  __syncthreads();
  if (t < 4) state[hh*4 + t] = out[t];
}

__global__ __launch_bounds__(512) void fallback_compact(const _Float16* __restrict__ Qh,
                                                        const _Float16* __restrict__ Ql,
                                                        const _Float16* __restrict__ Kh,
                                                        const _Float16* __restrict__ Kl,
                                                        const unsigned* __restrict__ state,
                                                        const unsigned* __restrict__ flagArr,
                                                        unsigned* __restrict__ cand,
                                                        unsigned* __restrict__ ccnt)
{
  const int bn = blockIdx.x, bm = blockIdx.y, h = blockIdx.z;
  if (flagArr[h] != 0) return;
  const int wave = threadIdx.x >> 6, lane = threadIdx.x & 63;
  const int wr = wave >> 1, wc = wave & 1;
  const int m0 = bm * 256 + wr * 64;
  const int n0 = bn * 128 + wc * 64;
  const int lr = lane & 15;
  const int ko = lane >> 4;

  __shared__ unsigned lbuf[LCAP];
  __shared__ unsigned lcnt, gbase;
  if (threadIdx.x == 0) lcnt = 0;
  __syncthreads();
  const unsigned binA = state[h*4+0];
  const unsigned binB = state[h*4+2];
  unsigned* __restrict__ mycand = cand + (size_t)h * CAPC;

  f32x4 acc[4][4];
#pragma unroll
  for (int i = 0; i < 4; ++i)
#pragma unroll
    for (int j = 0; j < 4; ++j) acc[i][j] = (f32x4){0.f, 0.f, 0.f, 0.f};

#pragma unroll
  for (int kk = 0; kk < 2; ++kk) {
    f16x8 aH[4], aL[4], bH[4], bL[4];
#pragma unroll
    for (int i = 0; i < 4; ++i) {
      const size_t aoff = (size_t)(m0 + i*16 + lr) * 1024 + h*64 + kk*32 + ko*8;
      aH[i] = *(const f16x8*)(Qh + aoff);
      aL[i] = *(const f16x8*)(Ql + aoff);
      const size_t boff = (size_t)(n0 + i*16 + lr) * 1024 + h*64 + kk*32 + ko*8;
      bH[i] = *(const f16x8*)(Kh + boff);
      bL[i] = *(const f16x8*)(Kl + boff);
    }
#pragma unroll
    for (int i = 0; i < 4; ++i)
#pragma unroll
      for (int j = 0; j < 4; ++j) {
        acc[i][j] = __builtin_amdgcn_mfma_f32_16x16x32_f16(aL[i], bL[j], acc[i][j], 0, 0, 0);
        acc[i][j] = __builtin_amdgcn_mfma_f32_16x16x32_f16(aH[i], bL[j], acc[i][j], 0, 0, 0);
        acc[i][j] = __builtin_amdgcn_mfma_f32_16x16x32_f16(aL[i], bH[j], acc[i][j], 0, 0, 0);
        acc[i][j] = __builtin_amdgcn_mfma_f32_16x16x32_f16(aH[i], bH[j], acc[i][j], 0, 0, 0);
      }
  }

#pragma unroll
  for (int i = 0; i < 4; ++i)
#pragma unroll
    for (int j = 0; j < 4; ++j)
#pragma unroll
      for (int r = 0; r < 4; ++r) {
        const float val = acc[i][j][r] * 0.125f;
        const unsigned u = sortkey(val);
        const unsigned bin = u >> 18;
        if (bin == binA || bin == binB) {
          unsigned id = atomicAdd(&lcnt, 1u);
          if (id < LCAP) lbuf[id] = u;
          else { unsigned g = atomicAdd(&ccnt[h], 1u); if (g < CAPC) mycand[g] = u; }
        }
      }
  __syncthreads();
  const unsigned n = (lcnt < LCAP) ? lcnt : LCAP;
  if (threadIdx.x == 0) gbase = n ? atomicAdd(&ccnt[h], n) : 0u;
  __syncthreads();
  const unsigned gb = gbase;
  for (unsigned i = threadIdx.x; i < n; i += 512)
    if (gb + i < CAPC) mycand[gb + i] = lbuf[i];
}

// seed the parallel-final-select state after scan9/fallback resolved binA/binB
__global__ __launch_bounds__(64) void seed_fs(const unsigned* __restrict__ state,
                                              unsigned* __restrict__ sstate)
{
  const int t = threadIdx.x;
  if (t < HH * 4) sstate[t] = state[t];
}

// ---------------- parallel final select: 3 rounds of (hist over 32 blocks, scan) ----------------
__global__ __launch_bounds__(256) void fs_hist(const unsigned* __restrict__ cand,
                                               const unsigned* __restrict__ ccnt,
                                               const unsigned* __restrict__ sstate,
                                               unsigned* __restrict__ fhist,
                                               int s, int w)
{
  const int hh = blockIdx.y;
  const int t = threadIdx.x;
  const unsigned nb = 1u << w;
  __shared__ unsigned lh0[256], lh1[256];
  lh0[t] = 0; lh1[t] = 0;
  __syncthreads();
  const unsigned pfxA = sstate[hh*4+0];
  const unsigned pfxB = sstate[hh*4+2];
  unsigned n = ccnt[hh]; if (n > CAPC) n = CAPC;
  const unsigned* __restrict__ list = cand + (size_t)hh * CAPC;
  for (unsigned i = blockIdx.x * 256 + t; i < n; i += 32 * 256) {
    const unsigned u = list[i];
    if ((u >> (s + w)) == pfxA) atomicAdd(&lh0[(u >> s) & (nb - 1)], 1u);
    if ((u >> (s + w)) == pfxB) atomicAdd(&lh1[(u >> s) & (nb - 1)], 1u);
  }
  __syncthreads();
  if (t < (int)nb) {
    if (lh0[t]) atomicAdd(&fhist[hh*512 + t], lh0[t]);
    if (lh1[t]) atomicAdd(&fhist[hh*512 + 256 + t], lh1[t]);
  }
}

__global__ __launch_bounds__(256) void fs_scan(unsigned* __restrict__ fhist,
                                               unsigned* __restrict__ sstate,
                                               float* __restrict__ thr,
                                               int s, int w)
{
  const int hh = blockIdx.x;
  const int t = threadIdx.x;
  const unsigned nb = 1u << w;
  if (t == 0) {
    float vals[2];
    for (int tgt = 0; tgt < 2; ++tgt) {
      unsigned pfx = sstate[hh*4 + tgt*2];
      unsigned k   = sstate[hh*4 + tgt*2 + 1];
      const unsigned* hb = &fhist[hh*512 + tgt*256];
      unsigned cum = 0, b = 0;
      for (; b < nb; ++b) { const unsigned c = hb[b]; if (cum + c > k) break; cum += c; }
      if (b == nb) b = nb - 1;
      pfx = (pfx << w) | b;
      k -= cum;
      sstate[hh*4 + tgt*2]     = pfx;
      sstate[hh*4 + tgt*2 + 1] = k;
      if (s == 0) vals[tgt] = inv_sortkey(pfx);
    }
    if (s == 0) thr[hh] = vals[0] + QFRAC * (vals[1] - vals[0]);
  }
  __syncthreads();
  fhist[hh*512 + t] = 0;           // zero for next round
  fhist[hh*512 + 256 + t] = 0;
}

// ---------------- pass 3: flash softmax+PV, key-split over 2 halves ----------------
__global__ __launch_bounds__(256) void flash_pv_sk(const _Float16* __restrict__ Qh,
                                                   const _Float16* __restrict__ Ql,
                                                   const _Float16* __restrict__ Kh,
                                                   const _Float16* __restrict__ Kl,
                                                   const _Float16* __restrict__ VtH,
                                                   const _Float16* __restrict__ VtL,
                                                   const float* __restrict__ thrArr,
                                                   float* __restrict__ pctx,
                                                   float* __restrict__ prs)
{
  const int bm = blockIdx.x;          // 0..31 -> rows bm*64
  const int h  = blockIdx.y;
  const int half = blockIdx.z;        // 0..1
  const int wave = threadIdx.x >> 6, lane = threadIdx.x & 63;
  const int lr = lane & 15;
  const int ko = lane >> 4;
  const int m0 = bm * 64;
  const float thr = thrArr[h];

  __shared__ _Float16 Plds[64][136];  // pad 128->136
  __shared__ float rsLDS[64][4];

  // Q fragments are kt-invariant: hoist
  f16x8 qH[4][2], qL[4][2];
#pragma unroll
  for (int i = 0; i < 4; ++i)
#pragma unroll
    for (int kk = 0; kk < 2; ++kk) {
      const size_t aoff = (size_t)(m0 + i*16 + lr) * 1024 + h*64 + kk*32 + ko*8;
      qH[i][kk] = *(const f16x8*)(Qh + aoff);
      qL[i][kk] = *(const f16x8*)(Ql + aoff);
    }

  f32x4 oacc[4];
#pragma unroll
  for (int i = 0; i < 4; ++i) oacc[i] = (f32x4){0.f, 0.f, 0.f, 0.f};
  float rs[4][4];
#pragma unroll
  for (int i = 0; i < 4; ++i)
#pragma unroll
    for (int r = 0; r < 4; ++r) rs[i][r] = 0.f;

  const int d0 = wave * 16;   // PV: wave owns dims d0..d0+15

  for (int kt = half*8; kt < half*8 + 8; ++kt) {
    const int n0 = kt*128 + wave*32;   // S: wave owns keys n0..n0+31
    f32x4 sacc[4][2];
#pragma unroll
    for (int i = 0; i < 4; ++i)
#pragma unroll
      for (int j = 0; j < 2; ++j) sacc[i][j] = (f32x4){0.f, 0.f, 0.f, 0.f};

#pragma unroll
    for (int kk = 0; kk < 2; ++kk) {
      f16x8 bH[2], bL[2];
#pragma unroll
      for (int j = 0; j < 2; ++j) {
        const size_t boff = (size_t)(n0 + j*16 + lr) * 1024 + h*64 + kk*32 + ko*8;
        bH[j] = *(const f16x8*)(Kh + boff);
        bL[j] = *(const f16x8*)(Kl + boff);
      }
#pragma unroll
      for (int i = 0; i < 4; ++i)
#pragma unroll
        for (int j = 0; j < 2; ++j) {
          sacc[i][j] = __builtin_amdgcn_mfma_f32_16x16x32_f16(qL[i][kk], bL[j], sacc[i][j], 0, 0, 0);
          sacc[i][j] = __builtin_amdgcn_mfma_f32_16x16x32_f16(qH[i][kk], bL[j], sacc[i][j], 0, 0, 0);
          sacc[i][j] = __builtin_amdgcn_mfma_f32_16x16x32_f16(qL[i][kk], bH[j], sacc[i][j], 0, 0, 0);
          sacc[i][j] = __builtin_amdgcn_mfma_f32_16x16x32_f16(qH[i][kk], bH[j], sacc[i][j], 0, 0, 0);
        }
    }

    // mask + exp + P->LDS + rowsum partials
#pragma unroll
    for (int i = 0; i < 4; ++i)
#pragma unroll
      for (int j = 0; j < 2; ++j)
#pragma unroll
        for (int r = 0; r < 4; ++r) {
          const float val = sacc[i][j][r] * 0.125f;
          const float p = (val >= thr) ? __expf(val - thr - ESHIFT) : 0.f;
          rs[i][r] += p;
          Plds[i*16 + ko*4 + r][wave*32 + j*16 + lr] = (_Float16)p;
        }
    __syncthreads();

    // PV: oacc[i] over dims d0+lr, keys kt*128..+127
#pragma unroll
    for (int kk2 = 0; kk2 < 4; ++kk2) {
      f16x8 pa[4];
#pragma unroll
      for (int i = 0; i < 4; ++i)
        pa[i] = *(const f16x8*)&Plds[i*16 + lr][kk2*32 + ko*8];
      const size_t vo = (size_t)(h*64 + d0 + lr) * 2048 + kt*128 + kk2*32 + ko*8;
      const f16x8 vH = *(const f16x8*)(VtH + vo);
      const f16x8 vL = *(const f16x8*)(VtL + vo);
#pragma unroll
      for (int i = 0; i < 4; ++i) {
        oacc[i] = __builtin_amdgcn_mfma_f32_16x16x32_f16(pa[i], vL, oacc[i], 0, 0, 0);
        oacc[i] = __builtin_amdgcn_mfma_f32_16x16x32_f16(pa[i], vH, oacc[i], 0, 0, 0);
      }
    }
    __syncthreads();   // before next kt overwrites Plds
  }

  // rowsum: reduce across the 16 lanes of each ko-group, then across waves
#pragma unroll
  for (int i = 0; i < 4; ++i)
#pragma unroll
    for (int r = 0; r < 4; ++r) {
      float v = rs[i][r];
      v += __shfl_xor(v, 1); v += __shfl_xor(v, 2);
      v += __shfl_xor(v, 4); v += __shfl_xor(v, 8);
      rs[i][r] = v;
    }
  if (lr == 0) {
#pragma unroll
    for (int i = 0; i < 4; ++i)
#pragma unroll
      for (int r = 0; r < 4; ++r)
        rsLDS[i*16 + ko*4 + r][wave] = rs[i][r];
  }
  __syncthreads();

  // write partial rowsums
  if (wave == 0 && lr == 0) {
#pragma unroll
    for (int i = 0; i < 4; ++i)
#pragma unroll
      for (int r = 0; r < 4; ++r) {
        const int lrow = i*16 + ko*4 + r;
        prs[half*32768 + h*2048 + m0 + lrow] =
            rsLDS[lrow][0] + rsLDS[lrow][1] + rsLDS[lrow][2] + rsLDS[lrow][3];
      }
  }

  // store raw partial O
  float* __restrict__ pc = pctx + (size_t)half * PLANE;
#pragma unroll
  for (int i = 0; i < 4; ++i)
#pragma unroll
    for (int r = 0; r < 4; ++r) {
      const int lrow = i*16 + ko*4 + r;
      pc[(size_t)(m0 + lrow) * 1024 + h*64 + d0 + lr] = oacc[i][r];
    }
}

// ---------------- host ----------------
extern "C" void kernel_launch(void* const* d_in, const int* in_sizes, int n_in,
                              void* d_out, int out_size, void* d_ws, size_t ws_size,
                              hipStream_t stream)
{
  const float* x  = (const float*)d_in[0];
  const float* Wq = (const float*)d_in[1];
  const float* bq = (const float*)d_in[2];
  const float* Wk = (const float*)d_in[3];
  const float* bk = (const float*)d_in[4];
  const float* Wv = (const float*)d_in[5];
  const float* bv = (const float*)d_in[6];
  const float* Wo = (const float*)d_in[7];
  const float* bo = (const float*)d_in[8];
  float* out = (float*)d_out;
  char*  ws  = (char*)d_ws;

  const size_t MB = 1u << 20;
  _Float16* xh      = (_Float16*)(ws + 0*MB);
  _Float16* xl      = (_Float16*)(ws + 4*MB);
  _Float16* wplanes = (_Float16*)(ws + 8*MB);    // 8 x 2 MiB transposed W planes
  _Float16* Qh      = (_Float16*)(ws + 24*MB);
  _Float16* Ql      = (_Float16*)(ws + 28*MB);
  _Float16* Kh      = (_Float16*)(ws + 32*MB);
  _Float16* Kl      = (_Float16*)(ws + 36*MB);
  _Float16* VtH     = (_Float16*)(ws + 40*MB);   // [1024 dims][2048 rows]
  _Float16* VtL     = (_Float16*)(ws + 44*MB);
  _Float16* ctxh    = (_Float16*)(ws + 48*MB);
  _Float16* ctxl    = (_Float16*)(ws + 52*MB);
  const size_t base = 56*MB;
  unsigned* state    = (unsigned*)(ws + base);
  float*    thr      = (float*)(ws + base + 4096);
  unsigned* ccnt     = (unsigned*)(ws + base + 8192);
  unsigned* flag     = (unsigned*)(ws + base + 12288);
  unsigned* rangeLo  = (unsigned*)(ws + base + 16384);
  unsigned* rangeHi  = (unsigned*)(ws + base + 20480);
  unsigned* sstate   = (unsigned*)(ws + base + 24576);
  unsigned* fhist    = (unsigned*)(ws + base + 28672);  // HH*512*4 = 32 KiB
  unsigned* cntBelow = (unsigned*)(ws + base + 65536);
  unsigned* ghist9   = (unsigned*)(ws + base + 69632);  // HH*16 u32
  unsigned* ghist    = (unsigned*)(ws + 57*MB);   // 1 MiB (fallback only)
  unsigned* shist    = (unsigned*)(ws + 58*MB);   // 1 MiB
  unsigned* cand     = (unsigned*)(ws + 59*MB);   // HH * CAPC * 4 = 20 MiB
  float*    prs      = (float*)(ws + 80*MB);      // 2 x 16 x 2048 f32
  float*    pbuf     = (float*)(ws + 81*MB);      // 6 x 8 MiB partials
  float*    pctx     = pbuf;                      // planes 0,1 (post combine_qk)
  float*    pO       = pbuf + (size_t)2 * PLANE;  // planes 2,3

  split_x<<<2048, 256, 0, stream>>>(x, xh, xl);
  split_wT<<<dim3(16, 16, 4), 256, 0, stream>>>(Wq, Wk, Wv, Wo, wplanes);
  gemm_qkv_part<<<dim3(8, 16, 6), 256, 0, stream>>>(xh, xl, wplanes, pbuf);
  combine_qk<<<dim3(2048, 2), 256, 0, stream>>>(pbuf, bq, bk, Qh, Ql, Kh, Kl);
  combine_vT<<<dim3(16, 32), 256, 0, stream>>>(pbuf, bv, VtH, VtL);

  init_sel<<<256, 256, 0, stream>>>(ghist, shist, ccnt, flag, fhist, cntBelow, ghist9);
  sample_hist<<<dim3(16, HH), 256, 0, stream>>>(Qh, Ql, Kh, Kl, shist);
  sample_scan<<<HH, 256, 0, stream>>>(shist, rangeLo, rangeHi);
  range_count<<<dim3(16, 8, HH), 512, 0, stream>>>(Qh, Ql, Kh, Kl, rangeLo, rangeHi,
                                                   cand, ccnt, cntBelow, ghist9);
  scan9<<<1, 64, 0, stream>>>(ghist9, cntBelow, rangeLo, rangeHi, ccnt, state, flag);
  // fallback chain (early-exit per head when prediction held)
  fb_scores_hist<<<dim3(16, 8, HH), 512, 0, stream>>>(Qh, Ql, Kh, Kl, flag, ghist);
  fb_scan14<<<HH, 256, 0, stream>>>(ghist, flag, state);
  fallback_compact<<<dim3(16, 8, HH), 512, 0, stream>>>(Qh, Ql, Kh, Kl, state, flag, cand, ccnt);
  seed_fs<<<1, 64, 0, stream>>>(state, sstate);
  // parallel final select: rounds (s,w) = (10,8), (2,8), (0,2)
  fs_hist<<<dim3(32, HH), 256, 0, stream>>>(cand, ccnt, sstate, fhist, 10, 8);
  fs_scan<<<HH, 256, 0, stream>>>(fhist, sstate, thr, 10, 8);
  fs_hist<<<dim3(32, HH), 256, 0, stream>>>(cand, ccnt, sstate, fhist, 2, 8);
  fs_scan<<<HH, 256, 0, stream>>>(fhist, sstate, thr, 2, 8);
  fs_hist<<<dim3(32, HH), 256, 0, stream>>>(cand, ccnt, sstate, fhist, 0, 2);
  fs_scan<<<HH, 256, 0, stream>>>(fhist, sstate, thr, 0, 2);

  flash_pv_sk<<<dim3(32, HH, 2), 256, 0, stream>>>(Qh, Ql, Kh, Kl, VtH, VtL, thr, pctx, prs);
  combine_ctx<<<2048, 256, 0, stream>>>(pctx, prs, ctxh, ctxl);

  gemm_o_part<<<dim3(8, 16, 2), 256, 0, stream>>>(ctxh, ctxl, wplanes, pO);
  combine_o<<<2048, 256, 0, stream>>>(pO, bo, out);
}

// Round 22
// 525.883 us; speedup vs baseline: 1.1219x; 1.0233x over previous
//
#include <hip/hip_runtime.h>
#include <math.h>

#define SS 2048
#define DD 1024
#define HH 16
#define CAPC 327680u  // candidate slots per head (range ~5 bins x ~16K/bin ~ 83K expected)
#define LCAP 2048     // per-block LDS candidate buffer (expected ~670/block)
#define RBIN 2        // predicted-bin safety margin (sampling sigma ~0.16 bins -> 12.5 sigma)

// quantile index: floor(0.95*(S*S-1)) = floor(3984587.85)
#define K_A 3984587u
#define K_B 3984588u
#define QFRAC 0.85f
#define WSCALE 2048.0f      // W planes pre-scaled so lo-residuals stay normal fp16
#define WSCALE_INV (1.0f/2048.0f)
#define ESHIFT 4.0f         // exp(s - thr - ESHIFT): kept P in [e^-4, ~e^6] — fp16-safe
#define PLANE 2097152       // floats per 2048x1024 fp32 partial plane (8 MiB)
#define NSAMP_RANK 124518u  // floor(0.95 * 131072) — sample quantile rank

typedef _Float16 f16x8 __attribute__((ext_vector_type(8)));
typedef _Float16 f16x4 __attribute__((ext_vector_type(4)));
typedef float    f32x4 __attribute__((ext_vector_type(4)));

__device__ __forceinline__ unsigned sortkey(float f) {
  unsigned b = __float_as_uint(f);
  return (b & 0x80000000u) ? ~b : (b | 0x80000000u);
}
__device__ __forceinline__ float inv_sortkey(unsigned u) {
  unsigned b = (u & 0x80000000u) ? (u ^ 0x80000000u) : ~u;
  return __uint_as_float(b);
}

// ---------------- input splitting ----------------
__global__ __launch_bounds__(256) void split_x(const float* __restrict__ x,
                                               _Float16* __restrict__ xh,
                                               _Float16* __restrict__ xl)
{
  const int i = blockIdx.x * 256 + threadIdx.x;   // float4 index, 524288 total
  float4 v = ((const float4*)x)[i];
  float vv[4] = {v.x, v.y, v.z, v.w};
  f16x4 h, l;
#pragma unroll
  for (int j = 0; j < 4; ++j) {
    _Float16 hh = (_Float16)vv[j];
    h[j] = hh;
    l[j] = (_Float16)(vv[j] - (float)hh);
  }
  ((f16x4*)xh)[i] = h;
  ((f16x4*)xl)[i] = l;
}

// W -> transposed hi/lo fp16 planes WT[n][k], scaled by 2048 (keeps lo normal).
__global__ __launch_bounds__(256) void split_wT(const float* __restrict__ Wq,
                                                const float* __restrict__ Wk,
                                                const float* __restrict__ Wv,
                                                const float* __restrict__ Wo,
                                                _Float16* __restrict__ wplanes)
{
  const int z = blockIdx.z;
  const float* W = (z == 0) ? Wq : (z == 1) ? Wk : (z == 2) ? Wv : Wo;
  _Float16* WhT = wplanes + (size_t)(2*z)     * (1024*1024);
  _Float16* WlT = wplanes + (size_t)(2*z + 1) * (1024*1024);
  __shared__ float tile[64][65];
  const int t  = threadIdx.x;
  const int r  = t >> 2;         // 0..63
  const int c0 = (t & 3) * 16;   // 0/16/32/48
  const int k0 = blockIdx.y * 64;
  const int n0 = blockIdx.x * 64;
#pragma unroll
  for (int j = 0; j < 4; ++j) {
    float4 v = *(const float4*)&W[(size_t)(k0 + r) * 1024 + n0 + c0 + j*4];
    tile[r][c0+j*4+0] = v.x; tile[r][c0+j*4+1] = v.y;
    tile[r][c0+j*4+2] = v.z; tile[r][c0+j*4+3] = v.w;
  }
  __syncthreads();
  f16x8 h0, h1, l0, l1;
#pragma unroll
  for (int j = 0; j < 8; ++j) {
    float v = tile[c0 + j][r] * WSCALE;
    _Float16 h = (_Float16)v;
    h0[j] = h; l0[j] = (_Float16)(v - (float)h);
  }
#pragma unroll
  for (int j = 0; j < 8; ++j) {
    float v = tile[c0 + 8 + j][r] * WSCALE;
    _Float16 h = (_Float16)v;
    h1[j] = h; l1[j] = (_Float16)(v - (float)h);
  }
  const size_t o = (size_t)(n0 + r) * 1024 + k0 + c0;
  *(f16x8*)&WhT[o]     = h0;
  *(f16x8*)&WhT[o + 8] = h1;
  *(f16x8*)&WlT[o]     = l0;
  *(f16x8*)&WlT[o + 8] = l1;
}

// ---------------- split-K MFMA GEMM partial ----------------
__device__ __forceinline__ void gemm_mfma_part(const _Float16* __restrict__ Ah,
                                               const _Float16* __restrict__ Al,
                                               const _Float16* __restrict__ BhT,
                                               const _Float16* __restrict__ BlT,
                                               float* __restrict__ pout,
                                               int bm, int bn, int kh)
{
  const int wave = threadIdx.x >> 6, lane = threadIdx.x & 63;
  const int wr = wave >> 1, wc = wave & 1;
  const int m0 = bm * 128 + wr * 64;
  const int n0 = bn * 128 + wc * 64;
  const int lr = lane & 15;
  const int ko = lane >> 4;

  f32x4 acc[4][4];
#pragma unroll
  for (int i = 0; i < 4; ++i)
#pragma unroll
    for (int j = 0; j < 4; ++j) acc[i][j] = (f32x4){0.f, 0.f, 0.f, 0.f};

  for (int kk = kh*16; kk < kh*16 + 16; ++kk) {
    const int kof = kk*32 + ko*8;
    f16x8 aH[4], aL[4], bH[4], bL[4];
#pragma unroll
    for (int i = 0; i < 4; ++i) {
      const size_t aoff = (size_t)(m0 + i*16 + lr) * 1024 + kof;
      aH[i] = *(const f16x8*)(Ah + aoff);
      aL[i] = *(const f16x8*)(Al + aoff);
      const size_t boff = (size_t)(n0 + i*16 + lr) * 1024 + kof;
      bH[i] = *(const f16x8*)(BhT + boff);
      bL[i] = *(const f16x8*)(BlT + boff);
    }
#pragma unroll
    for (int i = 0; i < 4; ++i)
#pragma unroll
      for (int j = 0; j < 4; ++j) {
        acc[i][j] = __builtin_amdgcn_mfma_f32_16x16x32_f16(aL[i], bL[j], acc[i][j], 0, 0, 0);
        acc[i][j] = __builtin_amdgcn_mfma_f32_16x16x32_f16(aH[i], bL[j], acc[i][j], 0, 0, 0);
        acc[i][j] = __builtin_amdgcn_mfma_f32_16x16x32_f16(aL[i], bH[j], acc[i][j], 0, 0, 0);
        acc[i][j] = __builtin_amdgcn_mfma_f32_16x16x32_f16(aH[i], bH[j], acc[i][j], 0, 0, 0);
      }
  }

#pragma unroll
  for (int i = 0; i < 4; ++i)
#pragma unroll
    for (int j = 0; j < 4; ++j)
#pragma unroll
      for (int r = 0; r < 4; ++r) {
        const int row = m0 + i*16 + ko*4 + r;
        const int col = n0 + j*16 + lr;
        pout[(size_t)row * 1024 + col] = acc[i][j][r];
      }
}

__global__ __launch_bounds__(256) void gemm_qkv_part(const _Float16* __restrict__ xh,
                                                     const _Float16* __restrict__ xl,
                                                     const _Float16* __restrict__ wplanes,
                                                     float* __restrict__ pbuf)
{
  const int z = blockIdx.z;           // 0..5: gemm_id*2 + khalf
  const int g = z >> 1, kh = z & 1;
  const _Float16* BhT = wplanes + (size_t)(2*g)     * (1024*1024);
  const _Float16* BlT = wplanes + (size_t)(2*g + 1) * (1024*1024);
  gemm_mfma_part(xh, xl, BhT, BlT, pbuf + (size_t)z * PLANE,
                 blockIdx.y, blockIdx.x, kh);
}

__global__ __launch_bounds__(256) void gemm_o_part(const _Float16* __restrict__ ctxh,
                                                   const _Float16* __restrict__ ctxl,
                                                   const _Float16* __restrict__ wplanes,
                                                   float* __restrict__ pO)
{
  const int kh = blockIdx.z;          // 0..1
  gemm_mfma_part(ctxh, ctxl,
                 wplanes + (size_t)6 * (1024*1024),
                 wplanes + (size_t)7 * (1024*1024),
                 pO + (size_t)kh * PLANE, blockIdx.y, blockIdx.x, kh);
}

// ---------------- combine kernels ----------------
__global__ __launch_bounds__(256) void combine_qk(const float* __restrict__ pbuf,
                                                  const float* __restrict__ bq,
                                                  const float* __restrict__ bk,
                                                  _Float16* __restrict__ Qh,
                                                  _Float16* __restrict__ Ql,
                                                  _Float16* __restrict__ Kh,
                                                  _Float16* __restrict__ Kl)
{
  const int which = blockIdx.y;       // 0=Q, 1=K
  const float* p0 = pbuf + (size_t)(which*2)     * PLANE;
  const float* p1 = pbuf + (size_t)(which*2 + 1) * PLANE;
  const float* bias = which ? bk : bq;
  _Float16* Oh = which ? Kh : Qh;
  _Float16* Ol = which ? Kl : Ql;
  const int i = blockIdx.x * 256 + threadIdx.x;   // f4 index, 524288
  const int coloff = (i & 255) * 4;
  float4 a = ((const float4*)p0)[i];
  float4 b = ((const float4*)p1)[i];
  float av[4] = {a.x, a.y, a.z, a.w};
  float bv[4] = {b.x, b.y, b.z, b.w};
  f16x4 h, l;
#pragma unroll
  for (int j = 0; j < 4; ++j) {
    const float val = (av[j] + bv[j]) * WSCALE_INV + bias[coloff + j];
    _Float16 hh = (_Float16)val;
    h[j] = hh;
    l[j] = (_Float16)(val - (float)hh);
  }
  ((f16x4*)Oh)[i] = h;
  ((f16x4*)Ol)[i] = l;
}

// V: combine + transpose to Vt[dim][row] hi/lo planes (LDS 64x64 tile).
__global__ __launch_bounds__(256) void combine_vT(const float* __restrict__ pbuf,
                                                  const float* __restrict__ bv,
                                                  _Float16* __restrict__ VtH,
                                                  _Float16* __restrict__ VtL)
{
  const float* p0 = pbuf + (size_t)4 * PLANE;
  const float* p1 = pbuf + (size_t)5 * PLANE;
  __shared__ float tile[64][65];
  const int t  = threadIdx.x;
  const int d0 = blockIdx.x * 64;     // dim tile
  const int m0 = blockIdx.y * 64;     // row tile
  {
    const int r  = t >> 2;            // row 0..63
    const int c0 = (t & 3) * 16;
#pragma unroll
    for (int j = 0; j < 4; ++j) {
      const size_t o = (size_t)(m0 + r) * 1024 + d0 + c0 + j*4;
      float4 a = *(const float4*)(p0 + o);
      float4 b = *(const float4*)(p1 + o);
      tile[r][c0+j*4+0] = (a.x + b.x) * WSCALE_INV + bv[d0 + c0 + j*4 + 0];
      tile[r][c0+j*4+1] = (a.y + b.y) * WSCALE_INV + bv[d0 + c0 + j*4 + 1];
      tile[r][c0+j*4+2] = (a.z + b.z) * WSCALE_INV + bv[d0 + c0 + j*4 + 2];
      tile[r][c0+j*4+3] = (a.w + b.w) * WSCALE_INV + bv[d0 + c0 + j*4 + 3];
    }
  }
  __syncthreads();
  {
    const int d  = t >> 2;            // dim 0..63
    const int rg = (t & 3) * 16;      // row group
#pragma unroll
    for (int j = 0; j < 4; ++j) {
      f16x4 hv, lv;
#pragma unroll
      for (int r = 0; r < 4; ++r) {
        const float val = tile[rg + j*4 + r][d];
        _Float16 h = (_Float16)val;
        hv[r] = h; lv[r] = (_Float16)(val - (float)h);
      }
      const size_t o = (size_t)(d0 + d) * 2048 + m0 + rg + j*4;
      *(f16x4*)&VtH[o] = hv;
      *(f16x4*)&VtL[o] = lv;
    }
  }
}

__global__ __launch_bounds__(256) void combine_o(const float* __restrict__ pO,
                                                 const float* __restrict__ bo,
                                                 float* __restrict__ out)
{
  const float* p0 = pO;
  const float* p1 = pO + (size_t)1 * PLANE;
  const int i = blockIdx.x * 256 + threadIdx.x;
  const int coloff = (i & 255) * 4;
  float4 a = ((const float4*)p0)[i];
  float4 b = ((const float4*)p1)[i];
  float4 o;
  o.x = (a.x + b.x) * WSCALE_INV + bo[coloff + 0];
  o.y = (a.y + b.y) * WSCALE_INV + bo[coloff + 1];
  o.z = (a.z + b.z) * WSCALE_INV + bo[coloff + 2];
  o.w = (a.w + b.w) * WSCALE_INV + bo[coloff + 3];
  ((float4*)out)[i] = o;
}

// ctx: (p0+p1) / (rs0+rs1), then fp16 hi/lo split.
__global__ __launch_bounds__(256) void combine_ctx(const float* __restrict__ pctx,
                                                   const float* __restrict__ prs,
                                                   _Float16* __restrict__ ctxh,
                                                   _Float16* __restrict__ ctxl)
{
  const float* p0 = pctx;
  const float* p1 = pctx + (size_t)1 * PLANE;
  const int i = blockIdx.x * 256 + threadIdx.x;   // f4 index, 524288
  const int row = i >> 8;
  const int cd  = (i & 255) * 4;
  const int h   = cd >> 6;
  const float rs = prs[h*2048 + row] + prs[32768 + h*2048 + row];
  float4 a = ((const float4*)p0)[i];
  float4 b = ((const float4*)p1)[i];
  float av[4] = {a.x, a.y, a.z, a.w};
  float bv[4] = {b.x, b.y, b.z, b.w};
  f16x4 hh, ll;
#pragma unroll
  for (int j = 0; j < 4; ++j) {
    const float val = (av[j] + bv[j]) / rs;
    _Float16 hv = (_Float16)val;
    hh[j] = hv;
    ll[j] = (_Float16)(val - (float)hv);
  }
  ((f16x4*)ctxh)[i] = hh;
  ((f16x4*)ctxl)[i] = ll;
}

// ---------------- selection init ----------------
__global__ __launch_bounds__(256) void init_sel(unsigned* __restrict__ ghist,
                                                unsigned* __restrict__ shist,
                                                unsigned* __restrict__ ccnt,
                                                unsigned* __restrict__ flag,
                                                unsigned* __restrict__ fhist,
                                                unsigned* __restrict__ cntBelow,
                                                unsigned* __restrict__ ghist9)
{
  int i = blockIdx.x * 256 + threadIdx.x;
  for (; i < HH * 16384; i += gridDim.x * 256) { ghist[i] = 0; shist[i] = 0; }
  const int j = blockIdx.x * 256 + threadIdx.x;
  if (j < HH * 512) fhist[j] = 0;
  if (j < HH * 16) ghist9[j] = 0;
  if (blockIdx.x == 0 && threadIdx.x < HH) {
    ccnt[threadIdx.x] = 0; flag[threadIdx.x] = 0; cntBelow[threadIdx.x] = 0;
  }
}

// ---------------- sampling pass: 64 of 2048 query rows (stride 32) ----------------
__global__ __launch_bounds__(256) void sample_hist(const _Float16* __restrict__ Qh,
                                                   const _Float16* __restrict__ Ql,
                                                   const _Float16* __restrict__ Kh,
                                                   const _Float16* __restrict__ Kl,
                                                   unsigned* __restrict__ shist)
{
  const int kb = blockIdx.x, h = blockIdx.y;
  const int wave = threadIdx.x >> 6, lane = threadIdx.x & 63;
  const int lr = lane & 15, ko = lane >> 4;
  const int n0 = kb*128 + wave*32;

  __shared__ unsigned lh[16384];   // 64 KB
  for (int i = threadIdx.x; i < 16384; i += 256) lh[i] = 0;
  __syncthreads();

  f32x4 acc[4][2];
#pragma unroll
  for (int i = 0; i < 4; ++i)
#pragma unroll
    for (int j = 0; j < 2; ++j) acc[i][j] = (f32x4){0.f, 0.f, 0.f, 0.f};

#pragma unroll
  for (int kk = 0; kk < 2; ++kk) {
    f16x8 aH[4], aL[4], bH[2], bL[2];
#pragma unroll
    for (int i = 0; i < 4; ++i) {
      const size_t aoff = (size_t)((i*16 + lr) * 32) * 1024 + h*64 + kk*32 + ko*8;
      aH[i] = *(const f16x8*)(Qh + aoff);
      aL[i] = *(const f16x8*)(Ql + aoff);
    }
#pragma unroll
    for (int j = 0; j < 2; ++j) {
      const size_t boff = (size_t)(n0 + j*16 + lr) * 1024 + h*64 + kk*32 + ko*8;
      bH[j] = *(const f16x8*)(Kh + boff);
      bL[j] = *(const f16x8*)(Kl + boff);
    }
#pragma unroll
    for (int i = 0; i < 4; ++i)
#pragma unroll
      for (int j = 0; j < 2; ++j) {
        acc[i][j] = __builtin_amdgcn_mfma_f32_16x16x32_f16(aL[i], bL[j], acc[i][j], 0, 0, 0);
        acc[i][j] = __builtin_amdgcn_mfma_f32_16x16x32_f16(aH[i], bL[j], acc[i][j], 0, 0, 0);
        acc[i][j] = __builtin_amdgcn_mfma_f32_16x16x32_f16(aL[i], bH[j], acc[i][j], 0, 0, 0);
        acc[i][j] = __builtin_amdgcn_mfma_f32_16x16x32_f16(aH[i], bH[j], acc[i][j], 0, 0, 0);
      }
  }

#pragma unroll
  for (int i = 0; i < 4; ++i)
#pragma unroll
    for (int j = 0; j < 2; ++j)
#pragma unroll
      for (int r = 0; r < 4; ++r) {
        const float val = acc[i][j][r] * 0.125f;
        atomicAdd(&lh[sortkey(val) >> 18], 1u);
      }
  __syncthreads();
  unsigned* __restrict__ gh = shist + (size_t)h * 16384;
  for (int i = threadIdx.x; i < 16384; i += 256) {
    const unsigned c = lh[i];
    if (c) atomicAdd(&gh[i], c);
  }
}

// find sample-quantile bin; emit conservative range [bin-RBIN, bin+RBIN]
__global__ __launch_bounds__(256) void sample_scan(const unsigned* __restrict__ shist,
                                                   unsigned* __restrict__ rangeLo,
                                                   unsigned* __restrict__ rangeHi)
{
  const int hh = blockIdx.x;
  const int t = threadIdx.x;
  __shared__ unsigned part[256];
  __shared__ unsigned outb;
  if (t == 0) outb = 8192u;  // defensive default
  const unsigned* __restrict__ hb = shist + (size_t)hh * 16384;
  unsigned s = 0;
  for (int j = 0; j < 64; ++j) s += hb[t*64 + j];
  part[t] = s;
  __syncthreads();
  if (t == 0) {
    unsigned run = 0;
    for (int i = 0; i < 256; ++i) { unsigned tmp = part[i]; part[i] = run; run += tmp; }
  }
  __syncthreads();
  const unsigned cum0 = part[t];
  if (NSAMP_RANK >= cum0 && NSAMP_RANK < cum0 + s) {
    unsigned c2 = cum0;
    for (int j = 0; j < 64; ++j) {
      const unsigned c = hb[t*64 + j];
      if (NSAMP_RANK < c2 + c) { outb = t*64 + j; break; }
      c2 += c;
    }
  }
  __syncthreads();
  if (t == 0) {
    const int b = (int)outb;
    rangeLo[hh] = (unsigned)((b - RBIN < 0) ? 0 : b - RBIN);
    rangeHi[hh] = (unsigned)((b + RBIN > 16383) ? 16383 : b + RBIN);
  }
}

// ---------------- pass 1: count-below + 5-bin range histogram + compaction ----------------
// r17-measured-best structure; RBIN=2 halves the in-range fraction (~1.9%).
__global__ __launch_bounds__(512) void range_count(const _Float16* __restrict__ Qh,
                                                   const _Float16* __restrict__ Ql,
                                                   const _Float16* __restrict__ Kh,
                                                   const _Float16* __restrict__ Kl,
                                                   const unsigned* __restrict__ rangeLo,
                                                   const unsigned* __restrict__ rangeHi,
                                                   unsigned* __restrict__ cand,
                                                   unsigned* __restrict__ ccnt,
                                                   unsigned* __restrict__ cntBelow,
                                                   unsigned* __restrict__ ghist9)
{
  const int bn = blockIdx.x, bm = blockIdx.y, h = blockIdx.z;
  const int wave = threadIdx.x >> 6, lane = threadIdx.x & 63;
  const int wr = wave >> 1, wc = wave & 1;
  const int m0 = bm * 256 + wr * 64;
  const int n0 = bn * 128 + wc * 64;
  const int lr = lane & 15;
  const int ko = lane >> 4;
  const unsigned lo = rangeLo[h], hi = rangeHi[h];
  unsigned* __restrict__ mycand = cand + (size_t)h * CAPC;

  __shared__ unsigned lh9[16];
  __shared__ unsigned lbuf[LCAP];  // 8 KB
  __shared__ unsigned lcnt, gbase, lbelow;
  if (threadIdx.x < 16) lh9[threadIdx.x] = 0;
  if (threadIdx.x == 0) { lcnt = 0; lbelow = 0; }
  __syncthreads();

  f32x4 acc[4][4];
#pragma unroll
  for (int i = 0; i < 4; ++i)
#pragma unroll
    for (int j = 0; j < 4; ++j) acc[i][j] = (f32x4){0.f, 0.f, 0.f, 0.f};

#pragma unroll
  for (int kk = 0; kk < 2; ++kk) {
    f16x8 aH[4], aL[4], bH[4], bL[4];
#pragma unroll
    for (int i = 0; i < 4; ++i) {
      const size_t aoff = (size_t)(m0 + i*16 + lr) * 1024 + h*64 + kk*32 + ko*8;
      aH[i] = *(const f16x8*)(Qh + aoff);
      aL[i] = *(const f16x8*)(Ql + aoff);
      const size_t boff = (size_t)(n0 + i*16 + lr) * 1024 + h*64 + kk*32 + ko*8;
      bH[i] = *(const f16x8*)(Kh + boff);
      bL[i] = *(const f16x8*)(Kl + boff);
    }
#pragma unroll
    for (int i = 0; i < 4; ++i)
#pragma unroll
      for (int j = 0; j < 4; ++j) {
        acc[i][j] = __builtin_amdgcn_mfma_f32_16x16x32_f16(aL[i], bL[j], acc[i][j], 0, 0, 0);
        acc[i][j] = __builtin_amdgcn_mfma_f32_16x16x32_f16(aH[i], bL[j], acc[i][j], 0, 0, 0);
        acc[i][j] = __builtin_amdgcn_mfma_f32_16x16x32_f16(aL[i], bH[j], acc[i][j], 0, 0, 0);
        acc[i][j] = __builtin_amdgcn_mfma_f32_16x16x32_f16(aH[i], bH[j], acc[i][j], 0, 0, 0);
      }
  }

  unsigned nb = 0;
#pragma unroll
  for (int i = 0; i < 4; ++i)
#pragma unroll
    for (int j = 0; j < 4; ++j)
#pragma unroll
      for (int r = 0; r < 4; ++r) {
        const float val = acc[i][j][r] * 0.125f;
        const unsigned u = sortkey(val);
        const unsigned bin = u >> 18;
        nb += (bin < lo) ? 1u : 0u;
        if (bin >= lo && bin <= hi) {
          atomicAdd(&lh9[bin - lo], 1u);
          unsigned id = atomicAdd(&lcnt, 1u);
          if (id < LCAP) lbuf[id] = u;
          else { unsigned g = atomicAdd(&ccnt[h], 1u); if (g < CAPC) mycand[g] = u; }
        }
      }
  // wave-reduce below-count, one LDS atomic per wave
  nb += __shfl_xor(nb, 1);  nb += __shfl_xor(nb, 2);
  nb += __shfl_xor(nb, 4);  nb += __shfl_xor(nb, 8);
  nb += __shfl_xor(nb, 16); nb += __shfl_xor(nb, 32);
  if (lane == 0) atomicAdd(&lbelow, nb);
  __syncthreads();
  if (threadIdx.x < 16) {
    const unsigned c = lh9[threadIdx.x];
    if (c) atomicAdd(&ghist9[h*16 + threadIdx.x], c);
  }
  if (threadIdx.x == 0 && lbelow) atomicAdd(&cntBelow[h], lbelow);
  const unsigned n = (lcnt < LCAP) ? lcnt : LCAP;
  if (threadIdx.x == 0) gbase = n ? atomicAdd(&ccnt[h], n) : 0u;
  __syncthreads();
  const unsigned gb = gbase;
  for (unsigned i = threadIdx.x; i < n; i += 512)
    if (gb + i < CAPC) mycand[gb + i] = lbuf[i];
}

// ---------------- scan over range: exact binA/residA/binB/residB ----------------
__global__ __launch_bounds__(64) void scan9(const unsigned* __restrict__ ghist9,
                                            const unsigned* __restrict__ cntBelow,
                                            const unsigned* __restrict__ rangeLo,
                                            const unsigned* __restrict__ rangeHi,
                                            unsigned* __restrict__ ccnt,
                                            unsigned* __restrict__ state,
                                            unsigned* __restrict__ flag)
{
  const int hh = threadIdx.x;
  if (hh >= HH) return;
  const unsigned lo = rangeLo[hh], hi = rangeHi[hh];
  const int nbins = (int)(hi - lo + 1);
  const unsigned base = cntBelow[hh];
  unsigned ok = 0;
  unsigned binA = 0, residA = 0, binB = 0, residB = 0;
  if (K_A >= base) {
    unsigned k = K_A - base;
    unsigned cum = 0;
    for (int b = 0; b < nbins; ++b) {
      const unsigned c = ghist9[hh*16 + b];
      if (k < cum + c) {
        binA = lo + b;
        residA = k - cum;
        if (residA + 1 < c) { binB = binA; residB = residA + 1; ok = 1; }
        else {
          for (int b2 = b + 1; b2 < nbins; ++b2) {
            if (ghist9[hh*16 + b2]) { binB = lo + b2; residB = 0; ok = 1; break; }
          }
        }
        break;
      }
      cum += c;
    }
  }
  if (ccnt[hh] > CAPC) ok = 0;
  flag[hh] = ok;
  if (ok) {
    state[hh*4+0] = binA; state[hh*4+1] = residA;
    state[hh*4+2] = binB; state[hh*4+3] = residB;
  } else {
    ccnt[hh] = 0;   // fallback recollects cleanly
  }
}

// ---------------- fallback chain (early-exit when prediction held) ----------------
__global__ __launch_bounds__(512) void fb_scores_hist(const _Float16* __restrict__ Qh,
                                                      const _Float16* __restrict__ Ql,
                                                      const _Float16* __restrict__ Kh,
                                                      const _Float16* __restrict__ Kl,
                                                      const unsigned* __restrict__ flagArr,
                                                      unsigned* __restrict__ ghist)
{
  const int bn = blockIdx.x, bm = blockIdx.y, h = blockIdx.z;
  if (flagArr[h] != 0) return;
  const int wave = threadIdx.x >> 6, lane = threadIdx.x & 63;
  const int wr = wave >> 1, wc = wave & 1;
  const int m0 = bm * 256 + wr * 64;
  const int n0 = bn * 128 + wc * 64;
  const int lr = lane & 15;
  const int ko = lane >> 4;

  __shared__ unsigned lh[16384];   // 64 KB
  for (int i = threadIdx.x; i < 16384; i += 512) lh[i] = 0;
  __syncthreads();

  f32x4 acc[4][4];
#pragma unroll
  for (int i = 0; i < 4; ++i)
#pragma unroll
    for (int j = 0; j < 4; ++j) acc[i][j] = (f32x4){0.f, 0.f, 0.f, 0.f};

#pragma unroll
  for (int kk = 0; kk < 2; ++kk) {
    f16x8 aH[4], aL[4], bH[4], bL[4];
#pragma unroll
    for (int i = 0; i < 4; ++i) {
      const size_t aoff = (size_t)(m0 + i*16 + lr) * 1024 + h*64 + kk*32 + ko*8;
      aH[i] = *(const f16x8*)(Qh + aoff);
      aL[i] = *(const f16x8*)(Ql + aoff);
      const size_t boff = (size_t)(n0 + i*16 + lr) * 1024 + h*64 + kk*32 + ko*8;
      bH[i] = *(const f16x8*)(Kh + boff);
      bL[i] = *(const f16x8*)(Kl + boff);
    }
#pragma unroll
    for (int i = 0; i < 4; ++i)
#pragma unroll
      for (int j = 0; j < 4; ++j) {
        acc[i][j] = __builtin_amdgcn_mfma_f32_16x16x32_f16(aL[i], bL[j], acc[i][j], 0, 0, 0);
        acc[i][j] = __builtin_amdgcn_mfma_f32_16x16x32_f16(aH[i], bL[j], acc[i][j], 0, 0, 0);
        acc[i][j] = __builtin_amdgcn_mfma_f32_16x16x32_f16(aL[i], bH[j], acc[i][j], 0, 0, 0);
        acc[i][j] = __builtin_amdgcn_mfma_f32_16x16x32_f16(aH[i], bH[j], acc[i][j], 0, 0, 0);
      }
  }

#pragma unroll
  for (int i = 0; i < 4; ++i)
#pragma unroll
    for (int j = 0; j < 4; ++j)
#pragma unroll
      for (int r = 0; r < 4; ++r) {
        const float val = acc[i][j][r] * 0.125f;
        atomicAdd(&lh[sortkey(val) >> 18], 1u);
      }
  __syncthreads();
  unsigned* __restrict__ gh = ghist + (size_t)h * 16384;
  for (int i = threadIdx.x; i < 16384; i += 512) {
    const unsigned c = lh[i];
    if (c) atomicAdd(&gh[i], c);
  }
}

__global__ __launch_bounds__(256) void fb_scan14(const unsigned* __restrict__ ghist,
                                                 const unsigned* __restrict__ flagArr,
                                                 unsigned* __restrict__ state)
{
  const int hh = blockIdx.x;
  if (flagArr[hh] != 0) return;
  const int t = threadIdx.x;
  __shared__ unsigned part[256];
  __shared__ unsigned out[4];
  const unsigned* __restrict__ hb = ghist + (size_t)hh * 16384;
  unsigned s = 0;
  for (int j = 0; j < 64; ++j) s += hb[t*64 + j];
  part[t] = s;
  __syncthreads();
  if (t == 0) {
    unsigned run = 0;
    for (int i = 0; i < 256; ++i) { unsigned tmp = part[i]; part[i] = run; run += tmp; }
  }
  __syncthreads();
  const unsigned cum0 = part[t];
  if (K_A >= cum0 && K_A < cum0 + s) {
    unsigned c2 = cum0;
    for (int j = 0; j < 64; ++j) {
      const unsigned c = hb[t*64 + j];
      if (K_A < c2 + c) {
        const unsigned binA = t*64 + j;
        const unsigned residA = K_A - c2;
        unsigned binB, residB;
        if (residA + 1 < c) { binB = binA; residB = residA + 1; }
        else {
          unsigned bb = binA + 1;
          while (bb < 16384 && hb[bb] == 0) ++bb;
          if (bb >= 16384) bb = 16383;  // defensive
          binB = bb; residB = 0;
        }
        out[0] = binA; out[1] = residA; out[2] = binB; out[3] = residB;
        break;
      }
      c2 += c;
    }
  }
  __syncthreads();
  if (t < 4) state[hh*4 + t] = out[t];
}

__global__ __launch_bounds__(512) void fallback_compact(const _Float16* __restrict__ Qh,
                                                        const _Float16* __restrict__ Ql,
                                                        const _Float16* __restrict__ Kh,
                                                        const _Float16* __restrict__ Kl,
                                                        const unsigned* __restrict__ state,
                                                        const unsigned* __restrict__ flagArr,
                                                        unsigned* __restrict__ cand,
                                                        unsigned* __restrict__ ccnt)
{
  const int bn = blockIdx.x, bm = blockIdx.y, h = blockIdx.z;
  if (flagArr[h] != 0) return;
  const int wave = threadIdx.x >> 6, lane = threadIdx.x & 63;
  const int wr = wave >> 1, wc = wave & 1;
  const int m0 = bm * 256 + wr * 64;
  const int n0 = bn * 128 + wc * 64;
  const int lr = lane & 15;
  const int ko = lane >> 4;

  __shared__ unsigned lbuf[LCAP];
  __shared__ unsigned lcnt, gbase;
  if (threadIdx.x == 0) lcnt = 0;
  __syncthreads();
  const unsigned binA = state[h*4+0];
  const unsigned binB = state[h*4+2];
  unsigned* __restrict__ mycand = cand + (size_t)h * CAPC;

  f32x4 acc[4][4];
#pragma unroll
  for (int i = 0; i < 4; ++i)
#pragma unroll
    for (int j = 0; j < 4; ++j) acc[i][j] = (f32x4){0.f, 0.f, 0.f, 0.f};

#pragma unroll
  for (int kk = 0; kk < 2; ++kk) {
    f16x8 aH[4], aL[4], bH[4], bL[4];
#pragma unroll
    for (int i = 0; i < 4; ++i) {
      const size_t aoff = (size_t)(m0 + i*16 + lr) * 1024 + h*64 + kk*32 + ko*8;
      aH[i] = *(const f16x8*)(Qh + aoff);
      aL[i] = *(const f16x8*)(Ql + aoff);
      const size_t boff = (size_t)(n0 + i*16 + lr) * 1024 + h*64 + kk*32 + ko*8;
      bH[i] = *(const f16x8*)(Kh + boff);
      bL[i] = *(const f16x8*)(Kl + boff);
    }
#pragma unroll
    for (int i = 0; i < 4; ++i)
#pragma unroll
      for (int j = 0; j < 4; ++j) {
        acc[i][j] = __builtin_amdgcn_mfma_f32_16x16x32_f16(aL[i], bL[j], acc[i][j], 0, 0, 0);
        acc[i][j] = __builtin_amdgcn_mfma_f32_16x16x32_f16(aH[i], bL[j], acc[i][j], 0, 0, 0);
        acc[i][j] = __builtin_amdgcn_mfma_f32_16x16x32_f16(aL[i], bH[j], acc[i][j], 0, 0, 0);
        acc[i][j] = __builtin_amdgcn_mfma_f32_16x16x32_f16(aH[i], bH[j], acc[i][j], 0, 0, 0);
      }
  }

#pragma unroll
  for (int i = 0; i < 4; ++i)
#pragma unroll
    for (int j = 0; j < 4; ++j)
#pragma unroll
      for (int r = 0; r < 4; ++r) {
        const float val = acc[i][j][r] * 0.125f;
        const unsigned u = sortkey(val);
        const unsigned bin = u >> 18;
        if (bin == binA || bin == binB) {
          unsigned id = atomicAdd(&lcnt, 1u);
          if (id < LCAP) lbuf[id] = u;
          else { unsigned g = atomicAdd(&ccnt[h], 1u); if (g < CAPC) mycand[g] = u; }
        }
      }
  __syncthreads();
  const unsigned n = (lcnt < LCAP) ? lcnt : LCAP;
  if (threadIdx.x == 0) gbase = n ? atomicAdd(&ccnt[h], n) : 0u;
  __syncthreads();
  const unsigned gb = gbase;
  for (unsigned i = threadIdx.x; i < n; i += 512)
    if (gb + i < CAPC) mycand[gb + i] = lbuf[i];
}

// seed the parallel-final-select state after scan9/fallback resolved binA/binB
__global__ __launch_bounds__(64) void seed_fs(const unsigned* __restrict__ state,
                                              unsigned* __restrict__ sstate)
{
  const int t = threadIdx.x;
  if (t < HH * 4) sstate[t] = state[t];
}

// ---------------- parallel final select: 3 rounds of (hist over 32 blocks, scan) ----------------
__global__ __launch_bounds__(256) void fs_hist(const unsigned* __restrict__ cand,
                                               const unsigned* __restrict__ ccnt,
                                               const unsigned* __restrict__ sstate,
                                               unsigned* __restrict__ fhist,
                                               int s, int w)
{
  const int hh = blockIdx.y;
  const int t = threadIdx.x;
  const unsigned nb = 1u << w;
  __shared__ unsigned lh0[256], lh1[256];
  lh0[t] = 0; lh1[t] = 0;
  __syncthreads();
  const unsigned pfxA = sstate[hh*4+0];
  const unsigned pfxB = sstate[hh*4+2];
  unsigned n = ccnt[hh]; if (n > CAPC) n = CAPC;
  const unsigned* __restrict__ list = cand + (size_t)hh * CAPC;
  for (unsigned i = blockIdx.x * 256 + t; i < n; i += 32 * 256) {
    const unsigned u = list[i];
    if ((u >> (s + w)) == pfxA) atomicAdd(&lh0[(u >> s) & (nb - 1)], 1u);
    if ((u >> (s + w)) == pfxB) atomicAdd(&lh1[(u >> s) & (nb - 1)], 1u);
  }
  __syncthreads();
  if (t < (int)nb) {
    if (lh0[t]) atomicAdd(&fhist[hh*512 + t], lh0[t]);
    if (lh1[t]) atomicAdd(&fhist[hh*512 + 256 + t], lh1[t]);
  }
}

__global__ __launch_bounds__(256) void fs_scan(unsigned* __restrict__ fhist,
                                               unsigned* __restrict__ sstate,
                                               float* __restrict__ thr,
                                               int s, int w)
{
  const int hh = blockIdx.x;
  const int t = threadIdx.x;
  const unsigned nb = 1u << w;
  if (t == 0) {
    float vals[2];
    for (int tgt = 0; tgt < 2; ++tgt) {
      unsigned pfx = sstate[hh*4 + tgt*2];
      unsigned k   = sstate[hh*4 + tgt*2 + 1];
      const unsigned* hb = &fhist[hh*512 + tgt*256];
      unsigned cum = 0, b = 0;
      for (; b < nb; ++b) { const unsigned c = hb[b]; if (cum + c > k) break; cum += c; }
      if (b == nb) b = nb - 1;
      pfx = (pfx << w) | b;
      k -= cum;
      sstate[hh*4 + tgt*2]     = pfx;
      sstate[hh*4 + tgt*2 + 1] = k;
      if (s == 0) vals[tgt] = inv_sortkey(pfx);
    }
    if (s == 0) thr[hh] = vals[0] + QFRAC * (vals[1] - vals[0]);
  }
  __syncthreads();
  fhist[hh*512 + t] = 0;           // zero for next round
  fhist[hh*512 + 256 + t] = 0;
}

// ---------------- pass 3: flash softmax+PV, key-split over 2 halves ----------------
__global__ __launch_bounds__(256) void flash_pv_sk(const _Float16* __restrict__ Qh,
                                                   const _Float16* __restrict__ Ql,
                                                   const _Float16* __restrict__ Kh,
                                                   const _Float16* __restrict__ Kl,
                                                   const _Float16* __restrict__ VtH,
                                                   const _Float16* __restrict__ VtL,
                                                   const float* __restrict__ thrArr,
                                                   float* __restrict__ pctx,
                                                   float* __restrict__ prs)
{
  const int bm = blockIdx.x;          // 0..31 -> rows bm*64
  const int h  = blockIdx.y;
  const int half = blockIdx.z;        // 0..1
  const int wave = threadIdx.x >> 6, lane = threadIdx.x & 63;
  const int lr = lane & 15;
  const int ko = lane >> 4;
  const int m0 = bm * 64;
  const float thr = thrArr[h];

  __shared__ _Float16 Plds[64][136];  // pad 128->136
  __shared__ float rsLDS[64][4];

  // Q fragments are kt-invariant: hoist
  f16x8 qH[4][2], qL[4][2];
#pragma unroll
  for (int i = 0; i < 4; ++i)
#pragma unroll
    for (int kk = 0; kk < 2; ++kk) {
      const size_t aoff = (size_t)(m0 + i*16 + lr) * 1024 + h*64 + kk*32 + ko*8;
      qH[i][kk] = *(const f16x8*)(Qh + aoff);
      qL[i][kk] = *(const f16x8*)(Ql + aoff);
    }

  f32x4 oacc[4];
#pragma unroll
  for (int i = 0; i < 4; ++i) oacc[i] = (f32x4){0.f, 0.f, 0.f, 0.f};
  float rs[4][4];
#pragma unroll
  for (int i = 0; i < 4; ++i)
#pragma unroll
    for (int r = 0; r < 4; ++r) rs[i][r] = 0.f;

  const int d0 = wave * 16;   // PV: wave owns dims d0..d0+15

  for (int kt = half*8; kt < half*8 + 8; ++kt) {
    const int n0 = kt*128 + wave*32;   // S: wave owns keys n0..n0+31
    f32x4 sacc[4][2];
#pragma unroll
    for (int i = 0; i < 4; ++i)
#pragma unroll
      for (int j = 0; j < 2; ++j) sacc[i][j] = (f32x4){0.f, 0.f, 0.f, 0.f};

#pragma unroll
    for (int kk = 0; kk < 2; ++kk) {
      f16x8 bH[2], bL[2];
#pragma unroll
      for (int j = 0; j < 2; ++j) {
        const size_t boff = (size_t)(n0 + j*16 + lr) * 1024 + h*64 + kk*32 + ko*8;
        bH[j] = *(const f16x8*)(Kh + boff);
        bL[j] = *(const f16x8*)(Kl + boff);
      }
#pragma unroll
      for (int i = 0; i < 4; ++i)
#pragma unroll
        for (int j = 0; j < 2; ++j) {
          sacc[i][j] = __builtin_amdgcn_mfma_f32_16x16x32_f16(qL[i][kk], bL[j], sacc[i][j], 0, 0, 0);
          sacc[i][j] = __builtin_amdgcn_mfma_f32_16x16x32_f16(qH[i][kk], bL[j], sacc[i][j], 0, 0, 0);
          sacc[i][j] = __builtin_amdgcn_mfma_f32_16x16x32_f16(qL[i][kk], bH[j], sacc[i][j], 0, 0, 0);
          sacc[i][j] = __builtin_amdgcn_mfma_f32_16x16x32_f16(qH[i][kk], bH[j], sacc[i][j], 0, 0, 0);
        }
    }

    // mask + exp + P->LDS + rowsum partials
#pragma unroll
    for (int i = 0; i < 4; ++i)
#pragma unroll
      for (int j = 0; j < 2; ++j)
#pragma unroll
        for (int r = 0; r < 4; ++r) {
          const float val = sacc[i][j][r] * 0.125f;
          const float p = (val >= thr) ? __expf(val - thr - ESHIFT) : 0.f;
          rs[i][r] += p;
          Plds[i*16 + ko*4 + r][wave*32 + j*16 + lr] = (_Float16)p;
        }
    __syncthreads();

    // PV: oacc[i] over dims d0+lr, keys kt*128..+127
#pragma unroll
    for (int kk2 = 0; kk2 < 4; ++kk2) {
      f16x8 pa[4];
#pragma unroll
      for (int i = 0; i < 4; ++i)
        pa[i] = *(const f16x8*)&Plds[i*16 + lr][kk2*32 + ko*8];
      const size_t vo = (size_t)(h*64 + d0 + lr) * 2048 + kt*128 + kk2*32 + ko*8;
      const f16x8 vH = *(const f16x8*)(VtH + vo);
      const f16x8 vL = *(const f16x8*)(VtL + vo);
#pragma unroll
      for (int i = 0; i < 4; ++i) {
        oacc[i] = __builtin_amdgcn_mfma_f32_16x16x32_f16(pa[i], vL, oacc[i], 0, 0, 0);
        oacc[i] = __builtin_amdgcn_mfma_f32_16x16x32_f16(pa[i], vH, oacc[i], 0, 0, 0);
      }
    }
    __syncthreads();   // before next kt overwrites Plds
  }

  // rowsum: reduce across the 16 lanes of each ko-group, then across waves
#pragma unroll
  for (int i = 0; i < 4; ++i)
#pragma unroll
    for (int r = 0; r < 4; ++r) {
      float v = rs[i][r];
      v += __shfl_xor(v, 1); v += __shfl_xor(v, 2);
      v += __shfl_xor(v, 4); v += __shfl_xor(v, 8);
      rs[i][r] = v;
    }
  if (lr == 0) {
#pragma unroll
    for (int i = 0; i < 4; ++i)
#pragma unroll
      for (int r = 0; r < 4; ++r)
        rsLDS[i*16 + ko*4 + r][wave] = rs[i][r];
  }
  __syncthreads();

  // write partial rowsums
  if (wave == 0 && lr == 0) {
#pragma unroll
    for (int i = 0; i < 4; ++i)
#pragma unroll
      for (int r = 0; r < 4; ++r) {
        const int lrow = i*16 + ko*4 + r;
        prs[half*32768 + h*2048 + m0 + lrow] =
            rsLDS[lrow][0] + rsLDS[lrow][1] + rsLDS[lrow][2] + rsLDS[lrow][3];
      }
  }

  // store raw partial O
  float* __restrict__ pc = pctx + (size_t)half * PLANE;
#pragma unroll
  for (int i = 0; i < 4; ++i)
#pragma unroll
    for (int r = 0; r < 4; ++r) {
      const int lrow = i*16 + ko*4 + r;
      pc[(size_t)(m0 + lrow) * 1024 + h*64 + d0 + lr] = oacc[i][r];
    }
}

// ---------------- host ----------------
extern "C" void kernel_launch(void* const* d_in, const int* in_sizes, int n_in,
                              void* d_out, int out_size, void* d_ws, size_t ws_size,
                              hipStream_t stream)
{
  const float* x  = (const float*)d_in[0];
  const float* Wq = (const float*)d_in[1];
  const float* bq = (const float*)d_in[2];
  const float* Wk = (const float*)d_in[3];
  const float* bk = (const float*)d_in[4];
  const float* Wv = (const float*)d_in[5];
  const float* bv = (const float*)d_in[6];
  const float* Wo = (const float*)d_in[7];
  const float* bo = (const float*)d_in[8];
  float* out = (float*)d_out;
  char*  ws  = (char*)d_ws;

  const size_t MB = 1u << 20;
  _Float16* xh      = (_Float16*)(ws + 0*MB);
  _Float16* xl      = (_Float16*)(ws + 4*MB);
  _Float16* wplanes = (_Float16*)(ws + 8*MB);    // 8 x 2 MiB transposed W planes
  _Float16* Qh      = (_Float16*)(ws + 24*MB);
  _Float16* Ql      = (_Float16*)(ws + 28*MB);
  _Float16* Kh      = (_Float16*)(ws + 32*MB);
  _Float16* Kl      = (_Float16*)(ws + 36*MB);
  _Float16* VtH     = (_Float16*)(ws + 40*MB);   // [1024 dims][2048 rows]
  _Float16* VtL     = (_Float16*)(ws + 44*MB);
  _Float16* ctxh    = (_Float16*)(ws + 48*MB);
  _Float16* ctxl    = (_Float16*)(ws + 52*MB);
  const size_t base = 56*MB;
  unsigned* state    = (unsigned*)(ws + base);
  float*    thr      = (float*)(ws + base + 4096);
  unsigned* ccnt     = (unsigned*)(ws + base + 8192);
  unsigned* flag     = (unsigned*)(ws + base + 12288);
  unsigned* rangeLo  = (unsigned*)(ws + base + 16384);
  unsigned* rangeHi  = (unsigned*)(ws + base + 20480);
  unsigned* sstate   = (unsigned*)(ws + base + 24576);
  unsigned* fhist    = (unsigned*)(ws + base + 28672);  // HH*512*4 = 32 KiB
  unsigned* cntBelow = (unsigned*)(ws + base + 65536);
  unsigned* ghist9   = (unsigned*)(ws + base + 69632);  // HH*16 u32
  unsigned* ghist    = (unsigned*)(ws + 57*MB);   // 1 MiB (fallback only)
  unsigned* shist    = (unsigned*)(ws + 58*MB);   // 1 MiB
  unsigned* cand     = (unsigned*)(ws + 59*MB);   // HH * CAPC * 4 = 20 MiB
  float*    prs      = (float*)(ws + 80*MB);      // 2 x 16 x 2048 f32
  float*    pbuf     = (float*)(ws + 81*MB);      // 6 x 8 MiB partials
  float*    pctx     = pbuf;                      // planes 0,1 (post combine_qk)
  float*    pO       = pbuf + (size_t)2 * PLANE;  // planes 2,3

  split_x<<<2048, 256, 0, stream>>>(x, xh, xl);
  split_wT<<<dim3(16, 16, 4), 256, 0, stream>>>(Wq, Wk, Wv, Wo, wplanes);
  gemm_qkv_part<<<dim3(8, 16, 6), 256, 0, stream>>>(xh, xl, wplanes, pbuf);
  combine_qk<<<dim3(2048, 2), 256, 0, stream>>>(pbuf, bq, bk, Qh, Ql, Kh, Kl);
  combine_vT<<<dim3(16, 32), 256, 0, stream>>>(pbuf, bv, VtH, VtL);

  init_sel<<<256, 256, 0, stream>>>(ghist, shist, ccnt, flag, fhist, cntBelow, ghist9);
  sample_hist<<<dim3(16, HH), 256, 0, stream>>>(Qh, Ql, Kh, Kl, shist);
  sample_scan<<<HH, 256, 0, stream>>>(shist, rangeLo, rangeHi);
  range_count<<<dim3(16, 8, HH), 512, 0, stream>>>(Qh, Ql, Kh, Kl, rangeLo, rangeHi,
                                                   cand, ccnt, cntBelow, ghist9);
  scan9<<<1, 64, 0, stream>>>(ghist9, cntBelow, rangeLo, rangeHi, ccnt, state, flag);
  // fallback chain (early-exit per head when prediction held)
  fb_scores_hist<<<dim3(16, 8, HH), 512, 0, stream>>>(Qh, Ql, Kh, Kl, flag, ghist);
  fb_scan14<<<HH, 256, 0, stream>>>(ghist, flag, state);
  fallback_compact<<<dim3(16, 8, HH), 512, 0, stream>>>(Qh, Ql, Kh, Kl, state, flag, cand, ccnt);
  seed_fs<<<1, 64, 0, stream>>>(state, sstate);
  // parallel final select: rounds (s,w) = (10,8), (2,8), (0,2)
  fs_hist<<<dim3(32, HH), 256, 0, stream>>>(cand, ccnt, sstate, fhist, 10, 8);
  fs_scan<<<HH, 256, 0, stream>>>(fhist, sstate, thr, 10, 8);
  fs_hist<<<dim3(32, HH), 256, 0, stream>>>(cand, ccnt, sstate, fhist, 2, 8);
  fs_scan<<<HH, 256, 0, stream>>>(fhist, sstate, thr, 2, 8);
  fs_hist<<<dim3(32, HH), 256, 0, stream>>>(cand, ccnt, sstate, fhist, 0, 2);
  fs_scan<<<HH, 256, 0, stream>>>(fhist, sstate, thr, 0, 2);

  flash_pv_sk<<<dim3(32, HH, 2), 256, 0, stream>>>(Qh, Ql, Kh, Kl, VtH, VtL, thr, pctx, prs);
  combine_ctx<<<2048, 256, 0, stream>>>(pctx, prs, ctxh, ctxl);

  gemm_o_part<<<dim3(8, 16, 2), 256, 0, stream>>>(ctxh, ctxl, wplanes, pO);
  combine_o<<<2048, 256, 0, stream>>>(pO, bo, out);
}

// Round 24
// 523.289 us; speedup vs baseline: 1.1275x; 1.0050x over previous
//
#include <hip/hip_runtime.h>
#include <math.h>

#define SS 2048
#define DD 1024
#define HH 16
#define CAPC 327680u  // candidate slots per head (range ~5 bins x ~16K/bin ~ 83K expected)
#define LCAP 2048     // per-block LDS candidate buffer (expected ~670/block)
#define RBIN 2        // predicted-bin safety margin (r22-validated; RBIN=1 failed post-timing r23)

// quantile index: floor(0.95*(S*S-1)) = floor(3984587.85)
#define K_A 3984587u
#define K_B 3984588u
#define QFRAC 0.85f
#define WSCALE 2048.0f      // W planes pre-scaled so lo-residuals stay normal fp16
#define WSCALE_INV (1.0f/2048.0f)
#define ESHIFT 4.0f         // exp(s - thr - ESHIFT): kept P in [e^-4, ~e^6] — fp16-safe
#define PLANE 2097152       // floats per 2048x1024 fp32 partial plane (8 MiB)
#define NSAMP_RANK 124518u  // floor(0.95 * 131072) — sample quantile rank

typedef _Float16 f16x8 __attribute__((ext_vector_type(8)));
typedef _Float16 f16x4 __attribute__((ext_vector_type(4)));
typedef float    f32x4 __attribute__((ext_vector_type(4)));

__device__ __forceinline__ unsigned sortkey(float f) {
  unsigned b = __float_as_uint(f);
  return (b & 0x80000000u) ? ~b : (b | 0x80000000u);
}
__device__ __forceinline__ float inv_sortkey(unsigned u) {
  unsigned b = (u & 0x80000000u) ? (u ^ 0x80000000u) : ~u;
  return __uint_as_float(b);
}

// ---------------- input splitting ----------------
__global__ __launch_bounds__(256) void split_x(const float* __restrict__ x,
                                               _Float16* __restrict__ xh,
                                               _Float16* __restrict__ xl)
{
  const int i = blockIdx.x * 256 + threadIdx.x;   // float4 index, 524288 total
  float4 v = ((const float4*)x)[i];
  float vv[4] = {v.x, v.y, v.z, v.w};
  f16x4 h, l;
#pragma unroll
  for (int j = 0; j < 4; ++j) {
    _Float16 hh = (_Float16)vv[j];
    h[j] = hh;
    l[j] = (_Float16)(vv[j] - (float)hh);
  }
  ((f16x4*)xh)[i] = h;
  ((f16x4*)xl)[i] = l;
}

// W -> transposed hi/lo fp16 planes WT[n][k], scaled by 2048 (keeps lo normal).
__global__ __launch_bounds__(256) void split_wT(const float* __restrict__ Wq,
                                                const float* __restrict__ Wk,
                                                const float* __restrict__ Wv,
                                                const float* __restrict__ Wo,
                                                _Float16* __restrict__ wplanes)
{
  const int z = blockIdx.z;
  const float* W = (z == 0) ? Wq : (z == 1) ? Wk : (z == 2) ? Wv : Wo;
  _Float16* WhT = wplanes + (size_t)(2*z)     * (1024*1024);
  _Float16* WlT = wplanes + (size_t)(2*z + 1) * (1024*1024);
  __shared__ float tile[64][65];
  const int t  = threadIdx.x;
  const int r  = t >> 2;         // 0..63
  const int c0 = (t & 3) * 16;   // 0/16/32/48
  const int k0 = blockIdx.y * 64;
  const int n0 = blockIdx.x * 64;
#pragma unroll
  for (int j = 0; j < 4; ++j) {
    float4 v = *(const float4*)&W[(size_t)(k0 + r) * 1024 + n0 + c0 + j*4];
    tile[r][c0+j*4+0] = v.x; tile[r][c0+j*4+1] = v.y;
    tile[r][c0+j*4+2] = v.z; tile[r][c0+j*4+3] = v.w;
  }
  __syncthreads();
  f16x8 h0, h1, l0, l1;
#pragma unroll
  for (int j = 0; j < 8; ++j) {
    float v = tile[c0 + j][r] * WSCALE;
    _Float16 h = (_Float16)v;
    h0[j] = h; l0[j] = (_Float16)(v - (float)h);
  }
#pragma unroll
  for (int j = 0; j < 8; ++j) {
    float v = tile[c0 + 8 + j][r] * WSCALE;
    _Float16 h = (_Float16)v;
    h1[j] = h; l1[j] = (_Float16)(v - (float)h);
  }
  const size_t o = (size_t)(n0 + r) * 1024 + k0 + c0;
  *(f16x8*)&WhT[o]     = h0;
  *(f16x8*)&WhT[o + 8] = h1;
  *(f16x8*)&WlT[o]     = l0;
  *(f16x8*)&WlT[o + 8] = l1;
}

// ---------------- split-K MFMA GEMM partial ----------------
__device__ __forceinline__ void gemm_mfma_part(const _Float16* __restrict__ Ah,
                                               const _Float16* __restrict__ Al,
                                               const _Float16* __restrict__ BhT,
                                               const _Float16* __restrict__ BlT,
                                               float* __restrict__ pout,
                                               int bm, int bn, int kh)
{
  const int wave = threadIdx.x >> 6, lane = threadIdx.x & 63;
  const int wr = wave >> 1, wc = wave & 1;
  const int m0 = bm * 128 + wr * 64;
  const int n0 = bn * 128 + wc * 64;
  const int lr = lane & 15;
  const int ko = lane >> 4;

  f32x4 acc[4][4];
#pragma unroll
  for (int i = 0; i < 4; ++i)
#pragma unroll
    for (int j = 0; j < 4; ++j) acc[i][j] = (f32x4){0.f, 0.f, 0.f, 0.f};

  for (int kk = kh*16; kk < kh*16 + 16; ++kk) {
    const int kof = kk*32 + ko*8;
    f16x8 aH[4], aL[4], bH[4], bL[4];
#pragma unroll
    for (int i = 0; i < 4; ++i) {
      const size_t aoff = (size_t)(m0 + i*16 + lr) * 1024 + kof;
      aH[i] = *(const f16x8*)(Ah + aoff);
      aL[i] = *(const f16x8*)(Al + aoff);
      const size_t boff = (size_t)(n0 + i*16 + lr) * 1024 + kof;
      bH[i] = *(const f16x8*)(BhT + boff);
      bL[i] = *(const f16x8*)(BlT + boff);
    }
#pragma unroll
    for (int i = 0; i < 4; ++i)
#pragma unroll
      for (int j = 0; j < 4; ++j) {
        acc[i][j] = __builtin_amdgcn_mfma_f32_16x16x32_f16(aL[i], bL[j], acc[i][j], 0, 0, 0);
        acc[i][j] = __builtin_amdgcn_mfma_f32_16x16x32_f16(aH[i], bL[j], acc[i][j], 0, 0, 0);
        acc[i][j] = __builtin_amdgcn_mfma_f32_16x16x32_f16(aL[i], bH[j], acc[i][j], 0, 0, 0);
        acc[i][j] = __builtin_amdgcn_mfma_f32_16x16x32_f16(aH[i], bH[j], acc[i][j], 0, 0, 0);
      }
  }

#pragma unroll
  for (int i = 0; i < 4; ++i)
#pragma unroll
    for (int j = 0; j < 4; ++j)
#pragma unroll
      for (int r = 0; r < 4; ++r) {
        const int row = m0 + i*16 + ko*4 + r;
        const int col = n0 + j*16 + lr;
        pout[(size_t)row * 1024 + col] = acc[i][j][r];
      }
}

__global__ __launch_bounds__(256) void gemm_qkv_part(const _Float16* __restrict__ xh,
                                                     const _Float16* __restrict__ xl,
                                                     const _Float16* __restrict__ wplanes,
                                                     float* __restrict__ pbuf)
{
  const int z = blockIdx.z;           // 0..5: gemm_id*2 + khalf
  const int g = z >> 1, kh = z & 1;
  const _Float16* BhT = wplanes + (size_t)(2*g)     * (1024*1024);
  const _Float16* BlT = wplanes + (size_t)(2*g + 1) * (1024*1024);
  gemm_mfma_part(xh, xl, BhT, BlT, pbuf + (size_t)z * PLANE,
                 blockIdx.y, blockIdx.x, kh);
}

__global__ __launch_bounds__(256) void gemm_o_part(const _Float16* __restrict__ ctxh,
                                                   const _Float16* __restrict__ ctxl,
                                                   const _Float16* __restrict__ wplanes,
                                                   float* __restrict__ pO)
{
  const int kh = blockIdx.z;          // 0..1
  gemm_mfma_part(ctxh, ctxl,
                 wplanes + (size_t)6 * (1024*1024),
                 wplanes + (size_t)7 * (1024*1024),
                 pO + (size_t)kh * PLANE, blockIdx.y, blockIdx.x, kh);
}

// ---------------- combine kernels ----------------
__global__ __launch_bounds__(256) void combine_qk(const float* __restrict__ pbuf,
                                                  const float* __restrict__ bq,
                                                  const float* __restrict__ bk,
                                                  _Float16* __restrict__ Qh,
                                                  _Float16* __restrict__ Ql,
                                                  _Float16* __restrict__ Kh,
                                                  _Float16* __restrict__ Kl)
{
  const int which = blockIdx.y;       // 0=Q, 1=K
  const float* p0 = pbuf + (size_t)(which*2)     * PLANE;
  const float* p1 = pbuf + (size_t)(which*2 + 1) * PLANE;
  const float* bias = which ? bk : bq;
  _Float16* Oh = which ? Kh : Qh;
  _Float16* Ol = which ? Kl : Ql;
  const int i = blockIdx.x * 256 + threadIdx.x;   // f4 index, 524288
  const int coloff = (i & 255) * 4;
  float4 a = ((const float4*)p0)[i];
  float4 b = ((const float4*)p1)[i];
  float av[4] = {a.x, a.y, a.z, a.w};
  float bv[4] = {b.x, b.y, b.z, b.w};
  f16x4 h, l;
#pragma unroll
  for (int j = 0; j < 4; ++j) {
    const float val = (av[j] + bv[j]) * WSCALE_INV + bias[coloff + j];
    _Float16 hh = (_Float16)val;
    h[j] = hh;
    l[j] = (_Float16)(val - (float)hh);
  }
  ((f16x4*)Oh)[i] = h;
  ((f16x4*)Ol)[i] = l;
}

// V: combine + transpose to Vt[dim][row] hi/lo planes (LDS 64x64 tile).
__global__ __launch_bounds__(256) void combine_vT(const float* __restrict__ pbuf,
                                                  const float* __restrict__ bv,
                                                  _Float16* __restrict__ VtH,
                                                  _Float16* __restrict__ VtL)
{
  const float* p0 = pbuf + (size_t)4 * PLANE;
  const float* p1 = pbuf + (size_t)5 * PLANE;
  __shared__ float tile[64][65];
  const int t  = threadIdx.x;
  const int d0 = blockIdx.x * 64;     // dim tile
  const int m0 = blockIdx.y * 64;     // row tile
  {
    const int r  = t >> 2;            // row 0..63
    const int c0 = (t & 3) * 16;
#pragma unroll
    for (int j = 0; j < 4; ++j) {
      const size_t o = (size_t)(m0 + r) * 1024 + d0 + c0 + j*4;
      float4 a = *(const float4*)(p0 + o);
      float4 b = *(const float4*)(p1 + o);
      tile[r][c0+j*4+0] = (a.x + b.x) * WSCALE_INV + bv[d0 + c0 + j*4 + 0];
      tile[r][c0+j*4+1] = (a.y + b.y) * WSCALE_INV + bv[d0 + c0 + j*4 + 1];
      tile[r][c0+j*4+2] = (a.z + b.z) * WSCALE_INV + bv[d0 + c0 + j*4 + 2];
      tile[r][c0+j*4+3] = (a.w + b.w) * WSCALE_INV + bv[d0 + c0 + j*4 + 3];
    }
  }
  __syncthreads();
  {
    const int d  = t >> 2;            // dim 0..63
    const int rg = (t & 3) * 16;      // row group
#pragma unroll
    for (int j = 0; j < 4; ++j) {
      f16x4 hv, lv;
#pragma unroll
      for (int r = 0; r < 4; ++r) {
        const float val = tile[rg + j*4 + r][d];
        _Float16 h = (_Float16)val;
        hv[r] = h; lv[r] = (_Float16)(val - (float)h);
      }
      const size_t o = (size_t)(d0 + d) * 2048 + m0 + rg + j*4;
      *(f16x4*)&VtH[o] = hv;
      *(f16x4*)&VtL[o] = lv;
    }
  }
}

__global__ __launch_bounds__(256) void combine_o(const float* __restrict__ pO,
                                                 const float* __restrict__ bo,
                                                 float* __restrict__ out)
{
  const float* p0 = pO;
  const float* p1 = pO + (size_t)1 * PLANE;
  const int i = blockIdx.x * 256 + threadIdx.x;
  const int coloff = (i & 255) * 4;
  float4 a = ((const float4*)p0)[i];
  float4 b = ((const float4*)p1)[i];
  float4 o;
  o.x = (a.x + b.x) * WSCALE_INV + bo[coloff + 0];
  o.y = (a.y + b.y) * WSCALE_INV + bo[coloff + 1];
  o.z = (a.z + b.z) * WSCALE_INV + bo[coloff + 2];
  o.w = (a.w + b.w) * WSCALE_INV + bo[coloff + 3];
  ((float4*)out)[i] = o;
}

// ctx: (p0+p1) / (rs0+rs1), then fp16 hi/lo split.
__global__ __launch_bounds__(256) void combine_ctx(const float* __restrict__ pctx,
                                                   const float* __restrict__ prs,
                                                   _Float16* __restrict__ ctxh,
                                                   _Float16* __restrict__ ctxl)
{
  const float* p0 = pctx;
  const float* p1 = pctx + (size_t)1 * PLANE;
  const int i = blockIdx.x * 256 + threadIdx.x;   // f4 index, 524288
  const int row = i >> 8;
  const int cd  = (i & 255) * 4;
  const int h   = cd >> 6;
  const float rs = prs[h*2048 + row] + prs[32768 + h*2048 + row];
  float4 a = ((const float4*)p0)[i];
  float4 b = ((const float4*)p1)[i];
  float av[4] = {a.x, a.y, a.z, a.w};
  float bv[4] = {b.x, b.y, b.z, b.w};
  f16x4 hh, ll;
#pragma unroll
  for (int j = 0; j < 4; ++j) {
    const float val = (av[j] + bv[j]) / rs;
    _Float16 hv = (_Float16)val;
    hh[j] = hv;
    ll[j] = (_Float16)(val - (float)hv);
  }
  ((f16x4*)ctxh)[i] = hh;
  ((f16x4*)ctxl)[i] = ll;
}

// ---------------- selection init ----------------
__global__ __launch_bounds__(256) void init_sel(unsigned* __restrict__ ghist,
                                                unsigned* __restrict__ shist,
                                                unsigned* __restrict__ ccnt,
                                                unsigned* __restrict__ flag,
                                                unsigned* __restrict__ fhist,
                                                unsigned* __restrict__ cntBelow,
                                                unsigned* __restrict__ ghist9)
{
  int i = blockIdx.x * 256 + threadIdx.x;
  for (; i < HH * 16384; i += gridDim.x * 256) { ghist[i] = 0; shist[i] = 0; }
  const int j = blockIdx.x * 256 + threadIdx.x;
  if (j < HH * 512) fhist[j] = 0;
  if (j < HH * 16) ghist9[j] = 0;
  if (blockIdx.x == 0 && threadIdx.x < HH) {
    ccnt[threadIdx.x] = 0; flag[threadIdx.x] = 0; cntBelow[threadIdx.x] = 0;
  }
}

// ---------------- sampling pass: 64 of 2048 query rows (stride 32) ----------------
__global__ __launch_bounds__(256) void sample_hist(const _Float16* __restrict__ Qh,
                                                   const _Float16* __restrict__ Ql,
                                                   const _Float16* __restrict__ Kh,
                                                   const _Float16* __restrict__ Kl,
                                                   unsigned* __restrict__ shist)
{
  const int kb = blockIdx.x, h = blockIdx.y;
  const int wave = threadIdx.x >> 6, lane = threadIdx.x & 63;
  const int lr = lane & 15, ko = lane >> 4;
  const int n0 = kb*128 + wave*32;

  __shared__ unsigned lh[16384];   // 64 KB
  for (int i = threadIdx.x; i < 16384; i += 256) lh[i] = 0;
  __syncthreads();

  f32x4 acc[4][2];
#pragma unroll
  for (int i = 0; i < 4; ++i)
#pragma unroll
    for (int j = 0; j < 2; ++j) acc[i][j] = (f32x4){0.f, 0.f, 0.f, 0.f};

#pragma unroll
  for (int kk = 0; kk < 2; ++kk) {
    f16x8 aH[4], aL[4], bH[2], bL[2];
#pragma unroll
    for (int i = 0; i < 4; ++i) {
      const size_t aoff = (size_t)((i*16 + lr) * 32) * 1024 + h*64 + kk*32 + ko*8;
      aH[i] = *(const f16x8*)(Qh + aoff);
      aL[i] = *(const f16x8*)(Ql + aoff);
    }
#pragma unroll
    for (int j = 0; j < 2; ++j) {
      const size_t boff = (size_t)(n0 + j*16 + lr) * 1024 + h*64 + kk*32 + ko*8;
      bH[j] = *(const f16x8*)(Kh + boff);
      bL[j] = *(const f16x8*)(Kl + boff);
    }
#pragma unroll
    for (int i = 0; i < 4; ++i)
#pragma unroll
      for (int j = 0; j < 2; ++j) {
        acc[i][j] = __builtin_amdgcn_mfma_f32_16x16x32_f16(aL[i], bL[j], acc[i][j], 0, 0, 0);
        acc[i][j] = __builtin_amdgcn_mfma_f32_16x16x32_f16(aH[i], bL[j], acc[i][j], 0, 0, 0);
        acc[i][j] = __builtin_amdgcn_mfma_f32_16x16x32_f16(aL[i], bH[j], acc[i][j], 0, 0, 0);
        acc[i][j] = __builtin_amdgcn_mfma_f32_16x16x32_f16(aH[i], bH[j], acc[i][j], 0, 0, 0);
      }
  }

#pragma unroll
  for (int i = 0; i < 4; ++i)
#pragma unroll
    for (int j = 0; j < 2; ++j)
#pragma unroll
      for (int r = 0; r < 4; ++r) {
        const float val = acc[i][j][r] * 0.125f;
        atomicAdd(&lh[sortkey(val) >> 18], 1u);
      }
  __syncthreads();
  unsigned* __restrict__ gh = shist + (size_t)h * 16384;
  for (int i = threadIdx.x; i < 16384; i += 256) {
    const unsigned c = lh[i];
    if (c) atomicAdd(&gh[i], c);
  }
}

// find sample-quantile bin; emit conservative range [bin-RBIN, bin+RBIN]
__global__ __launch_bounds__(256) void sample_scan(const unsigned* __restrict__ shist,
                                                   unsigned* __restrict__ rangeLo,
                                                   unsigned* __restrict__ rangeHi)
{
  const int hh = blockIdx.x;
  const int t = threadIdx.x;
  __shared__ unsigned part[256];
  __shared__ unsigned outb;
  if (t == 0) outb = 8192u;  // defensive default
  const unsigned* __restrict__ hb = shist + (size_t)hh * 16384;
  unsigned s = 0;
  for (int j = 0; j < 64; ++j) s += hb[t*64 + j];
  part[t] = s;
  __syncthreads();
  if (t == 0) {
    unsigned run = 0;
    for (int i = 0; i < 256; ++i) { unsigned tmp = part[i]; part[i] = run; run += tmp; }
  }
  __syncthreads();
  const unsigned cum0 = part[t];
  if (NSAMP_RANK >= cum0 && NSAMP_RANK < cum0 + s) {
    unsigned c2 = cum0;
    for (int j = 0; j < 64; ++j) {
      const unsigned c = hb[t*64 + j];
      if (NSAMP_RANK < c2 + c) { outb = t*64 + j; break; }
      c2 += c;
    }
  }
  __syncthreads();
  if (t == 0) {
    const int b = (int)outb;
    rangeLo[hh] = (unsigned)((b - RBIN < 0) ? 0 : b - RBIN);
    rangeHi[hh] = (unsigned)((b + RBIN > 16383) ? 16383 : b + RBIN);
  }
}

// ---------------- pass 1: count-below + 5-bin range histogram + compaction ----------------
// r17-measured-best structure with RBIN=2 (r22-validated best configuration).
__global__ __launch_bounds__(512) void range_count(const _Float16* __restrict__ Qh,
                                                   const _Float16* __restrict__ Ql,
                                                   const _Float16* __restrict__ Kh,
                                                   const _Float16* __restrict__ Kl,
                                                   const unsigned* __restrict__ rangeLo,
                                                   const unsigned* __restrict__ rangeHi,
                                                   unsigned* __restrict__ cand,
                                                   unsigned* __restrict__ ccnt,
                                                   unsigned* __restrict__ cntBelow,
                                                   unsigned* __restrict__ ghist9)
{
  const int bn = blockIdx.x, bm = blockIdx.y, h = blockIdx.z;
  const int wave = threadIdx.x >> 6, lane = threadIdx.x & 63;
  const int wr = wave >> 1, wc = wave & 1;
  const int m0 = bm * 256 + wr * 64;
  const int n0 = bn * 128 + wc * 64;
  const int lr = lane & 15;
  const int ko = lane >> 4;
  const unsigned lo = rangeLo[h], hi = rangeHi[h];
  unsigned* __restrict__ mycand = cand + (size_t)h * CAPC;

  __shared__ unsigned lh9[16];
  __shared__ unsigned lbuf[LCAP];  // 8 KB
  __shared__ unsigned lcnt, gbase, lbelow;
  if (threadIdx.x < 16) lh9[threadIdx.x] = 0;
  if (threadIdx.x == 0) { lcnt = 0; lbelow = 0; }
  __syncthreads();

  f32x4 acc[4][4];
#pragma unroll
  for (int i = 0; i < 4; ++i)
#pragma unroll
    for (int j = 0; j < 4; ++j) acc[i][j] = (f32x4){0.f, 0.f, 0.f, 0.f};

#pragma unroll
  for (int kk = 0; kk < 2; ++kk) {
    f16x8 aH[4], aL[4], bH[4], bL[4];
#pragma unroll
    for (int i = 0; i < 4; ++i) {
      const size_t aoff = (size_t)(m0 + i*16 + lr) * 1024 + h*64 + kk*32 + ko*8;
      aH[i] = *(const f16x8*)(Qh + aoff);
      aL[i] = *(const f16x8*)(Ql + aoff);
      const size_t boff = (size_t)(n0 + i*16 + lr) * 1024 + h*64 + kk*32 + ko*8;
      bH[i] = *(const f16x8*)(Kh + boff);
      bL[i] = *(const f16x8*)(Kl + boff);
    }
#pragma unroll
    for (int i = 0; i < 4; ++i)
#pragma unroll
      for (int j = 0; j < 4; ++j) {
        acc[i][j] = __builtin_amdgcn_mfma_f32_16x16x32_f16(aL[i], bL[j], acc[i][j], 0, 0, 0);
        acc[i][j] = __builtin_amdgcn_mfma_f32_16x16x32_f16(aH[i], bL[j], acc[i][j], 0, 0, 0);
        acc[i][j] = __builtin_amdgcn_mfma_f32_16x16x32_f16(aL[i], bH[j], acc[i][j], 0, 0, 0);
        acc[i][j] = __builtin_amdgcn_mfma_f32_16x16x32_f16(aH[i], bH[j], acc[i][j], 0, 0, 0);
      }
  }

  unsigned nb = 0;
#pragma unroll
  for (int i = 0; i < 4; ++i)
#pragma unroll
    for (int j = 0; j < 4; ++j)
#pragma unroll
      for (int r = 0; r < 4; ++r) {
        const float val = acc[i][j][r] * 0.125f;
        const unsigned u = sortkey(val);
        const unsigned bin = u >> 18;
        nb += (bin < lo) ? 1u : 0u;
        if (bin >= lo && bin <= hi) {
          atomicAdd(&lh9[bin - lo], 1u);
          unsigned id = atomicAdd(&lcnt, 1u);
          if (id < LCAP) lbuf[id] = u;
          else { unsigned g = atomicAdd(&ccnt[h], 1u); if (g < CAPC) mycand[g] = u; }
        }
      }
  // wave-reduce below-count, one LDS atomic per wave
  nb += __shfl_xor(nb, 1);  nb += __shfl_xor(nb, 2);
  nb += __shfl_xor(nb, 4);  nb += __shfl_xor(nb, 8);
  nb += __shfl_xor(nb, 16); nb += __shfl_xor(nb, 32);
  if (lane == 0) atomicAdd(&lbelow, nb);
  __syncthreads();
  if (threadIdx.x < 16) {
    const unsigned c = lh9[threadIdx.x];
    if (c) atomicAdd(&ghist9[h*16 + threadIdx.x], c);
  }
  if (threadIdx.x == 0 && lbelow) atomicAdd(&cntBelow[h], lbelow);
  const unsigned n = (lcnt < LCAP) ? lcnt : LCAP;
  if (threadIdx.x == 0) gbase = n ? atomicAdd(&ccnt[h], n) : 0u;
  __syncthreads();
  const unsigned gb = gbase;
  for (unsigned i = threadIdx.x; i < n; i += 512)
    if (gb + i < CAPC) mycand[gb + i] = lbuf[i];
}

// ---------------- scan over range: exact binA/residA/binB/residB ----------------
__global__ __launch_bounds__(64) void scan9(const unsigned* __restrict__ ghist9,
                                            const unsigned* __restrict__ cntBelow,
                                            const unsigned* __restrict__ rangeLo,
                                            const unsigned* __restrict__ rangeHi,
                                            unsigned* __restrict__ ccnt,
                                            unsigned* __restrict__ state,
                                            unsigned* __restrict__ flag)
{
  const int hh = threadIdx.x;
  if (hh >= HH) return;
  const unsigned lo = rangeLo[hh], hi = rangeHi[hh];
  const int nbins = (int)(hi - lo + 1);
  const unsigned base = cntBelow[hh];
  unsigned ok = 0;
  unsigned binA = 0, residA = 0, binB = 0, residB = 0;
  if (K_A >= base) {
    unsigned k = K_A - base;
    unsigned cum = 0;
    for (int b = 0; b < nbins; ++b) {
      const unsigned c = ghist9[hh*16 + b];
      if (k < cum + c) {
        binA = lo + b;
        residA = k - cum;
        if (residA + 1 < c) { binB = binA; residB = residA + 1; ok = 1; }
        else {
          for (int b2 = b + 1; b2 < nbins; ++b2) {
            if (ghist9[hh*16 + b2]) { binB = lo + b2; residB = 0; ok = 1; break; }
          }
        }
        break;
      }
      cum += c;
    }
  }
  if (ccnt[hh] > CAPC) ok = 0;
  flag[hh] = ok;
  if (ok) {
    state[hh*4+0] = binA; state[hh*4+1] = residA;
    state[hh*4+2] = binB; state[hh*4+3] = residB;
  } else {
    ccnt[hh] = 0;   // fallback recollects cleanly
  }
}

// ---------------- fallback chain (early-exit when prediction held) ----------------
__global__ __launch_bounds__(512) void fb_scores_hist(const _Float16* __restrict__ Qh,
                                                      const _Float16* __restrict__ Ql,
                                                      const _Float16* __restrict__ Kh,
                                                      const _Float16* __restrict__ Kl,
                                                      const unsigned* __restrict__ flagArr,
                                                      unsigned* __restrict__ ghist)
{
  const int bn = blockIdx.x, bm = blockIdx.y, h = blockIdx.z;
  if (flagArr[h] != 0) return;
  const int wave = threadIdx.x >> 6, lane = threadIdx.x & 63;
  const int wr = wave >> 1, wc = wave & 1;
  const int m0 = bm * 256 + wr * 64;
  const int n0 = bn * 128 + wc * 64;
  const int lr = lane & 15;
  const int ko = lane >> 4;

  __shared__ unsigned lh[16384];   // 64 KB
  for (int i = threadIdx.x; i < 16384; i += 512) lh[i] = 0;
  __syncthreads();

  f32x4 acc[4][4];
#pragma unroll
  for (int i = 0; i < 4; ++i)
#pragma unroll
    for (int j = 0; j < 4; ++j) acc[i][j] = (f32x4){0.f, 0.f, 0.f, 0.f};

#pragma unroll
  for (int kk = 0; kk < 2; ++kk) {
    f16x8 aH[4], aL[4], bH[4], bL[4];
#pragma unroll
    for (int i = 0; i < 4; ++i) {
      const size_t aoff = (size_t)(m0 + i*16 + lr) * 1024 + h*64 + kk*32 + ko*8;
      aH[i] = *(const f16x8*)(Qh + aoff);
      aL[i] = *(const f16x8*)(Ql + aoff);
      const size_t boff = (size_t)(n0 + i*16 + lr) * 1024 + h*64 + kk*32 + ko*8;
      bH[i] = *(const f16x8*)(Kh + boff);
      bL[i] = *(const f16x8*)(Kl + boff);
    }
#pragma unroll
    for (int i = 0; i < 4; ++i)
#pragma unroll
      for (int j = 0; j < 4; ++j) {
        acc[i][j] = __builtin_amdgcn_mfma_f32_16x16x32_f16(aL[i], bL[j], acc[i][j], 0, 0, 0);
        acc[i][j] = __builtin_amdgcn_mfma_f32_16x16x32_f16(aH[i], bL[j], acc[i][j], 0, 0, 0);
        acc[i][j] = __builtin_amdgcn_mfma_f32_16x16x32_f16(aL[i], bH[j], acc[i][j], 0, 0, 0);
        acc[i][j] = __builtin_amdgcn_mfma_f32_16x16x32_f16(aH[i], bH[j], acc[i][j], 0, 0, 0);
      }
  }

#pragma unroll
  for (int i = 0; i < 4; ++i)
#pragma unroll
    for (int j = 0; j < 4; ++j)
#pragma unroll
      for (int r = 0; r < 4; ++r) {
        const float val = acc[i][j][r] * 0.125f;
        atomicAdd(&lh[sortkey(val) >> 18], 1u);
      }
  __syncthreads();
  unsigned* __restrict__ gh = ghist + (size_t)h * 16384;
  for (int i = threadIdx.x; i < 16384; i += 512) {
    const unsigned c = lh[i];
    if (c) atomicAdd(&gh[i], c);
  }
}

__global__ __launch_bounds__(256) void fb_scan14(const unsigned* __restrict__ ghist,
                                                 const unsigned* __restrict__ flagArr,
                                                 unsigned* __restrict__ state)
{
  const int hh = blockIdx.x;
  if (flagArr[hh] != 0) return;
  const int t = threadIdx.x;
  __shared__ unsigned part[256];
  __shared__ unsigned out[4];
  const unsigned* __restrict__ hb = ghist + (size_t)hh * 16384;
  unsigned s = 0;
  for (int j = 0; j < 64; ++j) s += hb[t*64 + j];
  part[t] = s;
  __syncthreads();
  if (t == 0) {
    unsigned run = 0;
    for (int i = 0; i < 256; ++i) { unsigned tmp = part[i]; part[i] = run; run += tmp; }
  }
  __syncthreads();
  const unsigned cum0 = part[t];
  if (K_A >= cum0 && K_A < cum0 + s) {
    unsigned c2 = cum0;
    for (int j = 0; j < 64; ++j) {
      const unsigned c = hb[t*64 + j];
      if (K_A < c2 + c) {
        const unsigned binA = t*64 + j;
        const unsigned residA = K_A - c2;
        unsigned binB, residB;
        if (residA + 1 < c) { binB = binA; residB = residA + 1; }
        else {
          unsigned bb = binA + 1;
          while (bb < 16384 && hb[bb] == 0) ++bb;
          if (bb >= 16384) bb = 16383;  // defensive
          binB = bb; residB = 0;
        }
        out[0] = binA; out[1] = residA; out[2] = binB; out[3] = residB;
        break;
      }
      c2 += c;
    }
  }
  __syncthreads();
  if (t < 4) state[hh*4 + t] = out[t];
}

__global__ __launch_bounds__(512) void fallback_compact(const _Float16* __restrict__ Qh,
                                                        const _Float16* __restrict__ Ql,
                                                        const _Float16* __restrict__ Kh,
                                                        const _Float16* __restrict__ Kl,
                                                        const unsigned* __restrict__ state,
                                                        const unsigned* __restrict__ flagArr,
                                                        unsigned* __restrict__ cand,
                                                        unsigned* __restrict__ ccnt)
{
  const int bn = blockIdx.x, bm = blockIdx.y, h = blockIdx.z;
  if (flagArr[h] != 0) return;
  const int wave = threadIdx.x >> 6, lane = threadIdx.x & 63;
  const int wr = wave >> 1, wc = wave & 1;
  const int m0 = bm * 256 + wr * 64;
  const int n0 = bn * 128 + wc * 64;
  const int lr = lane & 15;
  const int ko = lane >> 4;

  __shared__ unsigned lbuf[LCAP];
  __shared__ unsigned lcnt, gbase;
  if (threadIdx.x == 0) lcnt = 0;
  __syncthreads();
  const unsigned binA = state[h*4+0];
  const unsigned binB = state[h*4+2];
  unsigned* __restrict__ mycand = cand + (size_t)h * CAPC;

  f32x4 acc[4][4];
#pragma unroll
  for (int i = 0; i < 4; ++i)
#pragma unroll
    for (int j = 0; j < 4; ++j) acc[i][j] = (f32x4){0.f, 0.f, 0.f, 0.f};

#pragma unroll
  for (int kk = 0; kk < 2; ++kk) {
    f16x8 aH[4], aL[4], bH[4], bL[4];
#pragma unroll
    for (int i = 0; i < 4; ++i) {
      const size_t aoff = (size_t)(m0 + i*16 + lr) * 1024 + h*64 + kk*32 + ko*8;
      aH[i] = *(const f16x8*)(Qh + aoff);
      aL[i] = *(const f16x8*)(Ql + aoff);
      const size_t boff = (size_t)(n0 + i*16 + lr) * 1024 + h*64 + kk*32 + ko*8;
      bH[i] = *(const f16x8*)(Kh + boff);
      bL[i] = *(const f16x8*)(Kl + boff);
    }
#pragma unroll
    for (int i = 0; i < 4; ++i)
#pragma unroll
      for (int j = 0; j < 4; ++j) {
        acc[i][j] = __builtin_amdgcn_mfma_f32_16x16x32_f16(aL[i], bL[j], acc[i][j], 0, 0, 0);
        acc[i][j] = __builtin_amdgcn_mfma_f32_16x16x32_f16(aH[i], bL[j], acc[i][j], 0, 0, 0);
        acc[i][j] = __builtin_amdgcn_mfma_f32_16x16x32_f16(aL[i], bH[j], acc[i][j], 0, 0, 0);
        acc[i][j] = __builtin_amdgcn_mfma_f32_16x16x32_f16(aH[i], bH[j], acc[i][j], 0, 0, 0);
      }
  }

#pragma unroll
  for (int i = 0; i < 4; ++i)
#pragma unroll
    for (int j = 0; j < 4; ++j)
#pragma unroll
      for (int r = 0; r < 4; ++r) {
        const float val = acc[i][j][r] * 0.125f;
        const unsigned u = sortkey(val);
        const unsigned bin = u >> 18;
        if (bin == binA || bin == binB) {
          unsigned id = atomicAdd(&lcnt, 1u);
          if (id < LCAP) lbuf[id] = u;
          else { unsigned g = atomicAdd(&ccnt[h], 1u); if (g < CAPC) mycand[g] = u; }
        }
      }
  __syncthreads();
  const unsigned n = (lcnt < LCAP) ? lcnt : LCAP;
  if (threadIdx.x == 0) gbase = n ? atomicAdd(&ccnt[h], n) : 0u;
  __syncthreads();
  const unsigned gb = gbase;
  for (unsigned i = threadIdx.x; i < n; i += 512)
    if (gb + i < CAPC) mycand[gb + i] = lbuf[i];
}

// seed the parallel-final-select state after scan9/fallback resolved binA/binB
__global__ __launch_bounds__(64) void seed_fs(const unsigned* __restrict__ state,
                                              unsigned* __restrict__ sstate)
{
  const int t = threadIdx.x;
  if (t < HH * 4) sstate[t] = state[t];
}

// ---------------- parallel final select: 3 rounds of (hist over 32 blocks, scan) ----------------
__global__ __launch_bounds__(256) void fs_hist(const unsigned* __restrict__ cand,
                                               const unsigned* __restrict__ ccnt,
                                               const unsigned* __restrict__ sstate,
                                               unsigned* __restrict__ fhist,
                                               int s, int w)
{
  const int hh = blockIdx.y;
  const int t = threadIdx.x;
  const unsigned nb = 1u << w;
  __shared__ unsigned lh0[256], lh1[256];
  lh0[t] = 0; lh1[t] = 0;
  __syncthreads();
  const unsigned pfxA = sstate[hh*4+0];
  const unsigned pfxB = sstate[hh*4+2];
  unsigned n = ccnt[hh]; if (n > CAPC) n = CAPC;
  const unsigned* __restrict__ list = cand + (size_t)hh * CAPC;
  for (unsigned i = blockIdx.x * 256 + t; i < n; i += 32 * 256) {
    const unsigned u = list[i];
    if ((u >> (s + w)) == pfxA) atomicAdd(&lh0[(u >> s) & (nb - 1)], 1u);
    if ((u >> (s + w)) == pfxB) atomicAdd(&lh1[(u >> s) & (nb - 1)], 1u);
  }
  __syncthreads();
  if (t < (int)nb) {
    if (lh0[t]) atomicAdd(&fhist[hh*512 + t], lh0[t]);
    if (lh1[t]) atomicAdd(&fhist[hh*512 + 256 + t], lh1[t]);
  }
}

__global__ __launch_bounds__(256) void fs_scan(unsigned* __restrict__ fhist,
                                               unsigned* __restrict__ sstate,
                                               float* __restrict__ thr,
                                               int s, int w)
{
  const int hh = blockIdx.x;
  const int t = threadIdx.x;
  const unsigned nb = 1u << w;
  if (t == 0) {
    float vals[2];
    for (int tgt = 0; tgt < 2; ++tgt) {
      unsigned pfx = sstate[hh*4 + tgt*2];
      unsigned k   = sstate[hh*4 + tgt*2 + 1];
      const unsigned* hb = &fhist[hh*512 + tgt*256];
      unsigned cum = 0, b = 0;
      for (; b < nb; ++b) { const unsigned c = hb[b]; if (cum + c > k) break; cum += c; }
      if (b == nb) b = nb - 1;
      pfx = (pfx << w) | b;
      k -= cum;
      sstate[hh*4 + tgt*2]     = pfx;
      sstate[hh*4 + tgt*2 + 1] = k;
      if (s == 0) vals[tgt] = inv_sortkey(pfx);
    }
    if (s == 0) thr[hh] = vals[0] + QFRAC * (vals[1] - vals[0]);
  }
  __syncthreads();
  fhist[hh*512 + t] = 0;           // zero for next round
  fhist[hh*512 + 256 + t] = 0;
}

// ---------------- pass 3: flash softmax+PV, key-split over 2 halves ----------------
__global__ __launch_bounds__(256) void flash_pv_sk(const _Float16* __restrict__ Qh,
                                                   const _Float16* __restrict__ Ql,
                                                   const _Float16* __restrict__ Kh,
                                                   const _Float16* __restrict__ Kl,
                                                   const _Float16* __restrict__ VtH,
                                                   const _Float16* __restrict__ VtL,
                                                   const float* __restrict__ thrArr,
                                                   float* __restrict__ pctx,
                                                   float* __restrict__ prs)
{
  const int bm = blockIdx.x;          // 0..31 -> rows bm*64
  const int h  = blockIdx.y;
  const int half = blockIdx.z;        // 0..1
  const int wave = threadIdx.x >> 6, lane = threadIdx.x & 63;
  const int lr = lane & 15;
  const int ko = lane >> 4;
  const int m0 = bm * 64;
  const float thr = thrArr[h];

  __shared__ _Float16 Plds[64][136];  // pad 128->136
  __shared__ float rsLDS[64][4];

  // Q fragments are kt-invariant: hoist
  f16x8 qH[4][2], qL[4][2];
#pragma unroll
  for (int i = 0; i < 4; ++i)
#pragma unroll
    for (int kk = 0; kk < 2; ++kk) {
      const size_t aoff = (size_t)(m0 + i*16 + lr) * 1024 + h*64 + kk*32 + ko*8;
      qH[i][kk] = *(const f16x8*)(Qh + aoff);
      qL[i][kk] = *(const f16x8*)(Ql + aoff);
    }

  f32x4 oacc[4];
#pragma unroll
  for (int i = 0; i < 4; ++i) oacc[i] = (f32x4){0.f, 0.f, 0.f, 0.f};
  float rs[4][4];
#pragma unroll
  for (int i = 0; i < 4; ++i)
#pragma unroll
    for (int r = 0; r < 4; ++r) rs[i][r] = 0.f;

  const int d0 = wave * 16;   // PV: wave owns dims d0..d0+15

  for (int kt = half*8; kt < half*8 + 8; ++kt) {
    const int n0 = kt*128 + wave*32;   // S: wave owns keys n0..n0+31
    f32x4 sacc[4][2];
#pragma unroll
    for (int i = 0; i < 4; ++i)
#pragma unroll
      for (int j = 0; j < 2; ++j) sacc[i][j] = (f32x4){0.f, 0.f, 0.f, 0.f};

#pragma unroll
    for (int kk = 0; kk < 2; ++kk) {
      f16x8 bH[2], bL[2];
#pragma unroll
      for (int j = 0; j < 2; ++j) {
        const size_t boff = (size_t)(n0 + j*16 + lr) * 1024 + h*64 + kk*32 + ko*8;
        bH[j] = *(const f16x8*)(Kh + boff);
        bL[j] = *(const f16x8*)(Kl + boff);
      }
#pragma unroll
      for (int i = 0; i < 4; ++i)
#pragma unroll
        for (int j = 0; j < 2; ++j) {
          sacc[i][j] = __builtin_amdgcn_mfma_f32_16x16x32_f16(qL[i][kk], bL[j], sacc[i][j], 0, 0, 0);
          sacc[i][j] = __builtin_amdgcn_mfma_f32_16x16x32_f16(qH[i][kk], bL[j], sacc[i][j], 0, 0, 0);
          sacc[i][j] = __builtin_amdgcn_mfma_f32_16x16x32_f16(qL[i][kk], bH[j], sacc[i][j], 0, 0, 0);
          sacc[i][j] = __builtin_amdgcn_mfma_f32_16x16x32_f16(qH[i][kk], bH[j], sacc[i][j], 0, 0, 0);
        }
    }

    // mask + exp + P->LDS + rowsum partials
#pragma unroll
    for (int i = 0; i < 4; ++i)
#pragma unroll
      for (int j = 0; j < 2; ++j)
#pragma unroll
        for (int r = 0; r < 4; ++r) {
          const float val = sacc[i][j][r] * 0.125f;
          const float p = (val >= thr) ? __expf(val - thr - ESHIFT) : 0.f;
          rs[i][r] += p;
          Plds[i*16 + ko*4 + r][wave*32 + j*16 + lr] = (_Float16)p;
        }
    __syncthreads();

    // PV: oacc[i] over dims d0+lr, keys kt*128..+127
#pragma unroll
    for (int kk2 = 0; kk2 < 4; ++kk2) {
      f16x8 pa[4];
#pragma unroll
      for (int i = 0; i < 4; ++i)
        pa[i] = *(const f16x8*)&Plds[i*16 + lr][kk2*32 + ko*8];
      const size_t vo = (size_t)(h*64 + d0 + lr) * 2048 + kt*128 + kk2*32 + ko*8;
      const f16x8 vH = *(const f16x8*)(VtH + vo);
      const f16x8 vL = *(const f16x8*)(VtL + vo);
#pragma unroll
      for (int i = 0; i < 4; ++i) {
        oacc[i] = __builtin_amdgcn_mfma_f32_16x16x32_f16(pa[i], vL, oacc[i], 0, 0, 0);
        oacc[i] = __builtin_amdgcn_mfma_f32_16x16x32_f16(pa[i], vH, oacc[i], 0, 0, 0);
      }
    }
    __syncthreads();   // before next kt overwrites Plds
  }

  // rowsum: reduce across the 16 lanes of each ko-group, then across waves
#pragma unroll
  for (int i = 0; i < 4; ++i)
#pragma unroll
    for (int r = 0; r < 4; ++r) {
      float v = rs[i][r];
      v += __shfl_xor(v, 1); v += __shfl_xor(v, 2);
      v += __shfl_xor(v, 4); v += __shfl_xor(v, 8);
      rs[i][r] = v;
    }
  if (lr == 0) {
#pragma unroll
    for (int i = 0; i < 4; ++i)
#pragma unroll
      for (int r = 0; r < 4; ++r)
        rsLDS[i*16 + ko*4 + r][wave] = rs[i][r];
  }
  __syncthreads();

  // write partial rowsums
  if (wave == 0 && lr == 0) {
#pragma unroll
    for (int i = 0; i < 4; ++i)
#pragma unroll
      for (int r = 0; r < 4; ++r) {
        const int lrow = i*16 + ko*4 + r;
        prs[half*32768 + h*2048 + m0 + lrow] =
            rsLDS[lrow][0] + rsLDS[lrow][1] + rsLDS[lrow][2] + rsLDS[lrow][3];
      }
  }

  // store raw partial O
  float* __restrict__ pc = pctx + (size_t)half * PLANE;
#pragma unroll
  for (int i = 0; i < 4; ++i)
#pragma unroll
    for (int r = 0; r < 4; ++r) {
      const int lrow = i*16 + ko*4 + r;
      pc[(size_t)(m0 + lrow) * 1024 + h*64 + d0 + lr] = oacc[i][r];
    }
}

// ---------------- host ----------------
extern "C" void kernel_launch(void* const* d_in, const int* in_sizes, int n_in,
                              void* d_out, int out_size, void* d_ws, size_t ws_size,
                              hipStream_t stream)
{
  const float* x  = (const float*)d_in[0];
  const float* Wq = (const float*)d_in[1];
  const float* bq = (const float*)d_in[2];
  const float* Wk = (const float*)d_in[3];
  const float* bk = (const float*)d_in[4];
  const float* Wv = (const float*)d_in[5];
  const float* bv = (const float*)d_in[6];
  const float* Wo = (const float*)d_in[7];
  const float* bo = (const float*)d_in[8];
  float* out = (float*)d_out;
  char*  ws  = (char*)d_ws;

  const size_t MB = 1u << 20;
  _Float16* xh      = (_Float16*)(ws + 0*MB);
  _Float16* xl      = (_Float16*)(ws + 4*MB);
  _Float16* wplanes = (_Float16*)(ws + 8*MB);    // 8 x 2 MiB transposed W planes
  _Float16* Qh      = (_Float16*)(ws + 24*MB);
  _Float16* Ql      = (_Float16*)(ws + 28*MB);
  _Float16* Kh      = (_Float16*)(ws + 32*MB);
  _Float16* Kl      = (_Float16*)(ws + 36*MB);
  _Float16* VtH     = (_Float16*)(ws + 40*MB);   // [1024 dims][2048 rows]
  _Float16* VtL     = (_Float16*)(ws + 44*MB);
  _Float16* ctxh    = (_Float16*)(ws + 48*MB);
  _Float16* ctxl    = (_Float16*)(ws + 52*MB);
  const size_t base = 56*MB;
  unsigned* state    = (unsigned*)(ws + base);
  float*    thr      = (float*)(ws + base + 4096);
  unsigned* ccnt     = (unsigned*)(ws + base + 8192);
  unsigned* flag     = (unsigned*)(ws + base + 12288);
  unsigned* rangeLo  = (unsigned*)(ws + base + 16384);
  unsigned* rangeHi  = (unsigned*)(ws + base + 20480);
  unsigned* sstate   = (unsigned*)(ws + base + 24576);
  unsigned* fhist    = (unsigned*)(ws + base + 28672);  // HH*512*4 = 32 KiB
  unsigned* cntBelow = (unsigned*)(ws + base + 65536);
  unsigned* ghist9   = (unsigned*)(ws + base + 69632);  // HH*16 u32
  unsigned* ghist    = (unsigned*)(ws + 57*MB);   // 1 MiB (fallback only)
  unsigned* shist    = (unsigned*)(ws + 58*MB);   // 1 MiB
  unsigned* cand     = (unsigned*)(ws + 59*MB);   // HH * CAPC * 4 = 20 MiB
  float*    prs      = (float*)(ws + 80*MB);      // 2 x 16 x 2048 f32
  float*    pbuf     = (float*)(ws + 81*MB);      // 6 x 8 MiB partials
  float*    pctx     = pbuf;                      // planes 0,1 (post combine_qk)
  float*    pO       = pbuf + (size_t)2 * PLANE;  // planes 2,3

  split_x<<<2048, 256, 0, stream>>>(x, xh, xl);
  split_wT<<<dim3(16, 16, 4), 256, 0, stream>>>(Wq, Wk, Wv, Wo, wplanes);
  gemm_qkv_part<<<dim3(8, 16, 6), 256, 0, stream>>>(xh, xl, wplanes, pbuf);
  combine_qk<<<dim3(2048, 2), 256, 0, stream>>>(pbuf, bq, bk, Qh, Ql, Kh, Kl);
  combine_vT<<<dim3(16, 32), 256, 0, stream>>>(pbuf, bv, VtH, VtL);

  init_sel<<<256, 256, 0, stream>>>(ghist, shist, ccnt, flag, fhist, cntBelow, ghist9);
  sample_hist<<<dim3(16, HH), 256, 0, stream>>>(Qh, Ql, Kh, Kl, shist);
  sample_scan<<<HH, 256, 0, stream>>>(shist, rangeLo, rangeHi);
  range_count<<<dim3(16, 8, HH), 512, 0, stream>>>(Qh, Ql, Kh, Kl, rangeLo, rangeHi,
                                                   cand, ccnt, cntBelow, ghist9);
  scan9<<<1, 64, 0, stream>>>(ghist9, cntBelow, rangeLo, rangeHi, ccnt, state, flag);
  // fallback chain (early-exit per head when prediction held)
  fb_scores_hist<<<dim3(16, 8, HH), 512, 0, stream>>>(Qh, Ql, Kh, Kl, flag, ghist);
  fb_scan14<<<HH, 256, 0, stream>>>(ghist, flag, state);
  fallback_compact<<<dim3(16, 8, HH), 512, 0, stream>>>(Qh, Ql, Kh, Kl, state, flag, cand, ccnt);
  seed_fs<<<1, 64, 0, stream>>>(state, sstate);
  // parallel final select: rounds (s,w) = (10,8), (2,8), (0,2)
  fs_hist<<<dim3(32, HH), 256, 0, stream>>>(cand, ccnt, sstate, fhist, 10, 8);
  fs_scan<<<HH, 256, 0, stream>>>(fhist, sstate, thr, 10, 8);
  fs_hist<<<dim3(32, HH), 256, 0, stream>>>(cand, ccnt, sstate, fhist, 2, 8);
  fs_scan<<<HH, 256, 0, stream>>>(fhist, sstate, thr, 2, 8);
  fs_hist<<<dim3(32, HH), 256, 0, stream>>>(cand, ccnt, sstate, fhist, 0, 2);
  fs_scan<<<HH, 256, 0, stream>>>(fhist, sstate, thr, 0, 2);

  flash_pv_sk<<<dim3(32, HH, 2), 256, 0, stream>>>(Qh, Ql, Kh, Kl, VtH, VtL, thr, pctx, prs);
  combine_ctx<<<2048, 256, 0, stream>>>(pctx, prs, ctxh, ctxl);

  gemm_o_part<<<dim3(8, 16, 2), 256, 0, stream>>>(ctxh, ctxl, wplanes, pO);
  combine_o<<<2048, 256, 0, stream>>>(pO, bo, out);
}

// Round 25
// 522.041 us; speedup vs baseline: 1.1302x; 1.0024x over previous
//
#include <hip/hip_runtime.h>
#include <math.h>

#define SS 2048
#define DD 1024
#define HH 16
#define CAPC 327680u  // candidate slots per head (range ~5 bins x ~16K/bin ~ 83K expected)
#define LCAP 2048     // per-block LDS candidate buffer (expected ~670/block)
#define RBIN 2        // predicted-bin safety margin (r22-validated; RBIN=1 failed post-timing r23)

// quantile index: floor(0.95*(S*S-1)) = floor(3984587.85)
#define K_A 3984587u
#define K_B 3984588u
#define QFRAC 0.85f
#define WSCALE 2048.0f      // W planes pre-scaled so lo-residuals stay normal fp16
#define WSCALE_INV (1.0f/2048.0f)
#define ESHIFT 4.0f         // exp(s - thr - ESHIFT): kept P in [e^-4, ~e^6] — fp16-safe
#define PLANE 2097152       // floats per 2048x1024 fp32 partial plane (8 MiB)
#define NSAMP_RANK 124518u  // floor(0.95 * 131072) — sample quantile rank

typedef _Float16 f16x8 __attribute__((ext_vector_type(8)));
typedef _Float16 f16x4 __attribute__((ext_vector_type(4)));
typedef float    f32x4 __attribute__((ext_vector_type(4)));

__device__ __forceinline__ unsigned sortkey(float f) {
  unsigned b = __float_as_uint(f);
  return (b & 0x80000000u) ? ~b : (b | 0x80000000u);
}
__device__ __forceinline__ float inv_sortkey(unsigned u) {
  unsigned b = (u & 0x80000000u) ? (u ^ 0x80000000u) : ~u;
  return __uint_as_float(b);
}

// ---------------- input splitting ----------------
__global__ __launch_bounds__(256) void split_x(const float* __restrict__ x,
                                               _Float16* __restrict__ xh,
                                               _Float16* __restrict__ xl)
{
  const int i = blockIdx.x * 256 + threadIdx.x;   // float4 index, 524288 total
  float4 v = ((const float4*)x)[i];
  float vv[4] = {v.x, v.y, v.z, v.w};
  f16x4 h, l;
#pragma unroll
  for (int j = 0; j < 4; ++j) {
    _Float16 hh = (_Float16)vv[j];
    h[j] = hh;
    l[j] = (_Float16)(vv[j] - (float)hh);
  }
  ((f16x4*)xh)[i] = h;
  ((f16x4*)xl)[i] = l;
}

// W -> transposed hi/lo fp16 planes WT[n][k], scaled by 2048 (keeps lo normal).
__global__ __launch_bounds__(256) void split_wT(const float* __restrict__ Wq,
                                                const float* __restrict__ Wk,
                                                const float* __restrict__ Wv,
                                                const float* __restrict__ Wo,
                                                _Float16* __restrict__ wplanes)
{
  const int z = blockIdx.z;
  const float* W = (z == 0) ? Wq : (z == 1) ? Wk : (z == 2) ? Wv : Wo;
  _Float16* WhT = wplanes + (size_t)(2*z)     * (1024*1024);
  _Float16* WlT = wplanes + (size_t)(2*z + 1) * (1024*1024);
  __shared__ float tile[64][65];
  const int t  = threadIdx.x;
  const int r  = t >> 2;         // 0..63
  const int c0 = (t & 3) * 16;   // 0/16/32/48
  const int k0 = blockIdx.y * 64;
  const int n0 = blockIdx.x * 64;
#pragma unroll
  for (int j = 0; j < 4; ++j) {
    float4 v = *(const float4*)&W[(size_t)(k0 + r) * 1024 + n0 + c0 + j*4];
    tile[r][c0+j*4+0] = v.x; tile[r][c0+j*4+1] = v.y;
    tile[r][c0+j*4+2] = v.z; tile[r][c0+j*4+3] = v.w;
  }
  __syncthreads();
  f16x8 h0, h1, l0, l1;
#pragma unroll
  for (int j = 0; j < 8; ++j) {
    float v = tile[c0 + j][r] * WSCALE;
    _Float16 h = (_Float16)v;
    h0[j] = h; l0[j] = (_Float16)(v - (float)h);
  }
#pragma unroll
  for (int j = 0; j < 8; ++j) {
    float v = tile[c0 + 8 + j][r] * WSCALE;
    _Float16 h = (_Float16)v;
    h1[j] = h; l1[j] = (_Float16)(v - (float)h);
  }
  const size_t o = (size_t)(n0 + r) * 1024 + k0 + c0;
  *(f16x8*)&WhT[o]     = h0;
  *(f16x8*)&WhT[o + 8] = h1;
  *(f16x8*)&WlT[o]     = l0;
  *(f16x8*)&WlT[o + 8] = l1;
}

// ---------------- split-K MFMA GEMM partial ----------------
__device__ __forceinline__ void gemm_mfma_part(const _Float16* __restrict__ Ah,
                                               const _Float16* __restrict__ Al,
                                               const _Float16* __restrict__ BhT,
                                               const _Float16* __restrict__ BlT,
                                               float* __restrict__ pout,
                                               int bm, int bn, int kh)
{
  const int wave = threadIdx.x >> 6, lane = threadIdx.x & 63;
  const int wr = wave >> 1, wc = wave & 1;
  const int m0 = bm * 128 + wr * 64;
  const int n0 = bn * 128 + wc * 64;
  const int lr = lane & 15;
  const int ko = lane >> 4;

  f32x4 acc[4][4];
#pragma unroll
  for (int i = 0; i < 4; ++i)
#pragma unroll
    for (int j = 0; j < 4; ++j) acc[i][j] = (f32x4){0.f, 0.f, 0.f, 0.f};

  for (int kk = kh*16; kk < kh*16 + 16; ++kk) {
    const int kof = kk*32 + ko*8;
    f16x8 aH[4], aL[4], bH[4], bL[4];
#pragma unroll
    for (int i = 0; i < 4; ++i) {
      const size_t aoff = (size_t)(m0 + i*16 + lr) * 1024 + kof;
      aH[i] = *(const f16x8*)(Ah + aoff);
      aL[i] = *(const f16x8*)(Al + aoff);
      const size_t boff = (size_t)(n0 + i*16 + lr) * 1024 + kof;
      bH[i] = *(const f16x8*)(BhT + boff);
      bL[i] = *(const f16x8*)(BlT + boff);
    }
#pragma unroll
    for (int i = 0; i < 4; ++i)
#pragma unroll
      for (int j = 0; j < 4; ++j) {
        acc[i][j] = __builtin_amdgcn_mfma_f32_16x16x32_f16(aL[i], bL[j], acc[i][j], 0, 0, 0);
        acc[i][j] = __builtin_amdgcn_mfma_f32_16x16x32_f16(aH[i], bL[j], acc[i][j], 0, 0, 0);
        acc[i][j] = __builtin_amdgcn_mfma_f32_16x16x32_f16(aL[i], bH[j], acc[i][j], 0, 0, 0);
        acc[i][j] = __builtin_amdgcn_mfma_f32_16x16x32_f16(aH[i], bH[j], acc[i][j], 0, 0, 0);
      }
  }

#pragma unroll
  for (int i = 0; i < 4; ++i)
#pragma unroll
    for (int j = 0; j < 4; ++j)
#pragma unroll
      for (int r = 0; r < 4; ++r) {
        const int row = m0 + i*16 + ko*4 + r;
        const int col = n0 + j*16 + lr;
        pout[(size_t)row * 1024 + col] = acc[i][j][r];
      }
}

__global__ __launch_bounds__(256) void gemm_qkv_part(const _Float16* __restrict__ xh,
                                                     const _Float16* __restrict__ xl,
                                                     const _Float16* __restrict__ wplanes,
                                                     float* __restrict__ pbuf)
{
  const int z = blockIdx.z;           // 0..5: gemm_id*2 + khalf
  const int g = z >> 1, kh = z & 1;
  const _Float16* BhT = wplanes + (size_t)(2*g)     * (1024*1024);
  const _Float16* BlT = wplanes + (size_t)(2*g + 1) * (1024*1024);
  gemm_mfma_part(xh, xl, BhT, BlT, pbuf + (size_t)z * PLANE,
                 blockIdx.y, blockIdx.x, kh);
}

__global__ __launch_bounds__(256) void gemm_o_part(const _Float16* __restrict__ ctxh,
                                                   const _Float16* __restrict__ ctxl,
                                                   const _Float16* __restrict__ wplanes,
                                                   float* __restrict__ pO)
{
  const int kh = blockIdx.z;          // 0..1
  gemm_mfma_part(ctxh, ctxl,
                 wplanes + (size_t)6 * (1024*1024),
                 wplanes + (size_t)7 * (1024*1024),
                 pO + (size_t)kh * PLANE, blockIdx.y, blockIdx.x, kh);
}

// ---------------- combine kernels ----------------
__global__ __launch_bounds__(256) void combine_qk(const float* __restrict__ pbuf,
                                                  const float* __restrict__ bq,
                                                  const float* __restrict__ bk,
                                                  _Float16* __restrict__ Qh,
                                                  _Float16* __restrict__ Ql,
                                                  _Float16* __restrict__ Kh,
                                                  _Float16* __restrict__ Kl)
{
  const int which = blockIdx.y;       // 0=Q, 1=K
  const float* p0 = pbuf + (size_t)(which*2)     * PLANE;
  const float* p1 = pbuf + (size_t)(which*2 + 1) * PLANE;
  const float* bias = which ? bk : bq;
  _Float16* Oh = which ? Kh : Qh;
  _Float16* Ol = which ? Kl : Ql;
  const int i = blockIdx.x * 256 + threadIdx.x;   // f4 index, 524288
  const int coloff = (i & 255) * 4;
  float4 a = ((const float4*)p0)[i];
  float4 b = ((const float4*)p1)[i];
  float av[4] = {a.x, a.y, a.z, a.w};
  float bv[4] = {b.x, b.y, b.z, b.w};
  f16x4 h, l;
#pragma unroll
  for (int j = 0; j < 4; ++j) {
    const float val = (av[j] + bv[j]) * WSCALE_INV + bias[coloff + j];
    _Float16 hh = (_Float16)val;
    h[j] = hh;
    l[j] = (_Float16)(val - (float)hh);
  }
  ((f16x4*)Oh)[i] = h;
  ((f16x4*)Ol)[i] = l;
}

// V: combine + transpose to Vt[dim][row] hi/lo planes (LDS 64x64 tile).
__global__ __launch_bounds__(256) void combine_vT(const float* __restrict__ pbuf,
                                                  const float* __restrict__ bv,
                                                  _Float16* __restrict__ VtH,
                                                  _Float16* __restrict__ VtL)
{
  const float* p0 = pbuf + (size_t)4 * PLANE;
  const float* p1 = pbuf + (size_t)5 * PLANE;
  __shared__ float tile[64][65];
  const int t  = threadIdx.x;
  const int d0 = blockIdx.x * 64;     // dim tile
  const int m0 = blockIdx.y * 64;     // row tile
  {
    const int r  = t >> 2;            // row 0..63
    const int c0 = (t & 3) * 16;
#pragma unroll
    for (int j = 0; j < 4; ++j) {
      const size_t o = (size_t)(m0 + r) * 1024 + d0 + c0 + j*4;
      float4 a = *(const float4*)(p0 + o);
      float4 b = *(const float4*)(p1 + o);
      tile[r][c0+j*4+0] = (a.x + b.x) * WSCALE_INV + bv[d0 + c0 + j*4 + 0];
      tile[r][c0+j*4+1] = (a.y + b.y) * WSCALE_INV + bv[d0 + c0 + j*4 + 1];
      tile[r][c0+j*4+2] = (a.z + b.z) * WSCALE_INV + bv[d0 + c0 + j*4 + 2];
      tile[r][c0+j*4+3] = (a.w + b.w) * WSCALE_INV + bv[d0 + c0 + j*4 + 3];
    }
  }
  __syncthreads();
  {
    const int d  = t >> 2;            // dim 0..63
    const int rg = (t & 3) * 16;      // row group
#pragma unroll
    for (int j = 0; j < 4; ++j) {
      f16x4 hv, lv;
#pragma unroll
      for (int r = 0; r < 4; ++r) {
        const float val = tile[rg + j*4 + r][d];
        _Float16 h = (_Float16)val;
        hv[r] = h; lv[r] = (_Float16)(val - (float)h);
      }
      const size_t o = (size_t)(d0 + d) * 2048 + m0 + rg + j*4;
      *(f16x4*)&VtH[o] = hv;
      *(f16x4*)&VtL[o] = lv;
    }
  }
}

__global__ __launch_bounds__(256) void combine_o(const float* __restrict__ pO,
                                                 const float* __restrict__ bo,
                                                 float* __restrict__ out)
{
  const float* p0 = pO;
  const float* p1 = pO + (size_t)1 * PLANE;
  const int i = blockIdx.x * 256 + threadIdx.x;
  const int coloff = (i & 255) * 4;
  float4 a = ((const float4*)p0)[i];
  float4 b = ((const float4*)p1)[i];
  float4 o;
  o.x = (a.x + b.x) * WSCALE_INV + bo[coloff + 0];
  o.y = (a.y + b.y) * WSCALE_INV + bo[coloff + 1];
  o.z = (a.z + b.z) * WSCALE_INV + bo[coloff + 2];
  o.w = (a.w + b.w) * WSCALE_INV + bo[coloff + 3];
  ((float4*)out)[i] = o;
}

// ctx: (p0+p1) / (rs0+rs1), then fp16 hi/lo split.
__global__ __launch_bounds__(256) void combine_ctx(const float* __restrict__ pctx,
                                                   const float* __restrict__ prs,
                                                   _Float16* __restrict__ ctxh,
                                                   _Float16* __restrict__ ctxl)
{
  const float* p0 = pctx;
  const float* p1 = pctx + (size_t)1 * PLANE;
  const int i = blockIdx.x * 256 + threadIdx.x;   // f4 index, 524288
  const int row = i >> 8;
  const int cd  = (i & 255) * 4;
  const int h   = cd >> 6;
  const float rs = prs[h*2048 + row] + prs[32768 + h*2048 + row];
  float4 a = ((const float4*)p0)[i];
  float4 b = ((const float4*)p1)[i];
  float av[4] = {a.x, a.y, a.z, a.w};
  float bv[4] = {b.x, b.y, b.z, b.w};
  f16x4 hh, ll;
#pragma unroll
  for (int j = 0; j < 4; ++j) {
    const float val = (av[j] + bv[j]) / rs;
    _Float16 hv = (_Float16)val;
    hh[j] = hv;
    ll[j] = (_Float16)(val - (float)hv);
  }
  ((f16x4*)ctxh)[i] = hh;
  ((f16x4*)ctxl)[i] = ll;
}

// ---------------- selection init ----------------
__global__ __launch_bounds__(256) void init_sel(unsigned* __restrict__ ghist,
                                                unsigned* __restrict__ shist,
                                                unsigned* __restrict__ ccnt,
                                                unsigned* __restrict__ flag,
                                                unsigned* __restrict__ fhist,
                                                unsigned* __restrict__ cntBelow,
                                                unsigned* __restrict__ ghist9)
{
  int i = blockIdx.x * 256 + threadIdx.x;
  for (; i < HH * 16384; i += gridDim.x * 256) { ghist[i] = 0; shist[i] = 0; }
  const int j = blockIdx.x * 256 + threadIdx.x;
  if (j < HH * 512) fhist[j] = 0;
  if (j < HH * 16) ghist9[j] = 0;
  if (blockIdx.x == 0 && threadIdx.x < HH) {
    ccnt[threadIdx.x] = 0; flag[threadIdx.x] = 0; cntBelow[threadIdx.x] = 0;
  }
}

// ---------------- sampling pass: 64 of 2048 query rows (stride 32) ----------------
__global__ __launch_bounds__(256) void sample_hist(const _Float16* __restrict__ Qh,
                                                   const _Float16* __restrict__ Ql,
                                                   const _Float16* __restrict__ Kh,
                                                   const _Float16* __restrict__ Kl,
                                                   unsigned* __restrict__ shist)
{
  const int kb = blockIdx.x, h = blockIdx.y;
  const int wave = threadIdx.x >> 6, lane = threadIdx.x & 63;
  const int lr = lane & 15, ko = lane >> 4;
  const int n0 = kb*128 + wave*32;

  __shared__ unsigned lh[16384];   // 64 KB
  for (int i = threadIdx.x; i < 16384; i += 256) lh[i] = 0;
  __syncthreads();

  f32x4 acc[4][2];
#pragma unroll
  for (int i = 0; i < 4; ++i)
#pragma unroll
    for (int j = 0; j < 2; ++j) acc[i][j] = (f32x4){0.f, 0.f, 0.f, 0.f};

#pragma unroll
  for (int kk = 0; kk < 2; ++kk) {
    f16x8 aH[4], aL[4], bH[2], bL[2];
#pragma unroll
    for (int i = 0; i < 4; ++i) {
      const size_t aoff = (size_t)((i*16 + lr) * 32) * 1024 + h*64 + kk*32 + ko*8;
      aH[i] = *(const f16x8*)(Qh + aoff);
      aL[i] = *(const f16x8*)(Ql + aoff);
    }
#pragma unroll
    for (int j = 0; j < 2; ++j) {
      const size_t boff = (size_t)(n0 + j*16 + lr) * 1024 + h*64 + kk*32 + ko*8;
      bH[j] = *(const f16x8*)(Kh + boff);
      bL[j] = *(const f16x8*)(Kl + boff);
    }
#pragma unroll
    for (int i = 0; i < 4; ++i)
#pragma unroll
      for (int j = 0; j < 2; ++j) {
        acc[i][j] = __builtin_amdgcn_mfma_f32_16x16x32_f16(aL[i], bL[j], acc[i][j], 0, 0, 0);
        acc[i][j] = __builtin_amdgcn_mfma_f32_16x16x32_f16(aH[i], bL[j], acc[i][j], 0, 0, 0);
        acc[i][j] = __builtin_amdgcn_mfma_f32_16x16x32_f16(aL[i], bH[j], acc[i][j], 0, 0, 0);
        acc[i][j] = __builtin_amdgcn_mfma_f32_16x16x32_f16(aH[i], bH[j], acc[i][j], 0, 0, 0);
      }
  }

#pragma unroll
  for (int i = 0; i < 4; ++i)
#pragma unroll
    for (int j = 0; j < 2; ++j)
#pragma unroll
      for (int r = 0; r < 4; ++r) {
        const float val = acc[i][j][r] * 0.125f;
        atomicAdd(&lh[sortkey(val) >> 18], 1u);
      }
  __syncthreads();
  unsigned* __restrict__ gh = shist + (size_t)h * 16384;
  for (int i = threadIdx.x; i < 16384; i += 256) {
    const unsigned c = lh[i];
    if (c) atomicAdd(&gh[i], c);
  }
}

// find sample-quantile bin; emit conservative range [bin-RBIN, bin+RBIN]
__global__ __launch_bounds__(256) void sample_scan(const unsigned* __restrict__ shist,
                                                   unsigned* __restrict__ rangeLo,
                                                   unsigned* __restrict__ rangeHi)
{
  const int hh = blockIdx.x;
  const int t = threadIdx.x;
  __shared__ unsigned part[256];
  __shared__ unsigned outb;
  if (t == 0) outb = 8192u;  // defensive default
  const unsigned* __restrict__ hb = shist + (size_t)hh * 16384;
  unsigned s = 0;
  for (int j = 0; j < 64; ++j) s += hb[t*64 + j];
  part[t] = s;
  __syncthreads();
  if (t == 0) {
    unsigned run = 0;
    for (int i = 0; i < 256; ++i) { unsigned tmp = part[i]; part[i] = run; run += tmp; }
  }
  __syncthreads();
  const unsigned cum0 = part[t];
  if (NSAMP_RANK >= cum0 && NSAMP_RANK < cum0 + s) {
    unsigned c2 = cum0;
    for (int j = 0; j < 64; ++j) {
      const unsigned c = hb[t*64 + j];
      if (NSAMP_RANK < c2 + c) { outb = t*64 + j; break; }
      c2 += c;
    }
  }
  __syncthreads();
  if (t == 0) {
    const int b = (int)outb;
    rangeLo[hh] = (unsigned)((b - RBIN < 0) ? 0 : b - RBIN);
    rangeHi[hh] = (unsigned)((b + RBIN > 16383) ? 16383 : b + RBIN);
  }
}

// ---------------- pass 1: count-below + 5-bin range histogram + compaction ----------------
// r17-measured-best structure with RBIN=2 (r22-validated). 1D grid with an
// XCD-aware bijective swizzle: each XCD gets a contiguous 256-block chunk
// (= exactly 2 heads, ~2 MB Q+K working set, fits the 4 MB per-XCD L2).
// Pure blockIdx->(bn,bm,h) remap; all cross-block accumulations are
// order-invariant, so output is bit-identical to the 3D-grid version.
__global__ __launch_bounds__(512) void range_count(const _Float16* __restrict__ Qh,
                                                   const _Float16* __restrict__ Ql,
                                                   const _Float16* __restrict__ Kh,
                                                   const _Float16* __restrict__ Kl,
                                                   const unsigned* __restrict__ rangeLo,
                                                   const unsigned* __restrict__ rangeHi,
                                                   unsigned* __restrict__ cand,
                                                   unsigned* __restrict__ ccnt,
                                                   unsigned* __restrict__ cntBelow,
                                                   unsigned* __restrict__ ghist9)
{
  const int wgid = blockIdx.x;                       // 0..2047
  const int swz  = (wgid & 7) * 256 + (wgid >> 3);   // XCD k gets swz in [k*256, k*256+256)
  const int h    = swz >> 7;                         // 128 blocks per head
  const int bm   = (swz >> 4) & 7;
  const int bn   = swz & 15;
  const int wave = threadIdx.x >> 6, lane = threadIdx.x & 63;
  const int wr = wave >> 1, wc = wave & 1;
  const int m0 = bm * 256 + wr * 64;
  const int n0 = bn * 128 + wc * 64;
  const int lr = lane & 15;
  const int ko = lane >> 4;
  const unsigned lo = rangeLo[h], hi = rangeHi[h];
  unsigned* __restrict__ mycand = cand + (size_t)h * CAPC;

  __shared__ unsigned lh9[16];
  __shared__ unsigned lbuf[LCAP];  // 8 KB
  __shared__ unsigned lcnt, gbase, lbelow;
  if (threadIdx.x < 16) lh9[threadIdx.x] = 0;
  if (threadIdx.x == 0) { lcnt = 0; lbelow = 0; }
  __syncthreads();

  f32x4 acc[4][4];
#pragma unroll
  for (int i = 0; i < 4; ++i)
#pragma unroll
    for (int j = 0; j < 4; ++j) acc[i][j] = (f32x4){0.f, 0.f, 0.f, 0.f};

#pragma unroll
  for (int kk = 0; kk < 2; ++kk) {
    f16x8 aH[4], aL[4], bH[4], bL[4];
#pragma unroll
    for (int i = 0; i < 4; ++i) {
      const size_t aoff = (size_t)(m0 + i*16 + lr) * 1024 + h*64 + kk*32 + ko*8;
      aH[i] = *(const f16x8*)(Qh + aoff);
      aL[i] = *(const f16x8*)(Ql + aoff);
      const size_t boff = (size_t)(n0 + i*16 + lr) * 1024 + h*64 + kk*32 + ko*8;
      bH[i] = *(const f16x8*)(Kh + boff);
      bL[i] = *(const f16x8*)(Kl + boff);
    }
#pragma unroll
    for (int i = 0; i < 4; ++i)
#pragma unroll
      for (int j = 0; j < 4; ++j) {
        acc[i][j] = __builtin_amdgcn_mfma_f32_16x16x32_f16(aL[i], bL[j], acc[i][j], 0, 0, 0);
        acc[i][j] = __builtin_amdgcn_mfma_f32_16x16x32_f16(aH[i], bL[j], acc[i][j], 0, 0, 0);
        acc[i][j] = __builtin_amdgcn_mfma_f32_16x16x32_f16(aL[i], bH[j], acc[i][j], 0, 0, 0);
        acc[i][j] = __builtin_amdgcn_mfma_f32_16x16x32_f16(aH[i], bH[j], acc[i][j], 0, 0, 0);
      }
  }

  unsigned nb = 0;
#pragma unroll
  for (int i = 0; i < 4; ++i)
#pragma unroll
    for (int j = 0; j < 4; ++j)
#pragma unroll
      for (int r = 0; r < 4; ++r) {
        const float val = acc[i][j][r] * 0.125f;
        const unsigned u = sortkey(val);
        const unsigned bin = u >> 18;
        nb += (bin < lo) ? 1u : 0u;
        if (bin >= lo && bin <= hi) {
          atomicAdd(&lh9[bin - lo], 1u);
          unsigned id = atomicAdd(&lcnt, 1u);
          if (id < LCAP) lbuf[id] = u;
          else { unsigned g = atomicAdd(&ccnt[h], 1u); if (g < CAPC) mycand[g] = u; }
        }
      }
  // wave-reduce below-count, one LDS atomic per wave
  nb += __shfl_xor(nb, 1);  nb += __shfl_xor(nb, 2);
  nb += __shfl_xor(nb, 4);  nb += __shfl_xor(nb, 8);
  nb += __shfl_xor(nb, 16); nb += __shfl_xor(nb, 32);
  if (lane == 0) atomicAdd(&lbelow, nb);
  __syncthreads();
  if (threadIdx.x < 16) {
    const unsigned c = lh9[threadIdx.x];
    if (c) atomicAdd(&ghist9[h*16 + threadIdx.x], c);
  }
  if (threadIdx.x == 0 && lbelow) atomicAdd(&cntBelow[h], lbelow);
  const unsigned n = (lcnt < LCAP) ? lcnt : LCAP;
  if (threadIdx.x == 0) gbase = n ? atomicAdd(&ccnt[h], n) : 0u;
  __syncthreads();
  const unsigned gb = gbase;
  for (unsigned i = threadIdx.x; i < n; i += 512)
    if (gb + i < CAPC) mycand[gb + i] = lbuf[i];
}

// ---------------- scan over range: exact binA/residA/binB/residB ----------------
__global__ __launch_bounds__(64) void scan9(const unsigned* __restrict__ ghist9,
                                            const unsigned* __restrict__ cntBelow,
                                            const unsigned* __restrict__ rangeLo,
                                            const unsigned* __restrict__ rangeHi,
                                            unsigned* __restrict__ ccnt,
                                            unsigned* __restrict__ state,
                                            unsigned* __restrict__ flag)
{
  const int hh = threadIdx.x;
  if (hh >= HH) return;
  const unsigned lo = rangeLo[hh], hi = rangeHi[hh];
  const int nbins = (int)(hi - lo + 1);
  const unsigned base = cntBelow[hh];
  unsigned ok = 0;
  unsigned binA = 0, residA = 0, binB = 0, residB = 0;
  if (K_A >= base) {
    unsigned k = K_A - base;
    unsigned cum = 0;
    for (int b = 0; b < nbins; ++b) {
      const unsigned c = ghist9[hh*16 + b];
      if (k < cum + c) {
        binA = lo + b;
        residA = k - cum;
        if (residA + 1 < c) { binB = binA; residB = residA + 1; ok = 1; }
        else {
          for (int b2 = b + 1; b2 < nbins; ++b2) {
            if (ghist9[hh*16 + b2]) { binB = lo + b2; residB = 0; ok = 1; break; }
          }
        }
        break;
      }
      cum += c;
    }
  }
  if (ccnt[hh] > CAPC) ok = 0;
  flag[hh] = ok;
  if (ok) {
    state[hh*4+0] = binA; state[hh*4+1] = residA;
    state[hh*4+2] = binB; state[hh*4+3] = residB;
  } else {
    ccnt[hh] = 0;   // fallback recollects cleanly
  }
}

// ---------------- fallback chain (early-exit when prediction held) ----------------
__global__ __launch_bounds__(512) void fb_scores_hist(const _Float16* __restrict__ Qh,
                                                      const _Float16* __restrict__ Ql,
                                                      const _Float16* __restrict__ Kh,
                                                      const _Float16* __restrict__ Kl,
                                                      const unsigned* __restrict__ flagArr,
                                                      unsigned* __restrict__ ghist)
{
  const int bn = blockIdx.x, bm = blockIdx.y, h = blockIdx.z;
  if (flagArr[h] != 0) return;
  const int wave = threadIdx.x >> 6, lane = threadIdx.x & 63;
  const int wr = wave >> 1, wc = wave & 1;
  const int m0 = bm * 256 + wr * 64;
  const int n0 = bn * 128 + wc * 64;
  const int lr = lane & 15;
  const int ko = lane >> 4;

  __shared__ unsigned lh[16384];   // 64 KB
  for (int i = threadIdx.x; i < 16384; i += 512) lh[i] = 0;
  __syncthreads();

  f32x4 acc[4][4];
#pragma unroll
  for (int i = 0; i < 4; ++i)
#pragma unroll
    for (int j = 0; j < 4; ++j) acc[i][j] = (f32x4){0.f, 0.f, 0.f, 0.f};

#pragma unroll
  for (int kk = 0; kk < 2; ++kk) {
    f16x8 aH[4], aL[4], bH[4], bL[4];
#pragma unroll
    for (int i = 0; i < 4; ++i) {
      const size_t aoff = (size_t)(m0 + i*16 + lr) * 1024 + h*64 + kk*32 + ko*8;
      aH[i] = *(const f16x8*)(Qh + aoff);
      aL[i] = *(const f16x8*)(Ql + aoff);
      const size_t boff = (size_t)(n0 + i*16 + lr) * 1024 + h*64 + kk*32 + ko*8;
      bH[i] = *(const f16x8*)(Kh + boff);
      bL[i] = *(const f16x8*)(Kl + boff);
    }
#pragma unroll
    for (int i = 0; i < 4; ++i)
#pragma unroll
      for (int j = 0; j < 4; ++j) {
        acc[i][j] = __builtin_amdgcn_mfma_f32_16x16x32_f16(aL[i], bL[j], acc[i][j], 0, 0, 0);
        acc[i][j] = __builtin_amdgcn_mfma_f32_16x16x32_f16(aH[i], bL[j], acc[i][j], 0, 0, 0);
        acc[i][j] = __builtin_amdgcn_mfma_f32_16x16x32_f16(aL[i], bH[j], acc[i][j], 0, 0, 0);
        acc[i][j] = __builtin_amdgcn_mfma_f32_16x16x32_f16(aH[i], bH[j], acc[i][j], 0, 0, 0);
      }
  }

#pragma unroll
  for (int i = 0; i < 4; ++i)
#pragma unroll
    for (int j = 0; j < 4; ++j)
#pragma unroll
      for (int r = 0; r < 4; ++r) {
        const float val = acc[i][j][r] * 0.125f;
        atomicAdd(&lh[sortkey(val) >> 18], 1u);
      }
  __syncthreads();
  unsigned* __restrict__ gh = ghist + (size_t)h * 16384;
  for (int i = threadIdx.x; i < 16384; i += 512) {
    const unsigned c = lh[i];
    if (c) atomicAdd(&gh[i], c);
  }
}

__global__ __launch_bounds__(256) void fb_scan14(const unsigned* __restrict__ ghist,
                                                 const unsigned* __restrict__ flagArr,
                                                 unsigned* __restrict__ state)
{
  const int hh = blockIdx.x;
  if (flagArr[hh] != 0) return;
  const int t = threadIdx.x;
  __shared__ unsigned part[256];
  __shared__ unsigned out[4];
  const unsigned* __restrict__ hb = ghist + (size_t)hh * 16384;
  unsigned s = 0;
  for (int j = 0; j < 64; ++j) s += hb[t*64 + j];
  part[t] = s;
  __syncthreads();
  if (t == 0) {
    unsigned run = 0;
    for (int i = 0; i < 256; ++i) { unsigned tmp = part[i]; part[i] = run; run += tmp; }
  }
  __syncthreads();
  const unsigned cum0 = part[t];
  if (K_A >= cum0 && K_A < cum0 + s) {
    unsigned c2 = cum0;
    for (int j = 0; j < 64; ++j) {
      const unsigned c = hb[t*64 + j];
      if (K_A < c2 + c) {
        const unsigned binA = t*64 + j;
        const unsigned residA = K_A - c2;
        unsigned binB, residB;
        if (residA + 1 < c) { binB = binA; residB = residA + 1; }
        else {
          unsigned bb = binA + 1;
          while (bb < 16384 && hb[bb] == 0) ++bb;
          if (bb >= 16384) bb = 16383;  // defensive
          binB = bb; residB = 0;
        }
        out[0] = binA; out[1] = residA; out[2] = binB; out[3] = residB;
        break;
      }
      c2 += c;
    }
  }
  __syncthreads();
  if (t < 4) state[hh*4 + t] = out[t];
}

__global__ __launch_bounds__(512) void fallback_compact(const _Float16* __restrict__ Qh,
                                                        const _Float16* __restrict__ Ql,
                                                        const _Float16* __restrict__ Kh,
                                                        const _Float16* __restrict__ Kl,
                                                        const unsigned* __restrict__ state,
                                                        const unsigned* __restrict__ flagArr,
                                                        unsigned* __restrict__ cand,
                                                        unsigned* __restrict__ ccnt)
{
  const int bn = blockIdx.x, bm = blockIdx.y, h = blockIdx.z;
  if (flagArr[h] != 0) return;
  const int wave = threadIdx.x >> 6, lane = threadIdx.x & 63;
  const int wr = wave >> 1, wc = wave & 1;
  const int m0 = bm * 256 + wr * 64;
  const int n0 = bn * 128 + wc * 64;
  const int lr = lane & 15;
  const int ko = lane >> 4;

  __shared__ unsigned lbuf[LCAP];
  __shared__ unsigned lcnt, gbase;
  if (threadIdx.x == 0) lcnt = 0;
  __syncthreads();
  const unsigned binA = state[h*4+0];
  const unsigned binB = state[h*4+2];
  unsigned* __restrict__ mycand = cand + (size_t)h * CAPC;

  f32x4 acc[4][4];
#pragma unroll
  for (int i = 0; i < 4; ++i)
#pragma unroll
    for (int j = 0; j < 4; ++j) acc[i][j] = (f32x4){0.f, 0.f, 0.f, 0.f};

#pragma unroll
  for (int kk = 0; kk < 2; ++kk) {
    f16x8 aH[4], aL[4], bH[4], bL[4];
#pragma unroll
    for (int i = 0; i < 4; ++i) {
      const size_t aoff = (size_t)(m0 + i*16 + lr) * 1024 + h*64 + kk*32 + ko*8;
      aH[i] = *(const f16x8*)(Qh + aoff);
      aL[i] = *(const f16x8*)(Ql + aoff);
      const size_t boff = (size_t)(n0 + i*16 + lr) * 1024 + h*64 + kk*32 + ko*8;
      bH[i] = *(const f16x8*)(Kh + boff);
      bL[i] = *(const f16x8*)(Kl + boff);
    }
#pragma unroll
    for (int i = 0; i < 4; ++i)
#pragma unroll
      for (int j = 0; j < 4; ++j) {
        acc[i][j] = __builtin_amdgcn_mfma_f32_16x16x32_f16(aL[i], bL[j], acc[i][j], 0, 0, 0);
        acc[i][j] = __builtin_amdgcn_mfma_f32_16x16x32_f16(aH[i], bL[j], acc[i][j], 0, 0, 0);
        acc[i][j] = __builtin_amdgcn_mfma_f32_16x16x32_f16(aL[i], bH[j], acc[i][j], 0, 0, 0);
        acc[i][j] = __builtin_amdgcn_mfma_f32_16x16x32_f16(aH[i], bH[j], acc[i][j], 0, 0, 0);
      }
  }

#pragma unroll
  for (int i = 0; i < 4; ++i)
#pragma unroll
    for (int j = 0; j < 4; ++j)
#pragma unroll
      for (int r = 0; r < 4; ++r) {
        const float val = acc[i][j][r] * 0.125f;
        const unsigned u = sortkey(val);
        const unsigned bin = u >> 18;
        if (bin == binA || bin == binB) {
          unsigned id = atomicAdd(&lcnt, 1u);
          if (id < LCAP) lbuf[id] = u;
          else { unsigned g = atomicAdd(&ccnt[h], 1u); if (g < CAPC) mycand[g] = u; }
        }
      }
  __syncthreads();
  const unsigned n = (lcnt < LCAP) ? lcnt : LCAP;
  if (threadIdx.x == 0) gbase = n ? atomicAdd(&ccnt[h], n) : 0u;
  __syncthreads();
  const unsigned gb = gbase;
  for (unsigned i = threadIdx.x; i < n; i += 512)
    if (gb + i < CAPC) mycand[gb + i] = lbuf[i];
}

// seed the parallel-final-select state after scan9/fallback resolved binA/binB
__global__ __launch_bounds__(64) void seed_fs(const unsigned* __restrict__ state,
                                              unsigned* __restrict__ sstate)
{
  const int t = threadIdx.x;
  if (t < HH * 4) sstate[t] = state[t];
}

// ---------------- parallel final select: 3 rounds of (hist over 32 blocks, scan) ----------------
__global__ __launch_bounds__(256) void fs_hist(const unsigned* __restrict__ cand,
                                               const unsigned* __restrict__ ccnt,
                                               const unsigned* __restrict__ sstate,
                                               unsigned* __restrict__ fhist,
                                               int s, int w)
{
  const int hh = blockIdx.y;
  const int t = threadIdx.x;
  const unsigned nb = 1u << w;
  __shared__ unsigned lh0[256], lh1[256];
  lh0[t] = 0; lh1[t] = 0;
  __syncthreads();
  const unsigned pfxA = sstate[hh*4+0];
  const unsigned pfxB = sstate[hh*4+2];
  unsigned n = ccnt[hh]; if (n > CAPC) n = CAPC;
  const unsigned* __restrict__ list = cand + (size_t)hh * CAPC;
  for (unsigned i = blockIdx.x * 256 + t; i < n; i += 32 * 256) {
    const unsigned u = list[i];
    if ((u >> (s + w)) == pfxA) atomicAdd(&lh0[(u >> s) & (nb - 1)], 1u);
    if ((u >> (s + w)) == pfxB) atomicAdd(&lh1[(u >> s) & (nb - 1)], 1u);
  }
  __syncthreads();
  if (t < (int)nb) {
    if (lh0[t]) atomicAdd(&fhist[hh*512 + t], lh0[t]);
    if (lh1[t]) atomicAdd(&fhist[hh*512 + 256 + t], lh1[t]);
  }
}

__global__ __launch_bounds__(256) void fs_scan(unsigned* __restrict__ fhist,
                                               unsigned* __restrict__ sstate,
                                               float* __restrict__ thr,
                                               int s, int w)
{
  const int hh = blockIdx.x;
  const int t = threadIdx.x;
  const unsigned nb = 1u << w;
  if (t == 0) {
    float vals[2];
    for (int tgt = 0; tgt < 2; ++tgt) {
      unsigned pfx = sstate[hh*4 + tgt*2];
      unsigned k   = sstate[hh*4 + tgt*2 + 1];
      const unsigned* hb = &fhist[hh*512 + tgt*256];
      unsigned cum = 0, b = 0;
      for (; b < nb; ++b) { const unsigned c = hb[b]; if (cum + c > k) break; cum += c; }
      if (b == nb) b = nb - 1;
      pfx = (pfx << w) | b;
      k -= cum;
      sstate[hh*4 + tgt*2]     = pfx;
      sstate[hh*4 + tgt*2 + 1] = k;
      if (s == 0) vals[tgt] = inv_sortkey(pfx);
    }
    if (s == 0) thr[hh] = vals[0] + QFRAC * (vals[1] - vals[0]);
  }
  __syncthreads();
  fhist[hh*512 + t] = 0;           // zero for next round
  fhist[hh*512 + 256 + t] = 0;
}

// ---------------- pass 3: flash softmax+PV, key-split over 2 halves ----------------
// 1D grid + XCD swizzle: each XCD gets 128 contiguous blocks = 4 (head,half)
// groups (~4 MB K+V+Q working set, L2-resident). Pure index remap; outputs
// are written exactly once by the same logic as the 3D version.
__global__ __launch_bounds__(256) void flash_pv_sk(const _Float16* __restrict__ Qh,
                                                   const _Float16* __restrict__ Ql,
                                                   const _Float16* __restrict__ Kh,
                                                   const _Float16* __restrict__ Kl,
                                                   const _Float16* __restrict__ VtH,
                                                   const _Float16* __restrict__ VtL,
                                                   const float* __restrict__ thrArr,
                                                   float* __restrict__ pctx,
                                                   float* __restrict__ prs)
{
  const int wgid = blockIdx.x;                       // 0..1023
  const int swz  = (wgid & 7) * 128 + (wgid >> 3);   // XCD k gets swz in [k*128, k*128+128)
  const int half = swz >> 9;                         // 0..1
  const int h    = (swz >> 5) & 15;                  // 0..15
  const int bm   = swz & 31;                         // 0..31 -> rows bm*64
  const int wave = threadIdx.x >> 6, lane = threadIdx.x & 63;
  const int lr = lane & 15;
  const int ko = lane >> 4;
  const int m0 = bm * 64;
  const float thr = thrArr[h];

  __shared__ _Float16 Plds[64][136];  // pad 128->136
  __shared__ float rsLDS[64][4];

  // Q fragments are kt-invariant: hoist
  f16x8 qH[4][2], qL[4][2];
#pragma unroll
  for (int i = 0; i < 4; ++i)
#pragma unroll
    for (int kk = 0; kk < 2; ++kk) {
      const size_t aoff = (size_t)(m0 + i*16 + lr) * 1024 + h*64 + kk*32 + ko*8;
      qH[i][kk] = *(const f16x8*)(Qh + aoff);
      qL[i][kk] = *(const f16x8*)(Ql + aoff);
    }

  f32x4 oacc[4];
#pragma unroll
  for (int i = 0; i < 4; ++i) oacc[i] = (f32x4){0.f, 0.f, 0.f, 0.f};
  float rs[4][4];
#pragma unroll
  for (int i = 0; i < 4; ++i)
#pragma unroll
    for (int r = 0; r < 4; ++r) rs[i][r] = 0.f;

  const int d0 = wave * 16;   // PV: wave owns dims d0..d0+15

  for (int kt = half*8; kt < half*8 + 8; ++kt) {
    const int n0 = kt*128 + wave*32;   // S: wave owns keys n0..n0+31
    f32x4 sacc[4][2];
#pragma unroll
    for (int i = 0; i < 4; ++i)
#pragma unroll
      for (int j = 0; j < 2; ++j) sacc[i][j] = (f32x4){0.f, 0.f, 0.f, 0.f};

#pragma unroll
    for (int kk = 0; kk < 2; ++kk) {
      f16x8 bH[2], bL[2];
#pragma unroll
      for (int j = 0; j < 2; ++j) {
        const size_t boff = (size_t)(n0 + j*16 + lr) * 1024 + h*64 + kk*32 + ko*8;
        bH[j] = *(const f16x8*)(Kh + boff);
        bL[j] = *(const f16x8*)(Kl + boff);
      }
#pragma unroll
      for (int i = 0; i < 4; ++i)
#pragma unroll
        for (int j = 0; j < 2; ++j) {
          sacc[i][j] = __builtin_amdgcn_mfma_f32_16x16x32_f16(qL[i][kk], bL[j], sacc[i][j], 0, 0, 0);
          sacc[i][j] = __builtin_amdgcn_mfma_f32_16x16x32_f16(qH[i][kk], bL[j], sacc[i][j], 0, 0, 0);
          sacc[i][j] = __builtin_amdgcn_mfma_f32_16x16x32_f16(qL[i][kk], bH[j], sacc[i][j], 0, 0, 0);
          sacc[i][j] = __builtin_amdgcn_mfma_f32_16x16x32_f16(qH[i][kk], bH[j], sacc[i][j], 0, 0, 0);
        }
    }

    // mask + exp + P->LDS + rowsum partials
#pragma unroll
    for (int i = 0; i < 4; ++i)
#pragma unroll
      for (int j = 0; j < 2; ++j)
#pragma unroll
        for (int r = 0; r < 4; ++r) {
          const float val = sacc[i][j][r] * 0.125f;
          const float p = (val >= thr) ? __expf(val - thr - ESHIFT) : 0.f;
          rs[i][r] += p;
          Plds[i*16 + ko*4 + r][wave*32 + j*16 + lr] = (_Float16)p;
        }
    __syncthreads();

    // PV: oacc[i] over dims d0+lr, keys kt*128..+127
#pragma unroll
    for (int kk2 = 0; kk2 < 4; ++kk2) {
      f16x8 pa[4];
#pragma unroll
      for (int i = 0; i < 4; ++i)
        pa[i] = *(const f16x8*)&Plds[i*16 + lr][kk2*32 + ko*8];
      const size_t vo = (size_t)(h*64 + d0 + lr) * 2048 + kt*128 + kk2*32 + ko*8;
      const f16x8 vH = *(const f16x8*)(VtH + vo);
      const f16x8 vL = *(const f16x8*)(VtL + vo);
#pragma unroll
      for (int i = 0; i < 4; ++i) {
        oacc[i] = __builtin_amdgcn_mfma_f32_16x16x32_f16(pa[i], vL, oacc[i], 0, 0, 0);
        oacc[i] = __builtin_amdgcn_mfma_f32_16x16x32_f16(pa[i], vH, oacc[i], 0, 0, 0);
      }
    }
    __syncthreads();   // before next kt overwrites Plds
  }

  // rowsum: reduce across the 16 lanes of each ko-group, then across waves
#pragma unroll
  for (int i = 0; i < 4; ++i)
#pragma unroll
    for (int r = 0; r < 4; ++r) {
      float v = rs[i][r];
      v += __shfl_xor(v, 1); v += __shfl_xor(v, 2);
      v += __shfl_xor(v, 4); v += __shfl_xor(v, 8);
      rs[i][r] = v;
    }
  if (lr == 0) {
#pragma unroll
    for (int i = 0; i < 4; ++i)
#pragma unroll
      for (int r = 0; r < 4; ++r)
        rsLDS[i*16 + ko*4 + r][wave] = rs[i][r];
  }
  __syncthreads();

  // write partial rowsums
  if (wave == 0 && lr == 0) {
#pragma unroll
    for (int i = 0; i < 4; ++i)
#pragma unroll
      for (int r = 0; r < 4; ++r) {
        const int lrow = i*16 + ko*4 + r;
        prs[half*32768 + h*2048 + m0 + lrow] =
            rsLDS[lrow][0] + rsLDS[lrow][1] + rsLDS[lrow][2] + rsLDS[lrow][3];
      }
  }

  // store raw partial O
  float* __restrict__ pc = pctx + (size_t)half * PLANE;
#pragma unroll
  for (int i = 0; i < 4; ++i)
#pragma unroll
    for (int r = 0; r < 4; ++r) {
      const int lrow = i*16 + ko*4 + r;
      pc[(size_t)(m0 + lrow) * 1024 + h*64 + d0 + lr] = oacc[i][r];
    }
}

// ---------------- host ----------------
extern "C" void kernel_launch(void* const* d_in, const int* in_sizes, int n_in,
                              void* d_out, int out_size, void* d_ws, size_t ws_size,
                              hipStream_t stream)
{
  const float* x  = (const float*)d_in[0];
  const float* Wq = (const float*)d_in[1];
  const float* bq = (const float*)d_in[2];
  const float* Wk = (const float*)d_in[3];
  const float* bk = (const float*)d_in[4];
  const float* Wv = (const float*)d_in[5];
  const float* bv = (const float*)d_in[6];
  const float* Wo = (const float*)d_in[7];
  const float* bo = (const float*)d_in[8];
  float* out = (float*)d_out;
  char*  ws  = (char*)d_ws;

  const size_t MB = 1u << 20;
  _Float16* xh      = (_Float16*)(ws + 0*MB);
  _Float16* xl      = (_Float16*)(ws + 4*MB);
  _Float16* wplanes = (_Float16*)(ws + 8*MB);    // 8 x 2 MiB transposed W planes
  _Float16* Qh      = (_Float16*)(ws + 24*MB);
  _Float16* Ql      = (_Float16*)(ws + 28*MB);
  _Float16* Kh      = (_Float16*)(ws + 32*MB);
  _Float16* Kl      = (_Float16*)(ws + 36*MB);
  _Float16* VtH     = (_Float16*)(ws + 40*MB);   // [1024 dims][2048 rows]
  _Float16* VtL     = (_Float16*)(ws + 44*MB);
  _Float16* ctxh    = (_Float16*)(ws + 48*MB);
  _Float16* ctxl    = (_Float16*)(ws + 52*MB);
  const size_t base = 56*MB;
  unsigned* state    = (unsigned*)(ws + base);
  float*    thr      = (float*)(ws + base + 4096);
  unsigned* ccnt     = (unsigned*)(ws + base + 8192);
  unsigned* flag     = (unsigned*)(ws + base + 12288);
  unsigned* rangeLo  = (unsigned*)(ws + base + 16384);
  unsigned* rangeHi  = (unsigned*)(ws + base + 20480);
  unsigned* sstate   = (unsigned*)(ws + base + 24576);
  unsigned* fhist    = (unsigned*)(ws + base + 28672);  // HH*512*4 = 32 KiB
  unsigned* cntBelow = (unsigned*)(ws + base + 65536);
  unsigned* ghist9   = (unsigned*)(ws + base + 69632);  // HH*16 u32
  unsigned* ghist    = (unsigned*)(ws + 57*MB);   // 1 MiB (fallback only)
  unsigned* shist    = (unsigned*)(ws + 58*MB);   // 1 MiB
  unsigned* cand     = (unsigned*)(ws + 59*MB);   // HH * CAPC * 4 = 20 MiB
  float*    prs      = (float*)(ws + 80*MB);      // 2 x 16 x 2048 f32
  float*    pbuf     = (float*)(ws + 81*MB);      // 6 x 8 MiB partials
  float*    pctx     = pbuf;                      // planes 0,1 (post combine_qk)
  float*    pO       = pbuf + (size_t)2 * PLANE;  // planes 2,3

  split_x<<<2048, 256, 0, stream>>>(x, xh, xl);
  split_wT<<<dim3(16, 16, 4), 256, 0, stream>>>(Wq, Wk, Wv, Wo, wplanes);
  gemm_qkv_part<<<dim3(8, 16, 6), 256, 0, stream>>>(xh, xl, wplanes, pbuf);
  combine_qk<<<dim3(2048, 2), 256, 0, stream>>>(pbuf, bq, bk, Qh, Ql, Kh, Kl);
  combine_vT<<<dim3(16, 32), 256, 0, stream>>>(pbuf, bv, VtH, VtL);

  init_sel<<<256, 256, 0, stream>>>(ghist, shist, ccnt, flag, fhist, cntBelow, ghist9);
  sample_hist<<<dim3(16, HH), 256, 0, stream>>>(Qh, Ql, Kh, Kl, shist);
  sample_scan<<<HH, 256, 0, stream>>>(shist, rangeLo, rangeHi);
  range_count<<<2048, 512, 0, stream>>>(Qh, Ql, Kh, Kl, rangeLo, rangeHi,
                                        cand, ccnt, cntBelow, ghist9);
  scan9<<<1, 64, 0, stream>>>(ghist9, cntBelow, rangeLo, rangeHi, ccnt, state, flag);
  // fallback chain (early-exit per head when prediction held)
  fb_scores_hist<<<dim3(16, 8, HH), 512, 0, stream>>>(Qh, Ql, Kh, Kl, flag, ghist);
  fb_scan14<<<HH, 256, 0, stream>>>(ghist, flag, state);
  fallback_compact<<<dim3(16, 8, HH), 512, 0, stream>>>(Qh, Ql, Kh, Kl, state, flag, cand, ccnt);
  seed_fs<<<1, 64, 0, stream>>>(state, sstate);
  // parallel final select: rounds (s,w) = (10,8), (2,8), (0,2)
  fs_hist<<<dim3(32, HH), 256, 0, stream>>>(cand, ccnt, sstate, fhist, 10, 8);
  fs_scan<<<HH, 256, 0, stream>>>(fhist, sstate, thr, 10, 8);
  fs_hist<<<dim3(32, HH), 256, 0, stream>>>(cand, ccnt, sstate, fhist, 2, 8);
  fs_scan<<<HH, 256, 0, stream>>>(fhist, sstate, thr, 2, 8);
  fs_hist<<<dim3(32, HH), 256, 0, stream>>>(cand, ccnt, sstate, fhist, 0, 2);
  fs_scan<<<HH, 256, 0, stream>>>(fhist, sstate, thr, 0, 2);

  flash_pv_sk<<<1024, 256, 0, stream>>>(Qh, Ql, Kh, Kl, VtH, VtL, thr, pctx, prs);
  combine_ctx<<<2048, 256, 0, stream>>>(pctx, prs, ctxh, ctxl);

  gemm_o_part<<<dim3(8, 16, 2), 256, 0, stream>>>(ctxh, ctxl, wplanes, pO);
  combine_o<<<2048, 256, 0, stream>>>(pO, bo, out);
}